// Round 1
// baseline (4949.928 us; speedup 1.0000x reference)
//
#include <hip/hip_runtime.h>
#include <math.h>

#define NN 25000
#define EE 400000
#define HH 64
#define NHEAD 4
#define SDIM 16
#define EFDIM 8
#define KHOP 2
#define MIN 168   // 2H + 2S + EF
#define WID 128
#define GIN 192

__device__ __forceinline__ float wave_sum64(float v) {
#pragma unroll
  for (int m = 1; m <= 32; m <<= 1) v += __shfl_xor(v, m, 64);
  return v;
}

// ---------------- CSR build ----------------
__global__ void k_histo(const int* __restrict__ idx, int* __restrict__ cnt) {
  int e = blockIdx.x * 256 + threadIdx.x;
  if (e < EE) atomicAdd(&cnt[idx[e]], 1);
}

__global__ void k_scan(const int* __restrict__ cnt, int* __restrict__ rp) {
  __shared__ int part[1024];
  int t = threadIdx.x;
  const int CH = (NN + 1023) / 1024;
  int base = t * CH;
  int s = 0;
  for (int i = 0; i < CH; ++i) {
    int j = base + i;
    if (j < NN) s += cnt[j];
  }
  part[t] = s;
  __syncthreads();
  for (int off = 1; off < 1024; off <<= 1) {
    int v = (t >= off) ? part[t - off] : 0;
    __syncthreads();
    part[t] += v;
    __syncthreads();
  }
  int run = (t == 0) ? 0 : part[t - 1];
  for (int i = 0; i < CH; ++i) {
    int j = base + i;
    if (j < NN) { rp[j] = run; run += cnt[j]; }
  }
  if (t == 1023) rp[NN] = run;
}

__global__ void k_scatter(const int* __restrict__ idx, const int* __restrict__ rp,
                          int* __restrict__ cur, int* __restrict__ eids) {
  int e = blockIdx.x * 256 + threadIdx.x;
  if (e < EE) {
    int n = idx[e];
    int p = atomicAdd(&cur[n], 1);
    eids[rp[n] + p] = e;
  }
}

// deterministic order within each segment (atomics scramble it)
__global__ void k_sortseg(const int* __restrict__ rp, int* __restrict__ eids) {
  int node = blockIdx.x * 256 + threadIdx.x;
  if (node >= NN) return;
  int b = rp[node], e = rp[node + 1];
  for (int i = b + 1; i < e; ++i) {
    int v = eids[i];
    int j = i - 1;
    while (j >= b && eids[j] > v) { eids[j + 1] = eids[j]; --j; }
    eids[j + 1] = v;
  }
}

// ---------------- LayerNorm (wave per row, H=64) ----------------
__global__ __launch_bounds__(256) void k_ln(const float* __restrict__ h,
                                            const float* __restrict__ lw,
                                            const float* __restrict__ lb,
                                            float* __restrict__ out) {
  int g = blockIdx.x * 256 + threadIdx.x;
  int node = g >> 6, lane = g & 63;
  if (node >= NN) return;
  float v = h[g];
  float mean = wave_sum64(v) * (1.0f / 64.0f);
  float d = v - mean;
  float var = wave_sum64(d * d) * (1.0f / 64.0f);
  out[g] = d * rsqrtf(var + 1e-5f) * lw[lane] + lb[lane];
}

// ---------------- fused per-edge MLP: raw[E,4] ----------------
// inp = [hn[idxA] | hn[idxB] | xs[idxA] | xs[idxB] | ef]  (168)
// raw = relu(inp @ w1^T) @ w2^T
__global__ __launch_bounds__(256, 2) void k_edge_mlp(
    const float* __restrict__ hn, const float* __restrict__ xs,
    const int* __restrict__ idxA, const int* __restrict__ idxB,
    const float* __restrict__ ef,
    const float* __restrict__ w1, const float* __restrict__ w2,
    float* __restrict__ raw) {
  __shared__ float inp_s[64][MIN];        // 43008 B
  __shared__ float w1t_s[24][WID + 4];    // 12672 B
  __shared__ float w2_s[NHEAD][WID];      // 2048 B
  int t = threadIdx.x;
  int eb = blockIdx.x * 64;
  {
    int es = t >> 2, q = t & 3;
    int e = eb + es;
    int a = idxA[e], b = idxB[e];
    const float4* hA = (const float4*)(hn + (size_t)a * HH);
    const float4* hB = (const float4*)(hn + (size_t)b * HH);
    float4* r0 = (float4*)(&inp_s[es][0]);
    float4* r1 = (float4*)(&inp_s[es][HH]);
#pragma unroll
    for (int c = 0; c < 4; ++c) {
      r0[q + 4 * c] = hA[q + 4 * c];
      r1[q + 4 * c] = hB[q + 4 * c];
    }
    ((float4*)(&inp_s[es][128]))[q] = ((const float4*)(xs + (size_t)a * SDIM))[q];
    ((float4*)(&inp_s[es][144]))[q] = ((const float4*)(xs + (size_t)b * SDIM))[q];
    if (q < 2)
      ((float4*)(&inp_s[es][160]))[q] = ((const float4*)(ef + (size_t)e * EFDIM))[q];
    for (int i = t; i < NHEAD * WID; i += 256) ((float*)w2_s)[i] = w2[i];
  }
  __syncthreads();

  int tx = t & 31, ty = t >> 5;  // j = tx*4.. , edges = ty*8..
  float acc[8][4];
#pragma unroll
  for (int i = 0; i < 8; ++i)
#pragma unroll
    for (int j = 0; j < 4; ++j) acc[i][j] = 0.f;

  for (int kc = 0; kc < 7; ++kc) {
    int k0 = kc * 24;
    {
      int j = t & 127, half = t >> 7;
      const float* wrow = w1 + (size_t)j * MIN + k0 + half * 12;
#pragma unroll
      for (int i = 0; i < 12; ++i) w1t_s[half * 12 + i][j] = wrow[i];
    }
    __syncthreads();
#pragma unroll
    for (int kk = 0; kk < 24; kk += 2) {
      float4 b0v = *(const float4*)(&w1t_s[kk][tx * 4]);
      float4 b1v = *(const float4*)(&w1t_s[kk + 1][tx * 4]);
#pragma unroll
      for (int e2 = 0; e2 < 8; ++e2) {
        float2 av = *(const float2*)(&inp_s[ty * 8 + e2][k0 + kk]);
        acc[e2][0] += av.x * b0v.x + av.y * b1v.x;
        acc[e2][1] += av.x * b0v.y + av.y * b1v.y;
        acc[e2][2] += av.x * b0v.z + av.y * b1v.z;
        acc[e2][3] += av.x * b0v.w + av.y * b1v.w;
      }
    }
    __syncthreads();
  }

  // layer 2: raw[e][o] = sum_j relu(hidden[e][j]) * w2[o][j]
  float w2v[4][4];
#pragma unroll
  for (int o = 0; o < 4; ++o)
#pragma unroll
    for (int i = 0; i < 4; ++i) w2v[o][i] = w2_s[o][tx * 4 + i];
  float r[8][4];
#pragma unroll
  for (int e2 = 0; e2 < 8; ++e2) {
#pragma unroll
    for (int o = 0; o < 4; ++o) r[e2][o] = 0.f;
#pragma unroll
    for (int i = 0; i < 4; ++i) {
      float hv = fmaxf(acc[e2][i], 0.f);
#pragma unroll
      for (int o = 0; o < 4; ++o) r[e2][o] += hv * w2v[o][i];
    }
  }
#pragma unroll
  for (int m = 1; m <= 16; m <<= 1)
#pragma unroll
    for (int e2 = 0; e2 < 8; ++e2)
#pragma unroll
      for (int o = 0; o < 4; ++o) r[e2][o] += __shfl_xor(r[e2][o], m, 64);
  if (tx == 0) {
#pragma unroll
    for (int e2 = 0; e2 < 8; ++e2) {
      int e = eb + ty * 8 + e2;
      *(float4*)(&raw[(size_t)e * 4]) =
          make_float4(r[e2][0], r[e2][1], r[e2][2], r[e2][3]);
    }
  }
}

// ---------------- segmented softmax over dest (wave per node) ----------------
__global__ __launch_bounds__(256) void k_segsoftmax(
    const float* __restrict__ raw, const int* __restrict__ rp,
    const int* __restrict__ eids, float* __restrict__ wout, int hop) {
  int node = blockIdx.x * 4 + (threadIdx.x >> 6);
  if (node >= NN) return;
  int lane = threadIdx.x & 63;
  int beg = rp[node], end = rp[node + 1];
  if (beg == end) return;
  int li = lane >> 2, o = lane & 3;
  float mx = -1e30f;
  for (int b = beg; b < end; b += 16) {
    int ii = b + li;
    if (ii < end) {
      float v = raw[(size_t)eids[ii] * 4 + o];
      v = (v > 0.f ? v : 0.01f * v) * 0.25f;  // leaky_relu / sqrt(HS=16)
      mx = fmaxf(mx, v);
    }
  }
#pragma unroll
  for (int m = 4; m <= 32; m <<= 1) mx = fmaxf(mx, __shfl_xor(mx, m, 64));
  float sum = 0.f;
  for (int b = beg; b < end; b += 16) {
    int ii = b + li;
    if (ii < end) {
      float v = raw[(size_t)eids[ii] * 4 + o];
      v = (v > 0.f ? v : 0.01f * v) * 0.25f;
      sum += expf(v - mx);
    }
  }
#pragma unroll
  for (int m = 4; m <= 32; m <<= 1) sum += __shfl_xor(sum, m, 64);
  float inv = 1.f / (sum + 1e-9f);
  for (int b = beg; b < end; b += 16) {
    int ii = b + li;
    if (ii < end) {
      int e = eids[ii];
      float v = raw[(size_t)e * 4 + o];
      v = (v > 0.f ? v : 0.01f * v) * 0.25f;
      wout[(size_t)e * (NHEAD * KHOP) + o * KHOP + hop] = expf(v - mx) * inv;
    }
  }
}

__global__ void k_sigmoid(const float* __restrict__ raw, float* __restrict__ wout,
                          int hop) {
  int g = blockIdx.x * 256 + threadIdx.x;
  if (g >= EE * NHEAD) return;
  int e = g >> 2, o = g & 3;
  float v = raw[g];
  wout[(size_t)e * (NHEAD * KHOP) + o * KHOP + hop] = 1.f / (1.f + expf(-v));
}

// ------------- aggregate + proj + residual (wave per node, lane = h) -------------
__global__ __launch_bounds__(256) void k_aggregate(
    const float* __restrict__ hn, const float* __restrict__ ws, int hop,
    const int* __restrict__ rp, const int* __restrict__ eids,
    const int* __restrict__ idxA, const float* __restrict__ proj,
    float* __restrict__ h) {
  __shared__ float proj_s[64][68];
  __shared__ float agg_s[4][64];
  int t = threadIdx.x;
  for (int i = t; i < 4096; i += 256) proj_s[i >> 6][i & 63] = proj[i];
  int wv = t >> 6, lane = t & 63;
  int node = blockIdx.x * 4 + wv;
  float acc = 0.f;
  if (node < NN) {
    int beg = rp[node], end = rp[node + 1];
    int hd = lane >> 4;
    for (int ii = beg; ii < end; ++ii) {
      int e = eids[ii];
      float w = ws[(size_t)e * (NHEAD * KHOP) + hd * KHOP + hop];
      acc += w * hn[(size_t)idxA[e] * HH + lane];
    }
  }
  agg_s[wv][lane] = acc;
  __syncthreads();
  if (node < NN) {
    float m = 0.f;
#pragma unroll
    for (int hh = 0; hh < 64; hh += 4) {
      float4 p = *(const float4*)(&proj_s[lane][hh]);
      m += p.x * agg_s[wv][hh] + p.y * agg_s[wv][hh + 1] +
           p.z * agg_s[wv][hh + 2] + p.w * agg_s[wv][hh + 3];
    }
    h[(size_t)node * HH + lane] += m;
  }
}

// ---------------- gating phase ----------------
__global__ void k_gatein(const float* __restrict__ x, const float* __restrict__ hf,
                         const float* __restrict__ hr, float* __restrict__ gi) {
  int g = blockIdx.x * 256 + threadIdx.x;
  if (g >= NN * HH) return;
  int node = g >> 6, j = g & 63;
  float xv = x[g];
  gi[(size_t)node * GIN + j] = xv;
  gi[(size_t)node * GIN + 64 + j] = hf[g] - xv;
  gi[(size_t)node * GIN + 128 + j] = hr[g] - xv;
}

__global__ void k_candin(const float* __restrict__ x, const float* __restrict__ r,
                         float* __restrict__ gi) {
  int g = blockIdx.x * 256 + threadIdx.x;
  if (g >= NN * HH) return;
  gi[(size_t)(g >> 6) * GIN + (g & 63)] = r[g] * x[g];
}

__global__ void k_final(const float* __restrict__ x, const float* __restrict__ zv,
                        const float* __restrict__ cand, float* __restrict__ outF) {
  int g = blockIdx.x * 256 + threadIdx.x;
  if (g >= NN * HH) return;
  float z = zv[g];
  outF[g] = (1.f - z) * x[g] + z * cand[g];
}

// C[M,Nc] = act(A[M,K] @ B[Nc,K]^T + bias)   ACT: 0 none, 1 relu, 2 sigmoid, 3 tanh
template <int ACT>
__global__ __launch_bounds__(256) void k_gemm(const float* __restrict__ A,
                                              const float* __restrict__ B,
                                              const float* __restrict__ bias,
                                              float* __restrict__ C, int M, int Nc,
                                              int Kd) {
  __shared__ float As[16][68];
  __shared__ float Bs[16][68];
  int t = threadIdx.x;
  int m0 = blockIdx.x * 64, n0 = blockIdx.y * 64;
  int tx = t & 15, ty = t >> 4;
  float acc[4][4];
#pragma unroll
  for (int i = 0; i < 4; ++i)
#pragma unroll
    for (int j = 0; j < 4; ++j) acc[i][j] = 0.f;
  int row = t & 63, kq = t >> 6;
  for (int k0 = 0; k0 < Kd; k0 += 16) {
    float4 av = make_float4(0.f, 0.f, 0.f, 0.f);
    float4 bv = make_float4(0.f, 0.f, 0.f, 0.f);
    if (m0 + row < M) av = *(const float4*)(&A[(size_t)(m0 + row) * Kd + k0 + kq * 4]);
    if (n0 + row < Nc) bv = *(const float4*)(&B[(size_t)(n0 + row) * Kd + k0 + kq * 4]);
    As[kq * 4 + 0][row] = av.x;
    As[kq * 4 + 1][row] = av.y;
    As[kq * 4 + 2][row] = av.z;
    As[kq * 4 + 3][row] = av.w;
    Bs[kq * 4 + 0][row] = bv.x;
    Bs[kq * 4 + 1][row] = bv.y;
    Bs[kq * 4 + 2][row] = bv.z;
    Bs[kq * 4 + 3][row] = bv.w;
    __syncthreads();
#pragma unroll
    for (int kk = 0; kk < 16; ++kk) {
      float4 a4v = *(const float4*)(&As[kk][ty * 4]);
      float4 b4v = *(const float4*)(&Bs[kk][tx * 4]);
      float a4[4] = {a4v.x, a4v.y, a4v.z, a4v.w};
      float b4[4] = {b4v.x, b4v.y, b4v.z, b4v.w};
#pragma unroll
      for (int i = 0; i < 4; ++i)
#pragma unroll
        for (int j = 0; j < 4; ++j) acc[i][j] += a4[i] * b4[j];
    }
    __syncthreads();
  }
#pragma unroll
  for (int i = 0; i < 4; ++i) {
    int m = m0 + ty * 4 + i;
    if (m >= M) continue;
#pragma unroll
    for (int j = 0; j < 4; ++j) {
      int n = n0 + tx * 4 + j;
      if (n >= Nc) continue;
      float v = acc[i][j] + bias[n];
      if (ACT == 1) v = fmaxf(v, 0.f);
      else if (ACT == 2) v = 1.f / (1.f + expf(-v));
      else if (ACT == 3) v = tanhf(v);
      C[(size_t)m * Nc + n] = v;
    }
  }
}

extern "C" void kernel_launch(void* const* d_in, const int* in_sizes, int n_in,
                              void* d_out, int out_size, void* d_ws, size_t ws_size,
                              hipStream_t stream) {
  const float* x = (const float*)d_in[0];
  const float* xs = (const float*)d_in[1];
  const int* ei = (const int*)d_in[2];
  const float* ef = (const float*)d_in[3];
  const float* fw1 = (const float*)d_in[4];
  const float* fw2 = (const float*)d_in[5];
  const float* fpj = (const float*)d_in[6];
  const float* rw1 = (const float*)d_in[7];
  const float* rw2 = (const float*)d_in[8];
  const float* rpj = (const float*)d_in[9];
  const float* lnw = (const float*)d_in[10];
  const float* lnb = (const float*)d_in[11];
  const float* r_w1 = (const float*)d_in[12];
  const float* r_b1 = (const float*)d_in[13];
  const float* r_w2 = (const float*)d_in[14];
  const float* r_b2 = (const float*)d_in[15];
  const float* z_w1 = (const float*)d_in[16];
  const float* z_b1 = (const float*)d_in[17];
  const float* z_w2 = (const float*)d_in[18];
  const float* z_b2 = (const float*)d_in[19];
  const float* c_w1 = (const float*)d_in[20];
  const float* c_b1 = (const float*)d_in[21];
  const float* c_w2 = (const float*)d_in[22];
  const float* c_b2 = (const float*)d_in[23];
  const int* srcp = ei;
  const int* dstp = ei + EE;

  float* outF = (float*)d_out;
  float* outFW = outF + (size_t)NN * HH;
  float* outRW = outFW + (size_t)EE * NHEAD * KHOP;
  float* outZ = outRW + (size_t)EE * NHEAD * KHOP;
  float* outR = outZ + (size_t)NN * HH;

  float* f = (float*)d_ws;
  size_t o = 0;
  float* h_fwd = f + o; o += (size_t)NN * HH;
  float* h_rev = f + o; o += (size_t)NN * HH;
  float* h_nrm = f + o; o += (size_t)NN * HH;
  float* raw = f + o;   o += (size_t)EE * NHEAD;
  float* gi = f + o;    o += (size_t)NN * GIN;
  float* hid = f + o;   o += (size_t)NN * GIN;
  float* cand = f + o;  o += (size_t)NN * HH;
  int* ib = (int*)(f + o);
  int* rp_d = ib;
  int* rp_s = rp_d + (NN + 8);
  int* cur = rp_s + (NN + 8);
  int* eid_d = cur + (NN + 8);
  int* eid_s = eid_d + EE;

  hipMemcpyAsync(h_fwd, x, (size_t)NN * HH * 4, hipMemcpyDeviceToDevice, stream);
  hipMemcpyAsync(h_rev, x, (size_t)NN * HH * 4, hipMemcpyDeviceToDevice, stream);

  const int EB = (EE + 255) / 256, NB = (NN + 255) / 256, NW = (NN + 3) / 4;

  // CSR by dest
  hipMemsetAsync(cur, 0, NN * 4, stream);
  k_histo<<<EB, 256, 0, stream>>>(dstp, cur);
  k_scan<<<1, 1024, 0, stream>>>(cur, rp_d);
  hipMemsetAsync(cur, 0, NN * 4, stream);
  k_scatter<<<EB, 256, 0, stream>>>(dstp, rp_d, cur, eid_d);
  k_sortseg<<<NB, 256, 0, stream>>>(rp_d, eid_d);
  // CSR by src
  hipMemsetAsync(cur, 0, NN * 4, stream);
  k_histo<<<EB, 256, 0, stream>>>(srcp, cur);
  k_scan<<<1, 1024, 0, stream>>>(cur, rp_s);
  hipMemsetAsync(cur, 0, NN * 4, stream);
  k_scatter<<<EB, 256, 0, stream>>>(srcp, rp_s, cur, eid_s);
  k_sortseg<<<NB, 256, 0, stream>>>(rp_s, eid_s);

  for (int k = 0; k < KHOP; ++k) {
    k_ln<<<(NN * HH) / 256, 256, 0, stream>>>(h_fwd, lnw, lnb, h_nrm);
    k_edge_mlp<<<EE / 64, 256, 0, stream>>>(h_nrm, xs, srcp, dstp, ef,
                                            fw1 + (size_t)k * WID * MIN,
                                            fw2 + (size_t)k * NHEAD * WID, raw);
    k_segsoftmax<<<NW, 256, 0, stream>>>(raw, rp_d, eid_d, outFW, k);
    k_aggregate<<<NW, 256, 0, stream>>>(h_nrm, outFW, k, rp_d, eid_d, srcp,
                                        fpj + (size_t)k * HH * HH, h_fwd);
  }
  for (int k = 0; k < KHOP; ++k) {
    k_ln<<<(NN * HH) / 256, 256, 0, stream>>>(h_rev, lnw, lnb, h_nrm);
    k_edge_mlp<<<EE / 64, 256, 0, stream>>>(h_nrm, xs, dstp, srcp, ef,
                                            rw1 + (size_t)k * WID * MIN,
                                            rw2 + (size_t)k * NHEAD * WID, raw);
    k_sigmoid<<<(EE * NHEAD) / 256, 256, 0, stream>>>(raw, outRW, k);
    k_aggregate<<<NW, 256, 0, stream>>>(h_nrm, outRW, k, rp_s, eid_s, dstp,
                                        rpj + (size_t)k * HH * HH, h_rev);
  }

  k_gatein<<<(NN * HH) / 256, 256, 0, stream>>>(x, h_fwd, h_rev, gi);
  dim3 g1((NN + 63) / 64, 3), g2((NN + 63) / 64, 1);
  k_gemm<1><<<g1, 256, 0, stream>>>(gi, r_w1, r_b1, hid, NN, GIN, GIN);
  k_gemm<2><<<g2, 256, 0, stream>>>(hid, r_w2, r_b2, outR, NN, HH, GIN);
  k_gemm<1><<<g1, 256, 0, stream>>>(gi, z_w1, z_b1, hid, NN, GIN, GIN);
  k_gemm<2><<<g2, 256, 0, stream>>>(hid, z_w2, z_b2, outZ, NN, HH, GIN);
  k_candin<<<(NN * HH) / 256, 256, 0, stream>>>(x, outR, gi);
  k_gemm<1><<<g1, 256, 0, stream>>>(gi, c_w1, c_b1, hid, NN, GIN, GIN);
  k_gemm<3><<<g2, 256, 0, stream>>>(hid, c_w2, c_b2, cand, NN, HH, GIN);
  k_final<<<(NN * HH) / 256, 256, 0, stream>>>(x, outZ, cand, outF);
}

// Round 3
// 1391.135 us; speedup vs baseline: 3.5582x; 3.5582x over previous
//
#include <hip/hip_runtime.h>
#include <math.h>

#define NN 25000
#define EE 400000
#define HH 64
#define NHEAD 4
#define SDIM 16
#define EFDIM 8
#define KHOP 2
#define MIN 168   // 2H + 2S + EF
#define WID 128
#define GIN 192
#define NCAT 80   // H + S

__device__ __forceinline__ float wave_sum64(float v) {
#pragma unroll
  for (int m = 1; m <= 32; m <<= 1) v += __shfl_xor(v, m, 64);
  return v;
}

// ---------------- CSR build ----------------
__global__ void k_histo(const int* __restrict__ idx, int* __restrict__ cnt) {
  int e = blockIdx.x * 256 + threadIdx.x;
  if (e < EE) atomicAdd(&cnt[idx[e]], 1);
}

__global__ void k_scan(const int* __restrict__ cnt, int* __restrict__ rp) {
  __shared__ int part[1024];
  int t = threadIdx.x;
  const int CH = (NN + 1023) / 1024;
  int base = t * CH;
  int s = 0;
  for (int i = 0; i < CH; ++i) {
    int j = base + i;
    if (j < NN) s += cnt[j];
  }
  part[t] = s;
  __syncthreads();
  for (int off = 1; off < 1024; off <<= 1) {
    int v = (t >= off) ? part[t - off] : 0;
    __syncthreads();
    part[t] += v;
    __syncthreads();
  }
  int run = (t == 0) ? 0 : part[t - 1];
  for (int i = 0; i < CH; ++i) {
    int j = base + i;
    if (j < NN) { rp[j] = run; run += cnt[j]; }
  }
  if (t == 1023) rp[NN] = run;
}

__global__ void k_scatter(const int* __restrict__ idx, const int* __restrict__ rp,
                          int* __restrict__ cur, int* __restrict__ eids) {
  int e = blockIdx.x * 256 + threadIdx.x;
  if (e < EE) {
    int n = idx[e];
    int p = atomicAdd(&cur[n], 1);
    eids[rp[n] + p] = e;
  }
}

// deterministic order within each segment (atomics scramble it)
__global__ void k_sortseg(const int* __restrict__ rp, int* __restrict__ eids) {
  int node = blockIdx.x * 256 + threadIdx.x;
  if (node >= NN) return;
  int b = rp[node], e = rp[node + 1];
  for (int i = b + 1; i < e; ++i) {
    int v = eids[i];
    int j = i - 1;
    while (j >= b && eids[j] > v) { eids[j + 1] = eids[j]; --j; }
    eids[j + 1] = v;
  }
}

// ------------- weight repack: w1[128][168] -> pAB[256][80], pE[8][128] -------------
// pAB row j<128: [w1[j][0:64] | w1[j][128:144]]   (A-side: h-part + xs-part)
// pAB row j>=128: [w1[j-128][64:128] | w1[j-128][144:160]]  (B-side)
// pE[f][j] = w1[j][160+f]
__global__ void k_pack(const float* __restrict__ w1, float* __restrict__ pAB,
                       float* __restrict__ pE) {
  int i = blockIdx.x * 256 + threadIdx.x;
  if (i < 256 * NCAT) {
    int j = i / NCAT, k = i % NCAT;
    int row = (j < 128) ? j : j - 128;
    int col = (j < 128) ? (k < 64 ? k : k + 64) : (k < 64 ? k + 64 : k + 80);
    pAB[i] = w1[row * MIN + col];
  } else if (i < 256 * NCAT + 8 * 128) {
    int ii = i - 256 * NCAT;
    int f = ii >> 7, j = ii & 127;
    pE[ii] = w1[j * MIN + 160 + f];
  }
}

// ---------------- LayerNorm + concat xs: nodecat[N,80] ----------------
__global__ __launch_bounds__(256) void k_ln(const float* __restrict__ h,
                                            const float* __restrict__ xs,
                                            const float* __restrict__ lw,
                                            const float* __restrict__ lb,
                                            float* __restrict__ nodecat) {
  int t = threadIdx.x;
  int node = blockIdx.x * 4 + (t >> 6), lane = t & 63;
  if (node >= NN) return;
  float v = h[(size_t)node * HH + lane];
  float mean = wave_sum64(v) * (1.0f / 64.0f);
  float d = v - mean;
  float var = wave_sum64(d * d) * (1.0f / 64.0f);
  nodecat[(size_t)node * NCAT + lane] = d * rsqrtf(var + 1e-5f) * lw[lane] + lb[lane];
  if (lane < SDIM)
    nodecat[(size_t)node * NCAT + HH + lane] = xs[(size_t)node * SDIM + lane];
}

// ---------------- edge combine: raw[e] = relu(cA[a]+cB[b]+W1e·ef[e]) @ w2^T ------
__global__ __launch_bounds__(256) void k_edge_combine(
    const float* __restrict__ cAB, const float* __restrict__ ef,
    const int* __restrict__ idxA, const int* __restrict__ idxB,
    const float* __restrict__ w1e, const float* __restrict__ w2,
    float* __restrict__ raw) {
  __shared__ float w1e_s[8][128];
  __shared__ float w2_s[4][128];
  int t = threadIdx.x;
  for (int i = t; i < 1024; i += 256) w1e_s[i >> 7][i & 127] = w1e[i];
  for (int i = t; i < 512; i += 256) w2_s[i >> 7][i & 127] = w2[i];
  __syncthreads();
  int es = t >> 2, q = t & 3;
  int e = blockIdx.x * 64 + es;
  int a = idxA[e], b = idxB[e];
  const float4* cAp = (const float4*)(cAB + (size_t)a * 256 + q * 32);
  const float4* cBp = (const float4*)(cAB + (size_t)b * 256 + 128 + q * 32);
  const float4* efp = (const float4*)(ef + (size_t)e * EFDIM);
  float4 e0 = efp[0], e1 = efp[1];
  float efv[8] = {e0.x, e0.y, e0.z, e0.w, e1.x, e1.y, e1.z, e1.w};
  float p[4] = {0.f, 0.f, 0.f, 0.f};
#pragma unroll
  for (int c = 0; c < 8; ++c) {
    int j = q * 32 + c * 4;
    float4 av = cAp[c], bv = cBp[c];
    float h0 = av.x + bv.x, h1 = av.y + bv.y, h2 = av.z + bv.z, h3 = av.w + bv.w;
#pragma unroll
    for (int f = 0; f < 8; ++f) {
      float4 wr = *(const float4*)(&w1e_s[f][j]);
      h0 += efv[f] * wr.x; h1 += efv[f] * wr.y;
      h2 += efv[f] * wr.z; h3 += efv[f] * wr.w;
    }
    h0 = fmaxf(h0, 0.f); h1 = fmaxf(h1, 0.f);
    h2 = fmaxf(h2, 0.f); h3 = fmaxf(h3, 0.f);
#pragma unroll
    for (int o = 0; o < 4; ++o) {
      float4 w2r = *(const float4*)(&w2_s[o][j]);
      p[o] += h0 * w2r.x + h1 * w2r.y + h2 * w2r.z + h3 * w2r.w;
    }
  }
#pragma unroll
  for (int o = 0; o < 4; ++o) {
    p[o] += __shfl_xor(p[o], 1, 64);
    p[o] += __shfl_xor(p[o], 2, 64);
  }
  if (q == 0)
    *(float4*)(&raw[(size_t)e * 4]) = make_float4(p[0], p[1], p[2], p[3]);
}

// ---------------- segmented softmax over dest (wave per node) ----------------
__global__ __launch_bounds__(256) void k_segsoftmax(
    const float* __restrict__ raw, const int* __restrict__ rp,
    const int* __restrict__ eids, float* __restrict__ wout, int hop) {
  int node = blockIdx.x * 4 + (threadIdx.x >> 6);
  if (node >= NN) return;
  int lane = threadIdx.x & 63;
  int beg = rp[node], end = rp[node + 1];
  if (beg == end) return;
  int li = lane >> 2, o = lane & 3;
  float mx = -1e30f;
  for (int b = beg; b < end; b += 16) {
    int ii = b + li;
    if (ii < end) {
      float v = raw[(size_t)eids[ii] * 4 + o];
      v = (v > 0.f ? v : 0.01f * v) * 0.25f;  // leaky_relu / sqrt(HS=16)
      mx = fmaxf(mx, v);
    }
  }
#pragma unroll
  for (int m = 4; m <= 32; m <<= 1) mx = fmaxf(mx, __shfl_xor(mx, m, 64));
  float sum = 0.f;
  for (int b = beg; b < end; b += 16) {
    int ii = b + li;
    if (ii < end) {
      float v = raw[(size_t)eids[ii] * 4 + o];
      v = (v > 0.f ? v : 0.01f * v) * 0.25f;
      sum += expf(v - mx);
    }
  }
#pragma unroll
  for (int m = 4; m <= 32; m <<= 1) sum += __shfl_xor(sum, m, 64);
  float inv = 1.f / (sum + 1e-9f);
  for (int b = beg; b < end; b += 16) {
    int ii = b + li;
    if (ii < end) {
      int e = eids[ii];
      float v = raw[(size_t)e * 4 + o];
      v = (v > 0.f ? v : 0.01f * v) * 0.25f;
      wout[(size_t)e * (NHEAD * KHOP) + o * KHOP + hop] = expf(v - mx) * inv;
    }
  }
}

__global__ void k_sigmoid(const float* __restrict__ raw, float* __restrict__ wout,
                          int hop) {
  int g = blockIdx.x * 256 + threadIdx.x;
  if (g >= EE * NHEAD) return;
  int e = g >> 2, o = g & 3;
  float v = raw[g];
  wout[(size_t)e * (NHEAD * KHOP) + o * KHOP + hop] = 1.f / (1.f + expf(-v));
}

// ------------- aggregate + proj + residual (wave per node, lane = h) -------------
// hn is nodecat with row stride NCAT (first 64 entries = normed h)
__global__ __launch_bounds__(256) void k_aggregate(
    const float* __restrict__ hn, const float* __restrict__ ws, int hop,
    const int* __restrict__ rp, const int* __restrict__ eids,
    const int* __restrict__ idxA, const float* __restrict__ proj,
    float* __restrict__ h) {
  __shared__ float proj_s[64][68];
  __shared__ float agg_s[4][64];
  int t = threadIdx.x;
  for (int i = t; i < 4096; i += 256) proj_s[i >> 6][i & 63] = proj[i];
  int wv = t >> 6, lane = t & 63;
  int node = blockIdx.x * 4 + wv;
  float acc = 0.f;
  if (node < NN) {
    int beg = rp[node], end = rp[node + 1];
    int hd = lane >> 4;
    for (int ii = beg; ii < end; ++ii) {
      int e = eids[ii];
      float w = ws[(size_t)e * (NHEAD * KHOP) + hd * KHOP + hop];
      acc += w * hn[(size_t)idxA[e] * NCAT + lane];
    }
  }
  agg_s[wv][lane] = acc;
  __syncthreads();
  if (node < NN) {
    float m = 0.f;
#pragma unroll
    for (int hh = 0; hh < 64; hh += 4) {
      float4 p = *(const float4*)(&proj_s[lane][hh]);
      m += p.x * agg_s[wv][hh] + p.y * agg_s[wv][hh + 1] +
           p.z * agg_s[wv][hh + 2] + p.w * agg_s[wv][hh + 3];
    }
    h[(size_t)node * HH + lane] += m;
  }
}

// ---------------- gating phase ----------------
__global__ void k_gatein(const float* __restrict__ x, const float* __restrict__ hf,
                         const float* __restrict__ hr, float* __restrict__ gi) {
  int g = blockIdx.x * 256 + threadIdx.x;
  if (g >= NN * HH) return;
  int node = g >> 6, j = g & 63;
  float xv = x[g];
  gi[(size_t)node * GIN + j] = xv;
  gi[(size_t)node * GIN + 64 + j] = hf[g] - xv;
  gi[(size_t)node * GIN + 128 + j] = hr[g] - xv;
}

__global__ void k_candin(const float* __restrict__ x, const float* __restrict__ r,
                         float* __restrict__ gi) {
  int g = blockIdx.x * 256 + threadIdx.x;
  if (g >= NN * HH) return;
  gi[(size_t)(g >> 6) * GIN + (g & 63)] = r[g] * x[g];
}

__global__ void k_final(const float* __restrict__ x, const float* __restrict__ zv,
                        const float* __restrict__ cand, float* __restrict__ outF) {
  int g = blockIdx.x * 256 + threadIdx.x;
  if (g >= NN * HH) return;
  float z = zv[g];
  outF[g] = (1.f - z) * x[g] + z * cand[g];
}

// C[M,Nc] = act(A[M,K] @ B[Nc,K]^T + bias)   ACT: 0 none, 1 relu, 2 sigmoid, 3 tanh
// bias may be nullptr.
template <int ACT>
__global__ __launch_bounds__(256) void k_gemm(const float* __restrict__ A,
                                              const float* __restrict__ B,
                                              const float* __restrict__ bias,
                                              float* __restrict__ C, int M, int Nc,
                                              int Kd) {
  __shared__ float As[16][68];
  __shared__ float Bs[16][68];
  int t = threadIdx.x;
  int m0 = blockIdx.x * 64, n0 = blockIdx.y * 64;
  int tx = t & 15, ty = t >> 4;
  float acc[4][4];
#pragma unroll
  for (int i = 0; i < 4; ++i)
#pragma unroll
    for (int j = 0; j < 4; ++j) acc[i][j] = 0.f;
  int row = t & 63, kq = t >> 6;
  for (int k0 = 0; k0 < Kd; k0 += 16) {
    float4 av = make_float4(0.f, 0.f, 0.f, 0.f);
    float4 bv = make_float4(0.f, 0.f, 0.f, 0.f);
    if (m0 + row < M) av = *(const float4*)(&A[(size_t)(m0 + row) * Kd + k0 + kq * 4]);
    if (n0 + row < Nc) bv = *(const float4*)(&B[(size_t)(n0 + row) * Kd + k0 + kq * 4]);
    As[kq * 4 + 0][row] = av.x;
    As[kq * 4 + 1][row] = av.y;
    As[kq * 4 + 2][row] = av.z;
    As[kq * 4 + 3][row] = av.w;
    Bs[kq * 4 + 0][row] = bv.x;
    Bs[kq * 4 + 1][row] = bv.y;
    Bs[kq * 4 + 2][row] = bv.z;
    Bs[kq * 4 + 3][row] = bv.w;
    __syncthreads();
#pragma unroll
    for (int kk = 0; kk < 16; ++kk) {
      float4 a4v = *(const float4*)(&As[kk][ty * 4]);
      float4 b4v = *(const float4*)(&Bs[kk][tx * 4]);
      float a4[4] = {a4v.x, a4v.y, a4v.z, a4v.w};
      float b4[4] = {b4v.x, b4v.y, b4v.z, b4v.w};
#pragma unroll
      for (int i = 0; i < 4; ++i)
#pragma unroll
        for (int j = 0; j < 4; ++j) acc[i][j] += a4[i] * b4[j];
    }
    __syncthreads();
  }
#pragma unroll
  for (int i = 0; i < 4; ++i) {
    int m = m0 + ty * 4 + i;
    if (m >= M) continue;
#pragma unroll
    for (int j = 0; j < 4; ++j) {
      int n = n0 + tx * 4 + j;
      if (n >= Nc) continue;
      float v = acc[i][j] + (bias ? bias[n] : 0.f);
      if (ACT == 1) v = fmaxf(v, 0.f);
      else if (ACT == 2) v = 1.f / (1.f + expf(-v));
      else if (ACT == 3) v = tanhf(v);
      C[(size_t)m * Nc + n] = v;
    }
  }
}

extern "C" void kernel_launch(void* const* d_in, const int* in_sizes, int n_in,
                              void* d_out, int out_size, void* d_ws, size_t ws_size,
                              hipStream_t stream) {
  const float* x = (const float*)d_in[0];
  const float* xs = (const float*)d_in[1];
  const int* ei = (const int*)d_in[2];
  const float* ef = (const float*)d_in[3];
  const float* fw1 = (const float*)d_in[4];
  const float* fw2 = (const float*)d_in[5];
  const float* fpj = (const float*)d_in[6];
  const float* rw1 = (const float*)d_in[7];
  const float* rw2 = (const float*)d_in[8];
  const float* rpj = (const float*)d_in[9];
  const float* lnw = (const float*)d_in[10];
  const float* lnb = (const float*)d_in[11];
  const float* r_w1 = (const float*)d_in[12];
  const float* r_b1 = (const float*)d_in[13];
  const float* r_w2 = (const float*)d_in[14];
  const float* r_b2 = (const float*)d_in[15];
  const float* z_w1 = (const float*)d_in[16];
  const float* z_b1 = (const float*)d_in[17];
  const float* z_w2 = (const float*)d_in[18];
  const float* z_b2 = (const float*)d_in[19];
  const float* c_w1 = (const float*)d_in[20];
  const float* c_b1 = (const float*)d_in[21];
  const float* c_w2 = (const float*)d_in[22];
  const float* c_b2 = (const float*)d_in[23];
  const int* srcp = ei;
  const int* dstp = ei + EE;

  float* outF = (float*)d_out;
  float* outFW = outF + (size_t)NN * HH;
  float* outRW = outFW + (size_t)EE * NHEAD * KHOP;
  float* outZ = outRW + (size_t)EE * NHEAD * KHOP;
  float* outR = outZ + (size_t)NN * HH;

  float* f = (float*)d_ws;
  size_t o = 0;
  float* h_fwd = f + o;   o += (size_t)NN * HH;
  float* h_rev = f + o;   o += (size_t)NN * HH;
  float* nodecat = f + o; o += (size_t)NN * NCAT;
  // shared region: hops use {cAB, raw}; gating (after hops) reuses it for {gi, hid, cand}
  float* shr = f + o;
  size_t hop_sz = (size_t)NN * 256 + (size_t)EE * NHEAD;
  size_t gate_sz = (size_t)NN * (GIN + GIN + HH);
  o += (hop_sz > gate_sz ? hop_sz : gate_sz);
  float* cAB = shr;
  float* raw = shr + (size_t)NN * 256;
  float* gi = shr;
  float* hid = shr + (size_t)NN * GIN;
  float* cand = shr + (size_t)NN * GIN * 2;
  float* packAB = f + o; o += 4 * (size_t)256 * NCAT;
  float* packE = f + o;  o += 4 * (size_t)8 * 128;
  int* ib = (int*)(f + o);
  int* rp_d = ib;
  int* rp_s = rp_d + (NN + 8);
  int* cur = rp_s + (NN + 8);
  int* eid_d = cur + (NN + 8);
  int* eid_s = eid_d + EE;

  hipMemcpyAsync(h_fwd, x, (size_t)NN * HH * 4, hipMemcpyDeviceToDevice, stream);
  hipMemcpyAsync(h_rev, x, (size_t)NN * HH * 4, hipMemcpyDeviceToDevice, stream);

  const int EB = (EE + 255) / 256, NB = (NN + 255) / 256, NW = (NN + 3) / 4;
  const int PB = (256 * NCAT + 8 * 128 + 255) / 256;

  // weight repacks (4: fwd k=0,1; rev k=0,1)
  for (int k = 0; k < KHOP; ++k) {
    k_pack<<<PB, 256, 0, stream>>>(fw1 + (size_t)k * WID * MIN,
                                   packAB + (size_t)k * 256 * NCAT,
                                   packE + (size_t)k * 8 * 128);
    k_pack<<<PB, 256, 0, stream>>>(rw1 + (size_t)k * WID * MIN,
                                   packAB + (size_t)(2 + k) * 256 * NCAT,
                                   packE + (size_t)(2 + k) * 8 * 128);
  }

  // CSR by dest
  hipMemsetAsync(cur, 0, NN * 4, stream);
  k_histo<<<EB, 256, 0, stream>>>(dstp, cur);
  k_scan<<<1, 1024, 0, stream>>>(cur, rp_d);
  hipMemsetAsync(cur, 0, NN * 4, stream);
  k_scatter<<<EB, 256, 0, stream>>>(dstp, rp_d, cur, eid_d);
  k_sortseg<<<NB, 256, 0, stream>>>(rp_d, eid_d);
  // CSR by src
  hipMemsetAsync(cur, 0, NN * 4, stream);
  k_histo<<<EB, 256, 0, stream>>>(srcp, cur);
  k_scan<<<1, 1024, 0, stream>>>(cur, rp_s);
  hipMemsetAsync(cur, 0, NN * 4, stream);
  k_scatter<<<EB, 256, 0, stream>>>(srcp, rp_s, cur, eid_s);
  k_sortseg<<<NB, 256, 0, stream>>>(rp_s, eid_s);

  dim3 gN((NN + 63) / 64, 4);  // node projection: [N,80]@[80,256]^T
  for (int k = 0; k < KHOP; ++k) {
    k_ln<<<NW, 256, 0, stream>>>(h_fwd, xs, lnw, lnb, nodecat);
    k_gemm<0><<<gN, 256, 0, stream>>>(nodecat, packAB + (size_t)k * 256 * NCAT,
                                      nullptr, cAB, NN, 256, NCAT);
    k_edge_combine<<<EE / 64, 256, 0, stream>>>(cAB, ef, srcp, dstp,
                                                packE + (size_t)k * 8 * 128,
                                                fw2 + (size_t)k * NHEAD * WID, raw);
    k_segsoftmax<<<NW, 256, 0, stream>>>(raw, rp_d, eid_d, outFW, k);
    k_aggregate<<<NW, 256, 0, stream>>>(nodecat, outFW, k, rp_d, eid_d, srcp,
                                        fpj + (size_t)k * HH * HH, h_fwd);
  }
  for (int k = 0; k < KHOP; ++k) {
    k_ln<<<NW, 256, 0, stream>>>(h_rev, xs, lnw, lnb, nodecat);
    k_gemm<0><<<gN, 256, 0, stream>>>(nodecat, packAB + (size_t)(2 + k) * 256 * NCAT,
                                      nullptr, cAB, NN, 256, NCAT);
    k_edge_combine<<<EE / 64, 256, 0, stream>>>(cAB, ef, dstp, srcp,
                                                packE + (size_t)(2 + k) * 8 * 128,
                                                rw2 + (size_t)k * NHEAD * WID, raw);
    k_sigmoid<<<(EE * NHEAD) / 256, 256, 0, stream>>>(raw, outRW, k);
    k_aggregate<<<NW, 256, 0, stream>>>(nodecat, outRW, k, rp_s, eid_s, dstp,
                                        rpj + (size_t)k * HH * HH, h_rev);
  }

  k_gatein<<<(NN * HH) / 256, 256, 0, stream>>>(x, h_fwd, h_rev, gi);
  dim3 g1((NN + 63) / 64, 3), g2((NN + 63) / 64, 1);
  k_gemm<1><<<g1, 256, 0, stream>>>(gi, r_w1, r_b1, hid, NN, GIN, GIN);
  k_gemm<2><<<g2, 256, 0, stream>>>(hid, r_w2, r_b2, outR, NN, HH, GIN);
  k_gemm<1><<<g1, 256, 0, stream>>>(gi, z_w1, z_b1, hid, NN, GIN, GIN);
  k_gemm<2><<<g2, 256, 0, stream>>>(hid, z_w2, z_b2, outZ, NN, HH, GIN);
  k_candin<<<(NN * HH) / 256, 256, 0, stream>>>(x, outR, gi);
  k_gemm<1><<<g1, 256, 0, stream>>>(gi, c_w1, c_b1, hid, NN, GIN, GIN);
  k_gemm<3><<<g2, 256, 0, stream>>>(hid, c_w2, c_b2, cand, NN, HH, GIN);
  k_final<<<(NN * HH) / 256, 256, 0, stream>>>(x, outZ, cand, outF);
}

// Round 4
// 1034.634 us; speedup vs baseline: 4.7842x; 1.3446x over previous
//
#include <hip/hip_runtime.h>
#include <math.h>

#define NN 25000
#define EE 400000
#define HH 64
#define NHEAD 4
#define SDIM 16
#define EFDIM 8
#define KHOP 2
#define MIN 168   // 2H + 2S + EF
#define WID 128
#define GIN 192
#define KP 96     // padded K for node-proj GEMM (80 -> 96)

typedef __attribute__((ext_vector_type(8))) short bf16x8;
typedef __attribute__((ext_vector_type(4))) float f32x4;
typedef unsigned short ushortT;
typedef unsigned int uintT;

__device__ __forceinline__ float wave_sum64(float v) {
#pragma unroll
  for (int m = 1; m <= 32; m <<= 1) v += __shfl_xor(v, m, 64);
  return v;
}

__device__ __forceinline__ ushortT f2b(float f) {
  uintT u = __float_as_uint(f);
  return (ushortT)((u + 0x7FFFu + ((u >> 16) & 1u)) >> 16);
}
__device__ __forceinline__ float b2f(ushortT h) {
  return __uint_as_float(((uintT)h) << 16);
}
__device__ __forceinline__ float b2f_lo(uintT u) { return __uint_as_float(u << 16); }
__device__ __forceinline__ float b2f_hi(uintT u) { return __uint_as_float(u & 0xffff0000u); }

// ---------------- CSR build ----------------
__global__ void k_histo(const int* __restrict__ idx, int* __restrict__ cnt) {
  int e = blockIdx.x * 256 + threadIdx.x;
  if (e < EE) atomicAdd(&cnt[idx[e]], 1);
}

__global__ void k_scan(const int* __restrict__ cnt, int* __restrict__ rp) {
  __shared__ int part[1024];
  int t = threadIdx.x;
  const int CH = (NN + 1023) / 1024;
  int base = t * CH;
  int s = 0;
  for (int i = 0; i < CH; ++i) {
    int j = base + i;
    if (j < NN) s += cnt[j];
  }
  part[t] = s;
  __syncthreads();
  for (int off = 1; off < 1024; off <<= 1) {
    int v = (t >= off) ? part[t - off] : 0;
    __syncthreads();
    part[t] += v;
    __syncthreads();
  }
  int run = (t == 0) ? 0 : part[t - 1];
  for (int i = 0; i < CH; ++i) {
    int j = base + i;
    if (j < NN) { rp[j] = run; run += cnt[j]; }
  }
  if (t == 1023) rp[NN] = run;
}

__global__ void k_scatter(const int* __restrict__ idx, const int* __restrict__ rp,
                          int* __restrict__ cur, int* __restrict__ eids) {
  int e = blockIdx.x * 256 + threadIdx.x;
  if (e < EE) {
    int n = idx[e];
    int p = atomicAdd(&cur[n], 1);
    eids[rp[n] + p] = e;
  }
}

__global__ void k_sortseg(const int* __restrict__ rp, int* __restrict__ eids) {
  int node = blockIdx.x * 256 + threadIdx.x;
  if (node >= NN) return;
  int b = rp[node], e = rp[node + 1];
  for (int i = b + 1; i < e; ++i) {
    int v = eids[i];
    int j = i - 1;
    while (j >= b && eids[j] > v) { eids[j + 1] = eids[j]; --j; }
    eids[j + 1] = v;
  }
}

// ------------- weight repack: w1[128][168] -> pAB_bf[256][96], pE[8][128] -------------
__global__ void k_pack_bf(const float* __restrict__ w1, ushortT* __restrict__ pAB,
                          float* __restrict__ pE) {
  int i = blockIdx.x * 256 + threadIdx.x;
  if (i < 256 * KP) {
    int j = i / KP, k = i % KP;
    float v = 0.f;
    if (k < 80) {
      int row = (j < 128) ? j : j - 128;
      int col = (j < 128) ? (k < 64 ? k : k + 64) : (k < 64 ? k + 64 : k + 80);
      v = w1[row * MIN + col];
    }
    pAB[i] = f2b(v);
  } else if (i < 256 * KP + 8 * 128) {
    int ii = i - 256 * KP;
    int f = ii >> 7, j = ii & 127;
    pE[ii] = w1[j * MIN + 160 + f];
  }
}

__global__ void k_cvt(const float* __restrict__ src, ushortT* __restrict__ dst, int n) {
  int i = blockIdx.x * 256 + threadIdx.x;
  if (i < n) dst[i] = f2b(src[i]);
}

// ---------------- LayerNorm + concat xs -> nodecat_bf[N][96] (cols 80..95 = 0) ------
__global__ __launch_bounds__(256) void k_ln(const float* __restrict__ h,
                                            const float* __restrict__ xs,
                                            const float* __restrict__ lw,
                                            const float* __restrict__ lb,
                                            ushortT* __restrict__ nodecat) {
  int t = threadIdx.x;
  int node = blockIdx.x * 4 + (t >> 6), lane = t & 63;
  if (node >= NN) return;
  float v = h[(size_t)node * HH + lane];
  float mean = wave_sum64(v) * (1.0f / 64.0f);
  float d = v - mean;
  float var = wave_sum64(d * d) * (1.0f / 64.0f);
  nodecat[(size_t)node * KP + lane] = f2b(d * rsqrtf(var + 1e-5f) * lw[lane] + lb[lane]);
  if (lane < SDIM) {
    nodecat[(size_t)node * KP + HH + lane] = f2b(xs[(size_t)node * SDIM + lane]);
    nodecat[(size_t)node * KP + 80 + lane] = 0;
  }
}

// ---------------- MFMA bf16 GEMM: C[M,*] = act(A[M,K]@W[N,K]^T + bias) --------------
// block = 4 waves; wave w -> rows m0+16w..+15, cols n0..n0+63 (4 frags).
// A frag: lane l holds A[m0+16w+(l&15)][k0+(l>>4)*8 + 0..7]
// B frag: lane l holds W[n0+16n+(l&15)][k0+(l>>4)*8 + 0..7]
// C/D:    col = lane&15, row = (lane>>4)*4 + reg   [m89-verified]
template <int ACT, int BF16OUT>
__global__ __launch_bounds__(256) void k_gemm_bf(
    const ushortT* __restrict__ A, int lda, const ushortT* __restrict__ W,
    const float* __restrict__ bias, void* __restrict__ Cout, int ldc, int M, int Kd) {
  int w = threadIdx.x >> 6, l = threadIdx.x & 63;
  int m0 = blockIdx.x * 64 + w * 16;
  int n0 = blockIdx.y * 64;
  int rowa = m0 + (l & 15);
  int kb = l >> 4;
  f32x4 acc0 = {0.f, 0.f, 0.f, 0.f}, acc1 = acc0, acc2 = acc0, acc3 = acc0;
  for (int k0 = 0; k0 < Kd; k0 += 32) {
    bf16x8 af = {0, 0, 0, 0, 0, 0, 0, 0};
    if (rowa < M) af = *(const bf16x8*)(A + (size_t)rowa * lda + k0 + kb * 8);
    const ushortT* wp = W + (size_t)(n0 + (l & 15)) * Kd + k0 + kb * 8;
    bf16x8 b0 = *(const bf16x8*)(wp);
    bf16x8 b1 = *(const bf16x8*)(wp + 16 * Kd);
    bf16x8 b2 = *(const bf16x8*)(wp + 32 * Kd);
    bf16x8 b3 = *(const bf16x8*)(wp + 48 * Kd);
    acc0 = __builtin_amdgcn_mfma_f32_16x16x32_bf16(af, b0, acc0, 0, 0, 0);
    acc1 = __builtin_amdgcn_mfma_f32_16x16x32_bf16(af, b1, acc1, 0, 0, 0);
    acc2 = __builtin_amdgcn_mfma_f32_16x16x32_bf16(af, b2, acc2, 0, 0, 0);
    acc3 = __builtin_amdgcn_mfma_f32_16x16x32_bf16(af, b3, acc3, 0, 0, 0);
  }
  int crow = m0 + (l >> 4) * 4;
  int ccol = n0 + (l & 15);
  f32x4 accs[4] = {acc0, acc1, acc2, acc3};
#pragma unroll
  for (int n = 0; n < 4; ++n) {
    int col = ccol + n * 16;
    float bv = bias ? bias[col] : 0.f;
#pragma unroll
    for (int r = 0; r < 4; ++r) {
      int row = crow + r;
      if (row < M) {
        float v = accs[n][r] + bv;
        if (ACT == 1) v = fmaxf(v, 0.f);
        else if (ACT == 2) v = 1.f / (1.f + expf(-v));
        else if (ACT == 3) v = tanhf(v);
        if (BF16OUT)
          ((ushortT*)Cout)[(size_t)row * ldc + col] = f2b(v);
        else
          ((float*)Cout)[(size_t)row * ldc + col] = v;
      }
    }
  }
}

// ------- edge combine: raw[e] = relu(cA[a]+cB[b]+W1e·ef[e]) @ w2^T  (cAB bf16) ------
// 4 lanes per edge; lane q handles cols {c*32 + q*8 .. +8} for c=0..3 (bank-spread).
__global__ __launch_bounds__(256) void k_edge_combine(
    const ushortT* __restrict__ cAB, const float* __restrict__ ef,
    const int* __restrict__ idxA, const int* __restrict__ idxB,
    const float* __restrict__ w1e, const float* __restrict__ w2,
    float* __restrict__ raw) {
  __shared__ float w1e_s[8][128];
  __shared__ float w2_s[4][128];
  int t = threadIdx.x;
  for (int i = t; i < 1024; i += 256) w1e_s[i >> 7][i & 127] = w1e[i];
  for (int i = t; i < 512; i += 256) w2_s[i >> 7][i & 127] = w2[i];
  __syncthreads();
  int es = t >> 2, q = t & 3;
  int e = blockIdx.x * 64 + es;
  int a = idxA[e], b = idxB[e];
  const ushortT* cA = cAB + (size_t)a * 256;
  const ushortT* cB = cAB + (size_t)b * 256 + 128;
  const float4* efp = (const float4*)(ef + (size_t)e * EFDIM);
  float4 e0 = efp[0], e1 = efp[1];
  float efv[8] = {e0.x, e0.y, e0.z, e0.w, e1.x, e1.y, e1.z, e1.w};
  float p[4] = {0.f, 0.f, 0.f, 0.f};
#pragma unroll
  for (int c = 0; c < 4; ++c) {
    int j = c * 32 + q * 8;
    uint4 ua4 = *(const uint4*)(cA + j);
    uint4 ub4 = *(const uint4*)(cB + j);
    const uintT* au = (const uintT*)&ua4;
    const uintT* bu = (const uintT*)&ub4;
    float h[8];
#pragma unroll
    for (int i2 = 0; i2 < 4; ++i2) {
      h[2 * i2] = b2f_lo(au[i2]) + b2f_lo(bu[i2]);
      h[2 * i2 + 1] = b2f_hi(au[i2]) + b2f_hi(bu[i2]);
    }
#pragma unroll
    for (int f = 0; f < 8; ++f) {
      float ev = efv[f];
      float4 w0 = *(const float4*)(&w1e_s[f][j]);
      float4 w1v = *(const float4*)(&w1e_s[f][j + 4]);
      h[0] += ev * w0.x; h[1] += ev * w0.y; h[2] += ev * w0.z; h[3] += ev * w0.w;
      h[4] += ev * w1v.x; h[5] += ev * w1v.y; h[6] += ev * w1v.z; h[7] += ev * w1v.w;
    }
#pragma unroll
    for (int i2 = 0; i2 < 8; ++i2) h[i2] = fmaxf(h[i2], 0.f);
#pragma unroll
    for (int o = 0; o < 4; ++o) {
      float4 u0 = *(const float4*)(&w2_s[o][j]);
      float4 u1 = *(const float4*)(&w2_s[o][j + 4]);
      p[o] += h[0] * u0.x + h[1] * u0.y + h[2] * u0.z + h[3] * u0.w +
              h[4] * u1.x + h[5] * u1.y + h[6] * u1.z + h[7] * u1.w;
    }
  }
#pragma unroll
  for (int o = 0; o < 4; ++o) {
    p[o] += __shfl_xor(p[o], 1, 64);
    p[o] += __shfl_xor(p[o], 2, 64);
  }
  if (q == 0)
    *(float4*)(&raw[(size_t)e * 4]) = make_float4(p[0], p[1], p[2], p[3]);
}

// ---------------- segmented softmax over dest (wave per node) ----------------
__global__ __launch_bounds__(256) void k_segsoftmax(
    const float* __restrict__ raw, const int* __restrict__ rp,
    const int* __restrict__ eids, float* __restrict__ wout, int hop) {
  int node = blockIdx.x * 4 + (threadIdx.x >> 6);
  if (node >= NN) return;
  int lane = threadIdx.x & 63;
  int beg = rp[node], end = rp[node + 1];
  if (beg == end) return;
  int li = lane >> 2, o = lane & 3;
  float mx = -1e30f;
  for (int b = beg; b < end; b += 16) {
    int ii = b + li;
    if (ii < end) {
      float v = raw[(size_t)eids[ii] * 4 + o];
      v = (v > 0.f ? v : 0.01f * v) * 0.25f;  // leaky_relu / sqrt(HS=16)
      mx = fmaxf(mx, v);
    }
  }
#pragma unroll
  for (int m = 4; m <= 32; m <<= 1) mx = fmaxf(mx, __shfl_xor(mx, m, 64));
  float sum = 0.f;
  for (int b = beg; b < end; b += 16) {
    int ii = b + li;
    if (ii < end) {
      float v = raw[(size_t)eids[ii] * 4 + o];
      v = (v > 0.f ? v : 0.01f * v) * 0.25f;
      sum += expf(v - mx);
    }
  }
#pragma unroll
  for (int m = 4; m <= 32; m <<= 1) sum += __shfl_xor(sum, m, 64);
  float inv = 1.f / (sum + 1e-9f);
  for (int b = beg; b < end; b += 16) {
    int ii = b + li;
    if (ii < end) {
      int e = eids[ii];
      float v = raw[(size_t)e * 4 + o];
      v = (v > 0.f ? v : 0.01f * v) * 0.25f;
      wout[(size_t)e * (NHEAD * KHOP) + o * KHOP + hop] = expf(v - mx) * inv;
    }
  }
}

__global__ void k_sigmoid(const float* __restrict__ raw, float* __restrict__ wout,
                          int hop) {
  int g = blockIdx.x * 256 + threadIdx.x;
  if (g >= EE * NHEAD) return;
  int e = g >> 2, o = g & 3;
  float v = raw[g];
  wout[(size_t)e * (NHEAD * KHOP) + o * KHOP + hop] = 1.f / (1.f + expf(-v));
}

// ------------- aggregate + proj + residual (wave per node, lane = h) -------------
// hn_bf is nodecat_bf (stride KP; first 64 cols = normed h)
__global__ __launch_bounds__(256) void k_aggregate(
    const ushortT* __restrict__ hn_bf, const float* __restrict__ ws, int hop,
    const int* __restrict__ rp, const int* __restrict__ eids,
    const int* __restrict__ idxA, const float* __restrict__ proj,
    float* __restrict__ h) {
  __shared__ float proj_s[64][68];
  __shared__ float agg_s[4][64];
  int t = threadIdx.x;
  for (int i = t; i < 4096; i += 256) proj_s[i >> 6][i & 63] = proj[i];
  int wv = t >> 6, lane = t & 63;
  int node = blockIdx.x * 4 + wv;
  float acc = 0.f;
  if (node < NN) {
    int beg = rp[node], end = rp[node + 1];
    int hd = lane >> 4;
    for (int ii = beg; ii < end; ++ii) {
      int e = eids[ii];
      float w = ws[(size_t)e * (NHEAD * KHOP) + hd * KHOP + hop];
      acc += w * b2f(hn_bf[(size_t)idxA[e] * KP + lane]);
    }
  }
  agg_s[wv][lane] = acc;
  __syncthreads();
  if (node < NN) {
    float m = 0.f;
#pragma unroll
    for (int hh = 0; hh < 64; hh += 4) {
      float4 p = *(const float4*)(&proj_s[lane][hh]);
      m += p.x * agg_s[wv][hh] + p.y * agg_s[wv][hh + 1] +
           p.z * agg_s[wv][hh + 2] + p.w * agg_s[wv][hh + 3];
    }
    h[(size_t)node * HH + lane] += m;
  }
}

// ---------------- gating phase ----------------
__global__ void k_gatein(const float* __restrict__ x, const float* __restrict__ hf,
                         const float* __restrict__ hr, ushortT* __restrict__ gi) {
  int g = blockIdx.x * 256 + threadIdx.x;
  if (g >= NN * HH) return;
  int node = g >> 6, j = g & 63;
  float xv = x[g];
  gi[(size_t)node * GIN + j] = f2b(xv);
  gi[(size_t)node * GIN + 64 + j] = f2b(hf[g] - xv);
  gi[(size_t)node * GIN + 128 + j] = f2b(hr[g] - xv);
}

__global__ void k_candin(const float* __restrict__ x, const float* __restrict__ r,
                         ushortT* __restrict__ gi) {
  int g = blockIdx.x * 256 + threadIdx.x;
  if (g >= NN * HH) return;
  gi[(size_t)(g >> 6) * GIN + (g & 63)] = f2b(r[g] * x[g]);
}

__global__ void k_final(const float* __restrict__ x, const float* __restrict__ zv,
                        const float* __restrict__ cand, float* __restrict__ outF) {
  int g = blockIdx.x * 256 + threadIdx.x;
  if (g >= NN * HH) return;
  float z = zv[g];
  outF[g] = (1.f - z) * x[g] + z * cand[g];
}

extern "C" void kernel_launch(void* const* d_in, const int* in_sizes, int n_in,
                              void* d_out, int out_size, void* d_ws, size_t ws_size,
                              hipStream_t stream) {
  const float* x = (const float*)d_in[0];
  const float* xs = (const float*)d_in[1];
  const int* ei = (const int*)d_in[2];
  const float* ef = (const float*)d_in[3];
  const float* fw1 = (const float*)d_in[4];
  const float* fw2 = (const float*)d_in[5];
  const float* fpj = (const float*)d_in[6];
  const float* rw1 = (const float*)d_in[7];
  const float* rw2 = (const float*)d_in[8];
  const float* rpj = (const float*)d_in[9];
  const float* lnw = (const float*)d_in[10];
  const float* lnb = (const float*)d_in[11];
  const float* r_w1 = (const float*)d_in[12];
  const float* r_b1 = (const float*)d_in[13];
  const float* r_w2 = (const float*)d_in[14];
  const float* r_b2 = (const float*)d_in[15];
  const float* z_w1 = (const float*)d_in[16];
  const float* z_b1 = (const float*)d_in[17];
  const float* z_w2 = (const float*)d_in[18];
  const float* z_b2 = (const float*)d_in[19];
  const float* c_w1 = (const float*)d_in[20];
  const float* c_b1 = (const float*)d_in[21];
  const float* c_w2 = (const float*)d_in[22];
  const float* c_b2 = (const float*)d_in[23];
  const int* srcp = ei;
  const int* dstp = ei + EE;

  float* outF = (float*)d_out;
  float* outFW = outF + (size_t)NN * HH;
  float* outRW = outFW + (size_t)EE * NHEAD * KHOP;
  float* outZ = outRW + (size_t)EE * NHEAD * KHOP;
  float* outR = outZ + (size_t)NN * HH;

  char* Wb = (char*)d_ws;
  size_t off = 0;
  auto alloc = [&](size_t bytes) -> void* {
    void* p = Wb + off;
    off += (bytes + 255) & ~(size_t)255;
    return p;
  };
  float* h_fwd = (float*)alloc((size_t)NN * HH * 4);
  float* h_rev = (float*)alloc((size_t)NN * HH * 4);
  ushortT* nodecat_bf = (ushortT*)alloc((size_t)NN * KP * 2);
  float* raw = (float*)alloc((size_t)EE * NHEAD * 4);
  // big region: hop phase -> cAB_bf [NN][256] bf16 (12.8MB); gate -> hid_bf [NN][384] (19.2MB)
  char* big = (char*)alloc((size_t)NN * 384 * 2);
  ushortT* cAB_bf = (ushortT*)big;
  ushortT* hid_bf = (ushortT*)big;
  ushortT* gi_bf = (ushortT*)alloc((size_t)NN * GIN * 2);
  float* cand = (float*)alloc((size_t)NN * HH * 4);
  ushortT* packAB_bf = (ushortT*)alloc((size_t)4 * 256 * KP * 2);
  float* packE = (float*)alloc((size_t)4 * 8 * 128 * 4);
  ushortT* rzw1_bf = (ushortT*)alloc((size_t)384 * GIN * 2);
  ushortT* rw2_bf = (ushortT*)alloc((size_t)HH * GIN * 2);
  ushortT* zw2_bf = (ushortT*)alloc((size_t)HH * GIN * 2);
  ushortT* cw1_bf = (ushortT*)alloc((size_t)GIN * GIN * 2);
  ushortT* cw2_bf = (ushortT*)alloc((size_t)HH * GIN * 2);
  float* rz_b1 = (float*)alloc(384 * 4);
  int* rp_d = (int*)alloc((NN + 8) * 4);
  int* rp_s = (int*)alloc((NN + 8) * 4);
  int* cur = (int*)alloc((NN + 8) * 4);
  int* eid_d = (int*)alloc((size_t)EE * 4);
  int* eid_s = (int*)alloc((size_t)EE * 4);

  hipMemcpyAsync(h_fwd, x, (size_t)NN * HH * 4, hipMemcpyDeviceToDevice, stream);
  hipMemcpyAsync(h_rev, x, (size_t)NN * HH * 4, hipMemcpyDeviceToDevice, stream);
  hipMemcpyAsync(rz_b1, r_b1, GIN * 4, hipMemcpyDeviceToDevice, stream);
  hipMemcpyAsync(rz_b1 + GIN, z_b1, GIN * 4, hipMemcpyDeviceToDevice, stream);

  const int EB = (EE + 255) / 256, NB = (NN + 255) / 256, NW = (NN + 3) / 4;
  const int PB = (256 * KP + 8 * 128 + 255) / 256;

  // weight repacks -> bf16
  for (int k = 0; k < KHOP; ++k) {
    k_pack_bf<<<PB, 256, 0, stream>>>(fw1 + (size_t)k * WID * MIN,
                                      packAB_bf + (size_t)k * 256 * KP,
                                      packE + (size_t)k * 8 * 128);
    k_pack_bf<<<PB, 256, 0, stream>>>(rw1 + (size_t)k * WID * MIN,
                                      packAB_bf + (size_t)(2 + k) * 256 * KP,
                                      packE + (size_t)(2 + k) * 8 * 128);
  }
  k_cvt<<<(GIN * GIN + 255) / 256, 256, 0, stream>>>(r_w1, rzw1_bf, GIN * GIN);
  k_cvt<<<(GIN * GIN + 255) / 256, 256, 0, stream>>>(z_w1, rzw1_bf + GIN * GIN, GIN * GIN);
  k_cvt<<<(HH * GIN + 255) / 256, 256, 0, stream>>>(r_w2, rw2_bf, HH * GIN);
  k_cvt<<<(HH * GIN + 255) / 256, 256, 0, stream>>>(z_w2, zw2_bf, HH * GIN);
  k_cvt<<<(GIN * GIN + 255) / 256, 256, 0, stream>>>(c_w1, cw1_bf, GIN * GIN);
  k_cvt<<<(HH * GIN + 255) / 256, 256, 0, stream>>>(c_w2, cw2_bf, HH * GIN);

  // CSR by dest
  hipMemsetAsync(cur, 0, NN * 4, stream);
  k_histo<<<EB, 256, 0, stream>>>(dstp, cur);
  k_scan<<<1, 1024, 0, stream>>>(cur, rp_d);
  hipMemsetAsync(cur, 0, NN * 4, stream);
  k_scatter<<<EB, 256, 0, stream>>>(dstp, rp_d, cur, eid_d);
  k_sortseg<<<NB, 256, 0, stream>>>(rp_d, eid_d);
  // CSR by src
  hipMemsetAsync(cur, 0, NN * 4, stream);
  k_histo<<<EB, 256, 0, stream>>>(srcp, cur);
  k_scan<<<1, 1024, 0, stream>>>(cur, rp_s);
  hipMemsetAsync(cur, 0, NN * 4, stream);
  k_scatter<<<EB, 256, 0, stream>>>(srcp, rp_s, cur, eid_s);
  k_sortseg<<<NB, 256, 0, stream>>>(rp_s, eid_s);

  const int MB64 = (NN + 63) / 64;  // 391
  dim3 gProj(MB64, 4);              // [NN,96]@[256,96]^T -> [NN,256]
  for (int k = 0; k < KHOP; ++k) {
    k_ln<<<NW, 256, 0, stream>>>(h_fwd, xs, lnw, lnb, nodecat_bf);
    k_gemm_bf<0, 1><<<gProj, 256, 0, stream>>>(nodecat_bf, KP,
                                               packAB_bf + (size_t)k * 256 * KP,
                                               nullptr, cAB_bf, 256, NN, KP);
    k_edge_combine<<<EE / 64, 256, 0, stream>>>(cAB_bf, ef, srcp, dstp,
                                                packE + (size_t)k * 8 * 128,
                                                fw2 + (size_t)k * NHEAD * WID, raw);
    k_segsoftmax<<<NW, 256, 0, stream>>>(raw, rp_d, eid_d, outFW, k);
    k_aggregate<<<NW, 256, 0, stream>>>(nodecat_bf, outFW, k, rp_d, eid_d, srcp,
                                        fpj + (size_t)k * HH * HH, h_fwd);
  }
  for (int k = 0; k < KHOP; ++k) {
    k_ln<<<NW, 256, 0, stream>>>(h_rev, xs, lnw, lnb, nodecat_bf);
    k_gemm_bf<0, 1><<<gProj, 256, 0, stream>>>(nodecat_bf, KP,
                                               packAB_bf + (size_t)(2 + k) * 256 * KP,
                                               nullptr, cAB_bf, 256, NN, KP);
    k_edge_combine<<<EE / 64, 256, 0, stream>>>(cAB_bf, ef, dstp, srcp,
                                                packE + (size_t)(2 + k) * 8 * 128,
                                                rw2 + (size_t)k * NHEAD * WID, raw);
    k_sigmoid<<<(EE * NHEAD) / 256, 256, 0, stream>>>(raw, outRW, k);
    k_aggregate<<<NW, 256, 0, stream>>>(nodecat_bf, outRW, k, rp_s, eid_s, dstp,
                                        rpj + (size_t)k * HH * HH, h_rev);
  }

  // gating
  k_gatein<<<(NN * HH) / 256, 256, 0, stream>>>(x, h_fwd, h_rev, gi_bf);
  dim3 gRZ1(MB64, 6), gC1(MB64, 3), g2(MB64, 1);
  k_gemm_bf<1, 1><<<gRZ1, 256, 0, stream>>>(gi_bf, GIN, rzw1_bf, rz_b1, hid_bf, 384,
                                            NN, GIN);
  k_gemm_bf<2, 0><<<g2, 256, 0, stream>>>(hid_bf, 384, rw2_bf, r_b2, outR, HH, NN, GIN);
  k_gemm_bf<2, 0><<<g2, 256, 0, stream>>>(hid_bf + GIN, 384, zw2_bf, z_b2, outZ, HH,
                                          NN, GIN);
  k_candin<<<(NN * HH) / 256, 256, 0, stream>>>(x, outR, gi_bf);
  k_gemm_bf<1, 1><<<gC1, 256, 0, stream>>>(gi_bf, GIN, cw1_bf, c_b1, hid_bf, GIN, NN,
                                           GIN);
  k_gemm_bf<3, 0><<<g2, 256, 0, stream>>>(hid_bf, GIN, cw2_bf, c_b2, cand, HH, NN, GIN);
  k_final<<<(NN * HH) / 256, 256, 0, stream>>>(x, outZ, cand, outF);
}

// Round 5
// 797.013 us; speedup vs baseline: 6.2106x; 1.2981x over previous
//
#include <hip/hip_runtime.h>
#include <math.h>

#define NN 25000
#define EE 400000
#define HH 64
#define NHEAD 4
#define SDIM 16
#define EFDIM 8
#define KHOP 2
#define MIN 168   // 2H + 2S + EF
#define WID 128
#define GIN 192
#define KP 96     // padded K for node-proj GEMM (80 -> 96)

typedef __attribute__((ext_vector_type(8))) short bf16x8;
typedef __attribute__((ext_vector_type(4))) float f32x4;
typedef unsigned short ushortT;
typedef unsigned int uintT;

__device__ __forceinline__ float wave_sum64(float v) {
#pragma unroll
  for (int m = 1; m <= 32; m <<= 1) v += __shfl_xor(v, m, 64);
  return v;
}

__device__ __forceinline__ ushortT f2b(float f) {
  uintT u = __float_as_uint(f);
  return (ushortT)((u + 0x7FFFu + ((u >> 16) & 1u)) >> 16);
}
__device__ __forceinline__ float b2f(ushortT h) {
  return __uint_as_float(((uintT)h) << 16);
}
__device__ __forceinline__ float b2f_lo(uintT u) { return __uint_as_float(u << 16); }
__device__ __forceinline__ float b2f_hi(uintT u) { return __uint_as_float(u & 0xffff0000u); }

// ---------------- CSR build ----------------
__global__ void k_histo(const int* __restrict__ idx, int* __restrict__ cnt) {
  int e = blockIdx.x * 256 + threadIdx.x;
  if (e < EE) atomicAdd(&cnt[idx[e]], 1);
}

__global__ void k_scan(const int* __restrict__ cnt, int* __restrict__ rp) {
  __shared__ int part[1024];
  int t = threadIdx.x;
  const int CH = (NN + 1023) / 1024;
  int base = t * CH;
  int s = 0;
  for (int i = 0; i < CH; ++i) {
    int j = base + i;
    if (j < NN) s += cnt[j];
  }
  part[t] = s;
  __syncthreads();
  for (int off = 1; off < 1024; off <<= 1) {
    int v = (t >= off) ? part[t - off] : 0;
    __syncthreads();
    part[t] += v;
    __syncthreads();
  }
  int run = (t == 0) ? 0 : part[t - 1];
  for (int i = 0; i < CH; ++i) {
    int j = base + i;
    if (j < NN) { rp[j] = run; run += cnt[j]; }
  }
  if (t == 1023) rp[NN] = run;
}

__global__ void k_scatter(const int* __restrict__ idx, const int* __restrict__ rp,
                          int* __restrict__ cur, int* __restrict__ eids) {
  int e = blockIdx.x * 256 + threadIdx.x;
  if (e < EE) {
    int n = idx[e];
    int p = atomicAdd(&cur[n], 1);
    eids[rp[n] + p] = e;
  }
}

__global__ void k_sortseg(const int* __restrict__ rp, int* __restrict__ eids) {
  int node = blockIdx.x * 256 + threadIdx.x;
  if (node >= NN) return;
  int b = rp[node], e = rp[node + 1];
  for (int i = b + 1; i < e; ++i) {
    int v = eids[i];
    int j = i - 1;
    while (j >= b && eids[j] > v) { eids[j + 1] = eids[j]; --j; }
    eids[j + 1] = v;
  }
}

// pair[ii] = {e, other_endpoint[e]} — removes one dependent-load level in aggregate
__global__ void k_mkpair(const int* __restrict__ eids, const int* __restrict__ other,
                         int2* __restrict__ pair) {
  int i = blockIdx.x * 256 + threadIdx.x;
  if (i < EE) {
    int e = eids[i];
    pair[i] = make_int2(e, other[e]);
  }
}

// ------------- weight repack: w1[128][168] -> pAB_bf[256][96], pE[8][128] -------------
__global__ void k_pack_bf(const float* __restrict__ w1, ushortT* __restrict__ pAB,
                          float* __restrict__ pE) {
  int i = blockIdx.x * 256 + threadIdx.x;
  if (i < 256 * KP) {
    int j = i / KP, k = i % KP;
    float v = 0.f;
    if (k < 80) {
      int row = (j < 128) ? j : j - 128;
      int col = (j < 128) ? (k < 64 ? k : k + 64) : (k < 64 ? k + 64 : k + 80);
      v = w1[row * MIN + col];
    }
    pAB[i] = f2b(v);
  } else if (i < 256 * KP + 8 * 128) {
    int ii = i - 256 * KP;
    int f = ii >> 7, j = ii & 127;
    pE[ii] = w1[j * MIN + 160 + f];
  }
}

__global__ void k_cvt(const float* __restrict__ src, ushortT* __restrict__ dst, int n) {
  int i = blockIdx.x * 256 + threadIdx.x;
  if (i < n) dst[i] = f2b(src[i]);
}

// ---------------- LayerNorm + concat xs -> nodecat_bf[N][96] (cols 80..95 = 0) ------
__global__ __launch_bounds__(256) void k_ln(const float* __restrict__ h,
                                            const float* __restrict__ xs,
                                            const float* __restrict__ lw,
                                            const float* __restrict__ lb,
                                            ushortT* __restrict__ nodecat) {
  int t = threadIdx.x;
  int node = blockIdx.x * 4 + (t >> 6), lane = t & 63;
  if (node >= NN) return;
  float v = h[(size_t)node * HH + lane];
  float mean = wave_sum64(v) * (1.0f / 64.0f);
  float d = v - mean;
  float var = wave_sum64(d * d) * (1.0f / 64.0f);
  nodecat[(size_t)node * KP + lane] = f2b(d * rsqrtf(var + 1e-5f) * lw[lane] + lb[lane]);
  if (lane < SDIM) {
    nodecat[(size_t)node * KP + HH + lane] = f2b(xs[(size_t)node * SDIM + lane]);
    nodecat[(size_t)node * KP + 80 + lane] = 0;
  }
}

// ---------------- MFMA bf16 GEMM: C[M,*] = act(A[M,K]@W[N,K]^T + bias) --------------
template <int ACT, int BF16OUT>
__global__ __launch_bounds__(256) void k_gemm_bf(
    const ushortT* __restrict__ A, int lda, const ushortT* __restrict__ W,
    const float* __restrict__ bias, void* __restrict__ Cout, int ldc, int M, int Kd) {
  int w = threadIdx.x >> 6, l = threadIdx.x & 63;
  int m0 = blockIdx.x * 64 + w * 16;
  int n0 = blockIdx.y * 64;
  int rowa = m0 + (l & 15);
  int kb = l >> 4;
  f32x4 acc0 = {0.f, 0.f, 0.f, 0.f}, acc1 = acc0, acc2 = acc0, acc3 = acc0;
  for (int k0 = 0; k0 < Kd; k0 += 32) {
    bf16x8 af = {0, 0, 0, 0, 0, 0, 0, 0};
    if (rowa < M) af = *(const bf16x8*)(A + (size_t)rowa * lda + k0 + kb * 8);
    const ushortT* wp = W + (size_t)(n0 + (l & 15)) * Kd + k0 + kb * 8;
    bf16x8 b0 = *(const bf16x8*)(wp);
    bf16x8 b1 = *(const bf16x8*)(wp + 16 * Kd);
    bf16x8 b2 = *(const bf16x8*)(wp + 32 * Kd);
    bf16x8 b3 = *(const bf16x8*)(wp + 48 * Kd);
    acc0 = __builtin_amdgcn_mfma_f32_16x16x32_bf16(af, b0, acc0, 0, 0, 0);
    acc1 = __builtin_amdgcn_mfma_f32_16x16x32_bf16(af, b1, acc1, 0, 0, 0);
    acc2 = __builtin_amdgcn_mfma_f32_16x16x32_bf16(af, b2, acc2, 0, 0, 0);
    acc3 = __builtin_amdgcn_mfma_f32_16x16x32_bf16(af, b3, acc3, 0, 0, 0);
  }
  int crow = m0 + (l >> 4) * 4;
  int ccol = n0 + (l & 15);
  f32x4 accs[4] = {acc0, acc1, acc2, acc3};
#pragma unroll
  for (int n = 0; n < 4; ++n) {
    int col = ccol + n * 16;
    float bv = bias ? bias[col] : 0.f;
#pragma unroll
    for (int r = 0; r < 4; ++r) {
      int row = crow + r;
      if (row < M) {
        float v = accs[n][r] + bv;
        if (ACT == 1) v = fmaxf(v, 0.f);
        else if (ACT == 2) v = 1.f / (1.f + expf(-v));
        else if (ACT == 3) v = tanhf(v);
        if (BF16OUT)
          ((ushortT*)Cout)[(size_t)row * ldc + col] = f2b(v);
        else
          ((float*)Cout)[(size_t)row * ldc + col] = v;
      }
    }
  }
}

// ------- edge combine: hidden = relu(cA[a]+cB[b]+W1e·ef[e]); p = hidden @ w2^T ------
// GATED=0: write transformed score s=leaky(p)/4 to outp[e*4+q]
// GATED=1: write sigmoid(p) directly to wout[e*8 + q*2 + hop]
template <int GATED>
__global__ __launch_bounds__(256) void k_edge_combine(
    const ushortT* __restrict__ cAB, const float* __restrict__ ef,
    const int* __restrict__ idxA, const int* __restrict__ idxB,
    const float* __restrict__ w1e, const float* __restrict__ w2,
    float* __restrict__ outp, int hop) {
  __shared__ float w1e_s[8][128];
  __shared__ float w2_s[4][128];
  int t = threadIdx.x;
  for (int i = t; i < 1024; i += 256) w1e_s[i >> 7][i & 127] = w1e[i];
  for (int i = t; i < 512; i += 256) w2_s[i >> 7][i & 127] = w2[i];
  __syncthreads();
  int es = t >> 2, q = t & 3;
  int e = blockIdx.x * 64 + es;
  int a = idxA[e], b = idxB[e];
  const ushortT* cA = cAB + (size_t)a * 256;
  const ushortT* cB = cAB + (size_t)b * 256 + 128;
  const float4* efp = (const float4*)(ef + (size_t)e * EFDIM);
  float4 e0 = efp[0], e1 = efp[1];
  float efv[8] = {e0.x, e0.y, e0.z, e0.w, e1.x, e1.y, e1.z, e1.w};
  float p[4] = {0.f, 0.f, 0.f, 0.f};
#pragma unroll
  for (int c = 0; c < 4; ++c) {
    int j = c * 32 + q * 8;
    uint4 ua4 = *(const uint4*)(cA + j);
    uint4 ub4 = *(const uint4*)(cB + j);
    const uintT* au = (const uintT*)&ua4;
    const uintT* bu = (const uintT*)&ub4;
    float h[8];
#pragma unroll
    for (int i2 = 0; i2 < 4; ++i2) {
      h[2 * i2] = b2f_lo(au[i2]) + b2f_lo(bu[i2]);
      h[2 * i2 + 1] = b2f_hi(au[i2]) + b2f_hi(bu[i2]);
    }
#pragma unroll
    for (int f = 0; f < 8; ++f) {
      float ev = efv[f];
      float4 w0 = *(const float4*)(&w1e_s[f][j]);
      float4 w1v = *(const float4*)(&w1e_s[f][j + 4]);
      h[0] += ev * w0.x; h[1] += ev * w0.y; h[2] += ev * w0.z; h[3] += ev * w0.w;
      h[4] += ev * w1v.x; h[5] += ev * w1v.y; h[6] += ev * w1v.z; h[7] += ev * w1v.w;
    }
#pragma unroll
    for (int i2 = 0; i2 < 8; ++i2) h[i2] = fmaxf(h[i2], 0.f);
#pragma unroll
    for (int o = 0; o < 4; ++o) {
      float4 u0 = *(const float4*)(&w2_s[o][j]);
      float4 u1 = *(const float4*)(&w2_s[o][j + 4]);
      p[o] += h[0] * u0.x + h[1] * u0.y + h[2] * u0.z + h[3] * u0.w +
              h[4] * u1.x + h[5] * u1.y + h[6] * u1.z + h[7] * u1.w;
    }
  }
#pragma unroll
  for (int o = 0; o < 4; ++o) {
    p[o] += __shfl_xor(p[o], 1, 64);
    p[o] += __shfl_xor(p[o], 2, 64);
  }
  float pv = (q == 0) ? p[0] : (q == 1) ? p[1] : (q == 2) ? p[2] : p[3];
  if (GATED) {
    outp[(size_t)e * (NHEAD * KHOP) + q * KHOP + hop] = 1.f / (1.f + expf(-pv));
  } else {
    outp[(size_t)e * 4 + q] = (pv > 0.f ? pv : 0.01f * pv) * 0.25f;
  }
}

// ---------------- segmented softmax over dest (wave per node) ----------------
// s holds PRE-TRANSFORMED scores (leaky/sqrt applied in edge_combine)
__global__ __launch_bounds__(256) void k_segsoftmax(
    const float* __restrict__ s, const int* __restrict__ rp,
    const int* __restrict__ eids, float* __restrict__ wout, int hop) {
  int node = blockIdx.x * 4 + (threadIdx.x >> 6);
  if (node >= NN) return;
  int lane = threadIdx.x & 63;
  int beg = rp[node], end = rp[node + 1];
  if (beg == end) return;
  int li = lane >> 2, o = lane & 3;
  int deg = end - beg;
  if (deg <= 64) {
    // one global read per edge: cache score+eid in registers (4 slots, unrolled)
    int ee[4];
    float sv[4];
    int i0 = beg + li;
#pragma unroll
    for (int u = 0; u < 4; ++u) {
      int idx = i0 + u * 16;
      bool val = idx < end;
      int id2 = val ? idx : beg;
      int e = eids[id2];
      float v = s[(size_t)e * 4 + o];
      ee[u] = e;
      sv[u] = val ? v : -1e30f;
    }
    float mx = fmaxf(fmaxf(sv[0], sv[1]), fmaxf(sv[2], sv[3]));
#pragma unroll
    for (int m = 4; m <= 32; m <<= 1) mx = fmaxf(mx, __shfl_xor(mx, m, 64));
    float ex[4];
    float sum = 0.f;
#pragma unroll
    for (int u = 0; u < 4; ++u) {
      ex[u] = (sv[u] > -1e29f) ? expf(sv[u] - mx) : 0.f;
      sum += ex[u];
    }
#pragma unroll
    for (int m = 4; m <= 32; m <<= 1) sum += __shfl_xor(sum, m, 64);
    float inv = 1.f / (sum + 1e-9f);
#pragma unroll
    for (int u = 0; u < 4; ++u) {
      if (i0 + u * 16 < end)
        wout[(size_t)ee[u] * (NHEAD * KHOP) + o * KHOP + hop] = ex[u] * inv;
    }
  } else {
    float mx = -1e30f;
    for (int ii = beg + li; ii < end; ii += 16)
      mx = fmaxf(mx, s[(size_t)eids[ii] * 4 + o]);
#pragma unroll
    for (int m = 4; m <= 32; m <<= 1) mx = fmaxf(mx, __shfl_xor(mx, m, 64));
    float sum = 0.f;
    for (int ii = beg + li; ii < end; ii += 16)
      sum += expf(s[(size_t)eids[ii] * 4 + o] - mx);
#pragma unroll
    for (int m = 4; m <= 32; m <<= 1) sum += __shfl_xor(sum, m, 64);
    float inv = 1.f / (sum + 1e-9f);
    for (int ii = beg + li; ii < end; ii += 16) {
      int e = eids[ii];
      wout[(size_t)e * (NHEAD * KHOP) + o * KHOP + hop] =
          expf(s[(size_t)e * 4 + o] - mx) * inv;
    }
  }
}

// ------------- aggregate + proj + residual (wave per node, lane = h) -------------
// 8-wide branchless unroll: all gathers issued before use (MLP=8)
__global__ __launch_bounds__(256) void k_aggregate(
    const ushortT* __restrict__ hn_bf, const float* __restrict__ ws, int hop,
    const int* __restrict__ rp, const int2* __restrict__ pair,
    const float* __restrict__ proj, float* __restrict__ h) {
  __shared__ float proj_s[64][68];
  __shared__ float agg_s[4][64];
  int t = threadIdx.x;
  for (int i = t; i < 4096; i += 256) proj_s[i >> 6][i & 63] = proj[i];
  int wv = t >> 6, lane = t & 63;
  int node = blockIdx.x * 4 + wv;
  float acc = 0.f;
  if (node < NN) {
    int beg = rp[node], end = rp[node + 1];
    int hd2 = (lane >> 4) * KHOP + hop;
    for (int ii = beg; ii < end; ii += 8) {
      int idxv[8];
      int2 pr[8];
      float wv8[8];
      float hv[8];
#pragma unroll
      for (int u = 0; u < 8; ++u) {
        int idx = ii + u;
        idxv[u] = (idx < end) ? idx : beg;
      }
#pragma unroll
      for (int u = 0; u < 8; ++u) pr[u] = pair[idxv[u]];
#pragma unroll
      for (int u = 0; u < 8; ++u)
        wv8[u] = ws[(size_t)pr[u].x * (NHEAD * KHOP) + hd2];
#pragma unroll
      for (int u = 0; u < 8; ++u)
        hv[u] = b2f(hn_bf[(size_t)pr[u].y * KP + lane]);
#pragma unroll
      for (int u = 0; u < 8; ++u) {
        float w = (ii + u < end) ? wv8[u] : 0.f;
        acc += w * hv[u];
      }
    }
  }
  agg_s[wv][lane] = acc;
  __syncthreads();
  if (node < NN) {
    float m = 0.f;
#pragma unroll
    for (int hh = 0; hh < 64; hh += 4) {
      float4 p = *(const float4*)(&proj_s[lane][hh]);
      m += p.x * agg_s[wv][hh] + p.y * agg_s[wv][hh + 1] +
           p.z * agg_s[wv][hh + 2] + p.w * agg_s[wv][hh + 3];
    }
    h[(size_t)node * HH + lane] += m;
  }
}

// ---------------- gating phase ----------------
__global__ void k_gatein(const float* __restrict__ x, const float* __restrict__ hf,
                         const float* __restrict__ hr, ushortT* __restrict__ gi) {
  int g = blockIdx.x * 256 + threadIdx.x;
  if (g >= NN * HH) return;
  int node = g >> 6, j = g & 63;
  float xv = x[g];
  gi[(size_t)node * GIN + j] = f2b(xv);
  gi[(size_t)node * GIN + 64 + j] = f2b(hf[g] - xv);
  gi[(size_t)node * GIN + 128 + j] = f2b(hr[g] - xv);
}

__global__ void k_candin(const float* __restrict__ x, const float* __restrict__ r,
                         ushortT* __restrict__ gi) {
  int g = blockIdx.x * 256 + threadIdx.x;
  if (g >= NN * HH) return;
  gi[(size_t)(g >> 6) * GIN + (g & 63)] = f2b(r[g] * x[g]);
}

__global__ void k_final(const float* __restrict__ x, const float* __restrict__ zv,
                        const float* __restrict__ cand, float* __restrict__ outF) {
  int g = blockIdx.x * 256 + threadIdx.x;
  if (g >= NN * HH) return;
  float z = zv[g];
  outF[g] = (1.f - z) * x[g] + z * cand[g];
}

extern "C" void kernel_launch(void* const* d_in, const int* in_sizes, int n_in,
                              void* d_out, int out_size, void* d_ws, size_t ws_size,
                              hipStream_t stream) {
  const float* x = (const float*)d_in[0];
  const float* xs = (const float*)d_in[1];
  const int* ei = (const int*)d_in[2];
  const float* ef = (const float*)d_in[3];
  const float* fw1 = (const float*)d_in[4];
  const float* fw2 = (const float*)d_in[5];
  const float* fpj = (const float*)d_in[6];
  const float* rw1 = (const float*)d_in[7];
  const float* rw2 = (const float*)d_in[8];
  const float* rpj = (const float*)d_in[9];
  const float* lnw = (const float*)d_in[10];
  const float* lnb = (const float*)d_in[11];
  const float* r_w1 = (const float*)d_in[12];
  const float* r_b1 = (const float*)d_in[13];
  const float* r_w2 = (const float*)d_in[14];
  const float* r_b2 = (const float*)d_in[15];
  const float* z_w1 = (const float*)d_in[16];
  const float* z_b1 = (const float*)d_in[17];
  const float* z_w2 = (const float*)d_in[18];
  const float* z_b2 = (const float*)d_in[19];
  const float* c_w1 = (const float*)d_in[20];
  const float* c_b1 = (const float*)d_in[21];
  const float* c_w2 = (const float*)d_in[22];
  const float* c_b2 = (const float*)d_in[23];
  const int* srcp = ei;
  const int* dstp = ei + EE;

  float* outF = (float*)d_out;
  float* outFW = outF + (size_t)NN * HH;
  float* outRW = outFW + (size_t)EE * NHEAD * KHOP;
  float* outZ = outRW + (size_t)EE * NHEAD * KHOP;
  float* outR = outZ + (size_t)NN * HH;

  char* Wb = (char*)d_ws;
  size_t off = 0;
  auto alloc = [&](size_t bytes) -> void* {
    void* p = Wb + off;
    off += (bytes + 255) & ~(size_t)255;
    return p;
  };
  float* h_fwd = (float*)alloc((size_t)NN * HH * 4);
  float* h_rev = (float*)alloc((size_t)NN * HH * 4);
  ushortT* nodecat_bf = (ushortT*)alloc((size_t)NN * KP * 2);
  float* raw = (float*)alloc((size_t)EE * NHEAD * 4);
  char* big = (char*)alloc((size_t)NN * 384 * 2);
  ushortT* cAB_bf = (ushortT*)big;
  ushortT* hid_bf = (ushortT*)big;
  ushortT* gi_bf = (ushortT*)alloc((size_t)NN * GIN * 2);
  float* cand = (float*)alloc((size_t)NN * HH * 4);
  ushortT* packAB_bf = (ushortT*)alloc((size_t)4 * 256 * KP * 2);
  float* packE = (float*)alloc((size_t)4 * 8 * 128 * 4);
  ushortT* rzw1_bf = (ushortT*)alloc((size_t)384 * GIN * 2);
  ushortT* rw2_bf = (ushortT*)alloc((size_t)HH * GIN * 2);
  ushortT* zw2_bf = (ushortT*)alloc((size_t)HH * GIN * 2);
  ushortT* cw1_bf = (ushortT*)alloc((size_t)GIN * GIN * 2);
  ushortT* cw2_bf = (ushortT*)alloc((size_t)HH * GIN * 2);
  float* rz_b1 = (float*)alloc(384 * 4);
  int* rp_d = (int*)alloc((NN + 8) * 4);
  int* rp_s = (int*)alloc((NN + 8) * 4);
  int* cur = (int*)alloc((NN + 8) * 4);
  int* eid_d = (int*)alloc((size_t)EE * 4);
  int* eid_s = (int*)alloc((size_t)EE * 4);
  int2* pair_d = (int2*)alloc((size_t)EE * 8);
  int2* pair_s = (int2*)alloc((size_t)EE * 8);

  hipMemcpyAsync(h_fwd, x, (size_t)NN * HH * 4, hipMemcpyDeviceToDevice, stream);
  hipMemcpyAsync(h_rev, x, (size_t)NN * HH * 4, hipMemcpyDeviceToDevice, stream);
  hipMemcpyAsync(rz_b1, r_b1, GIN * 4, hipMemcpyDeviceToDevice, stream);
  hipMemcpyAsync(rz_b1 + GIN, z_b1, GIN * 4, hipMemcpyDeviceToDevice, stream);

  const int EB = (EE + 255) / 256, NB = (NN + 255) / 256, NW = (NN + 3) / 4;
  const int PB = (256 * KP + 8 * 128 + 255) / 256;

  // weight repacks -> bf16
  for (int k = 0; k < KHOP; ++k) {
    k_pack_bf<<<PB, 256, 0, stream>>>(fw1 + (size_t)k * WID * MIN,
                                      packAB_bf + (size_t)k * 256 * KP,
                                      packE + (size_t)k * 8 * 128);
    k_pack_bf<<<PB, 256, 0, stream>>>(rw1 + (size_t)k * WID * MIN,
                                      packAB_bf + (size_t)(2 + k) * 256 * KP,
                                      packE + (size_t)(2 + k) * 8 * 128);
  }
  k_cvt<<<(GIN * GIN + 255) / 256, 256, 0, stream>>>(r_w1, rzw1_bf, GIN * GIN);
  k_cvt<<<(GIN * GIN + 255) / 256, 256, 0, stream>>>(z_w1, rzw1_bf + GIN * GIN, GIN * GIN);
  k_cvt<<<(HH * GIN + 255) / 256, 256, 0, stream>>>(r_w2, rw2_bf, HH * GIN);
  k_cvt<<<(HH * GIN + 255) / 256, 256, 0, stream>>>(z_w2, zw2_bf, HH * GIN);
  k_cvt<<<(GIN * GIN + 255) / 256, 256, 0, stream>>>(c_w1, cw1_bf, GIN * GIN);
  k_cvt<<<(HH * GIN + 255) / 256, 256, 0, stream>>>(c_w2, cw2_bf, HH * GIN);

  // CSR by dest
  hipMemsetAsync(cur, 0, NN * 4, stream);
  k_histo<<<EB, 256, 0, stream>>>(dstp, cur);
  k_scan<<<1, 1024, 0, stream>>>(cur, rp_d);
  hipMemsetAsync(cur, 0, NN * 4, stream);
  k_scatter<<<EB, 256, 0, stream>>>(dstp, rp_d, cur, eid_d);
  k_sortseg<<<NB, 256, 0, stream>>>(rp_d, eid_d);
  k_mkpair<<<EB, 256, 0, stream>>>(eid_d, srcp, pair_d);
  // CSR by src
  hipMemsetAsync(cur, 0, NN * 4, stream);
  k_histo<<<EB, 256, 0, stream>>>(srcp, cur);
  k_scan<<<1, 1024, 0, stream>>>(cur, rp_s);
  hipMemsetAsync(cur, 0, NN * 4, stream);
  k_scatter<<<EB, 256, 0, stream>>>(srcp, rp_s, cur, eid_s);
  k_sortseg<<<NB, 256, 0, stream>>>(rp_s, eid_s);
  k_mkpair<<<EB, 256, 0, stream>>>(eid_s, dstp, pair_s);

  const int MB64 = (NN + 63) / 64;  // 391
  dim3 gProj(MB64, 4);              // [NN,96]@[256,96]^T -> [NN,256]
  for (int k = 0; k < KHOP; ++k) {
    k_ln<<<NW, 256, 0, stream>>>(h_fwd, xs, lnw, lnb, nodecat_bf);
    k_gemm_bf<0, 1><<<gProj, 256, 0, stream>>>(nodecat_bf, KP,
                                               packAB_bf + (size_t)k * 256 * KP,
                                               nullptr, cAB_bf, 256, NN, KP);
    k_edge_combine<0><<<EE / 64, 256, 0, stream>>>(
        cAB_bf, ef, srcp, dstp, packE + (size_t)k * 8 * 128,
        fw2 + (size_t)k * NHEAD * WID, raw, 0);
    k_segsoftmax<<<NW, 256, 0, stream>>>(raw, rp_d, eid_d, outFW, k);
    k_aggregate<<<NW, 256, 0, stream>>>(nodecat_bf, outFW, k, rp_d, pair_d,
                                        fpj + (size_t)k * HH * HH, h_fwd);
  }
  for (int k = 0; k < KHOP; ++k) {
    k_ln<<<NW, 256, 0, stream>>>(h_rev, xs, lnw, lnb, nodecat_bf);
    k_gemm_bf<0, 1><<<gProj, 256, 0, stream>>>(nodecat_bf, KP,
                                               packAB_bf + (size_t)(2 + k) * 256 * KP,
                                               nullptr, cAB_bf, 256, NN, KP);
    k_edge_combine<1><<<EE / 64, 256, 0, stream>>>(
        cAB_bf, ef, dstp, srcp, packE + (size_t)(2 + k) * 8 * 128,
        rw2 + (size_t)k * NHEAD * WID, outRW, k);
    k_aggregate<<<NW, 256, 0, stream>>>(nodecat_bf, outRW, k, rp_s, pair_s,
                                        rpj + (size_t)k * HH * HH, h_rev);
  }

  // gating
  k_gatein<<<(NN * HH) / 256, 256, 0, stream>>>(x, h_fwd, h_rev, gi_bf);
  dim3 gRZ1(MB64, 6), gC1(MB64, 3), g2(MB64, 1);
  k_gemm_bf<1, 1><<<gRZ1, 256, 0, stream>>>(gi_bf, GIN, rzw1_bf, rz_b1, hid_bf, 384,
                                            NN, GIN);
  k_gemm_bf<2, 0><<<g2, 256, 0, stream>>>(hid_bf, 384, rw2_bf, r_b2, outR, HH, NN, GIN);
  k_gemm_bf<2, 0><<<g2, 256, 0, stream>>>(hid_bf + GIN, 384, zw2_bf, z_b2, outZ, HH,
                                          NN, GIN);
  k_candin<<<(NN * HH) / 256, 256, 0, stream>>>(x, outR, gi_bf);
  k_gemm_bf<1, 1><<<gC1, 256, 0, stream>>>(gi_bf, GIN, cw1_bf, c_b1, hid_bf, GIN, NN,
                                           GIN);
  k_gemm_bf<3, 0><<<g2, 256, 0, stream>>>(hid_bf, GIN, cw2_bf, c_b2, cand, HH, NN, GIN);
  k_final<<<(NN * HH) / 256, 256, 0, stream>>>(x, outZ, cand, outF);
}

// Round 6
// 651.203 us; speedup vs baseline: 7.6012x; 1.2239x over previous
//
#include <hip/hip_runtime.h>
#include <math.h>

#define NN 25000
#define EE 400000
#define HH 64
#define NHEAD 4
#define SDIM 16
#define EFDIM 8
#define KHOP 2
#define MIN 168   // 2H + 2S + EF
#define WID 128
#define GIN 192
#define KP 96     // padded K for node-proj GEMM (80 -> 96)

typedef __attribute__((ext_vector_type(8))) short bf16x8;
typedef __attribute__((ext_vector_type(4))) float f32x4;
typedef unsigned short ushortT;
typedef unsigned int uintT;

__device__ __forceinline__ float wave_sum64(float v) {
#pragma unroll
  for (int m = 1; m <= 32; m <<= 1) v += __shfl_xor(v, m, 64);
  return v;
}

__device__ __forceinline__ ushortT f2b(float f) {
  uintT u = __float_as_uint(f);
  return (ushortT)((u + 0x7FFFu + ((u >> 16) & 1u)) >> 16);
}
__device__ __forceinline__ float b2f(ushortT h) {
  return __uint_as_float(((uintT)h) << 16);
}
__device__ __forceinline__ float b2f_lo(uintT u) { return __uint_as_float(u << 16); }
__device__ __forceinline__ float b2f_hi(uintT u) { return __uint_as_float(u & 0xffff0000u); }

// ---------------- CSR build (both directions in one pass) ----------------
__global__ void k_histo2(const int* __restrict__ src, const int* __restrict__ dst,
                         int* __restrict__ cnt_s, int* __restrict__ cnt_d) {
  int e = blockIdx.x * 256 + threadIdx.x;
  if (e < EE) {
    atomicAdd(&cnt_d[dst[e]], 1);
    atomicAdd(&cnt_s[src[e]], 1);
  }
}

__global__ void k_scan2(const int* __restrict__ cnt_d, const int* __restrict__ cnt_s,
                        int* __restrict__ rp_d, int* __restrict__ rp_s) {
  const int* cnt = blockIdx.x ? cnt_s : cnt_d;
  int* rp = blockIdx.x ? rp_s : rp_d;
  __shared__ int part[1024];
  int t = threadIdx.x;
  const int CH = (NN + 1023) / 1024;
  int base = t * CH;
  int s = 0;
  for (int i = 0; i < CH; ++i) {
    int j = base + i;
    if (j < NN) s += cnt[j];
  }
  part[t] = s;
  __syncthreads();
  for (int off = 1; off < 1024; off <<= 1) {
    int v = (t >= off) ? part[t - off] : 0;
    __syncthreads();
    part[t] += v;
    __syncthreads();
  }
  int run = (t == 0) ? 0 : part[t - 1];
  for (int i = 0; i < CH; ++i) {
    int j = base + i;
    if (j < NN) { rp[j] = run; run += cnt[j]; }
  }
  if (t == 1023) rp[NN] = run;
}

__global__ void k_scatter2(const int* __restrict__ src, const int* __restrict__ dst,
                           const int* __restrict__ rp_s, const int* __restrict__ rp_d,
                           int* __restrict__ cur_s, int* __restrict__ cur_d,
                           int* __restrict__ eid_s, int* __restrict__ eid_d) {
  int e = blockIdx.x * 256 + threadIdx.x;
  if (e < EE) {
    int nd = dst[e];
    int pd = atomicAdd(&cur_d[nd], 1);
    eid_d[rp_d[nd] + pd] = e;
    int ns = src[e];
    int ps = atomicAdd(&cur_s[ns], 1);
    eid_s[rp_s[ns] + ps] = e;
  }
}

// wave-parallel bitonic sort of each segment (deterministic ascending order)
__global__ __launch_bounds__(256) void k_sortseg2(const int* __restrict__ rp_d,
                                                  const int* __restrict__ rp_s,
                                                  int* __restrict__ eid_d,
                                                  int* __restrict__ eid_s) {
  int gw = blockIdx.x * 4 + (threadIdx.x >> 6);
  int lane = threadIdx.x & 63;
  if (gw >= 2 * NN) return;
  const int* rp = (gw < NN) ? rp_d : rp_s;
  int* eids = (gw < NN) ? eid_d : eid_s;
  int node = (gw < NN) ? gw : gw - NN;
  int beg = rp[node], end = rp[node + 1];
  int deg = end - beg;
  if (deg <= 1) return;
  if (deg <= 64) {
    int v = (lane < deg) ? eids[beg + lane] : 0x7fffffff;
#pragma unroll
    for (int k = 2; k <= 64; k <<= 1) {
#pragma unroll
      for (int j = k >> 1; j > 0; j >>= 1) {
        int other = __shfl_xor(v, j, 64);
        bool takeMin = (((lane & k) == 0) == ((lane & j) == 0));
        v = takeMin ? min(v, other) : max(v, other);
      }
    }
    if (lane < deg) eids[beg + lane] = v;
  } else if (lane == 0) {
    for (int i = beg + 1; i < end; ++i) {
      int v = eids[i];
      int j = i - 1;
      while (j >= beg && eids[j] > v) { eids[j + 1] = eids[j]; --j; }
      eids[j + 1] = v;
    }
  }
}

// pair[ii] = {e, other_endpoint[e]} for both CSRs
__global__ void k_mkpair2(const int* __restrict__ eid_d, const int* __restrict__ eid_s,
                          const int* __restrict__ src, const int* __restrict__ dst,
                          int2* __restrict__ pair_d, int2* __restrict__ pair_s) {
  int i = blockIdx.x * 256 + threadIdx.x;
  if (i < EE) {
    int e1 = eid_d[i];
    pair_d[i] = make_int2(e1, src[e1]);
    int e2 = eid_s[i];
    pair_s[i] = make_int2(e2, dst[e2]);
  }
}

// ------------- weight repack: w1[128][168] -> pAB_bf[256][96], pE[8][128] -------------
// blockIdx.y = hop slot (0,1 = fwd k ; 2,3 = rev k)
__global__ void k_pack_bf(const float* __restrict__ fw1, const float* __restrict__ rw1,
                          ushortT* __restrict__ pAB_all, float* __restrict__ pE_all) {
  int y = blockIdx.y;
  const float* w1 = (y < 2) ? fw1 + (size_t)y * WID * MIN
                            : rw1 + (size_t)(y - 2) * WID * MIN;
  ushortT* pAB = pAB_all + (size_t)y * 256 * KP;
  float* pE = pE_all + (size_t)y * 8 * 128;
  int i = blockIdx.x * 256 + threadIdx.x;
  if (i < 256 * KP) {
    int j = i / KP, k = i % KP;
    float v = 0.f;
    if (k < 80) {
      int row = (j < 128) ? j : j - 128;
      int col = (j < 128) ? (k < 64 ? k : k + 64) : (k < 64 ? k + 64 : k + 80);
      v = w1[row * MIN + col];
    }
    pAB[i] = f2b(v);
  } else if (i < 256 * KP + 8 * 128) {
    int ii = i - 256 * KP;
    int f = ii >> 7, j = ii & 127;
    pE[ii] = w1[j * MIN + 160 + f];
  }
}

// fused conversion of all gating weights to bf16
#define CW1 (GIN * GIN)   // 36864
#define CW2 (HH * GIN)    // 12288
__global__ void k_cvt6(const float* __restrict__ r_w1, const float* __restrict__ z_w1,
                       const float* __restrict__ c_w1, const float* __restrict__ r_w2,
                       const float* __restrict__ z_w2, const float* __restrict__ c_w2,
                       ushortT* __restrict__ rzw1, ushortT* __restrict__ cw1,
                       ushortT* __restrict__ rw2, ushortT* __restrict__ zw2,
                       ushortT* __restrict__ cw2) {
  int i = blockIdx.x * 256 + threadIdx.x;
  if (i < CW1) rzw1[i] = f2b(r_w1[i]);
  else if (i < 2 * CW1) rzw1[i] = f2b(z_w1[i - CW1]);
  else if (i < 3 * CW1) cw1[i - 2 * CW1] = f2b(c_w1[i - 2 * CW1]);
  else if (i < 3 * CW1 + CW2) rw2[i - 3 * CW1] = f2b(r_w2[i - 3 * CW1]);
  else if (i < 3 * CW1 + 2 * CW2) zw2[i - 3 * CW1 - CW2] = f2b(z_w2[i - 3 * CW1 - CW2]);
  else if (i < 3 * CW1 + 3 * CW2) cw2[i - 3 * CW1 - 2 * CW2] = f2b(c_w2[i - 3 * CW1 - 2 * CW2]);
}

// ---------------- LayerNorm + concat xs -> nodecat_bf[N][96] (cols 80..95 = 0) ------
__global__ __launch_bounds__(256) void k_ln(const float* __restrict__ h,
                                            const float* __restrict__ xs,
                                            const float* __restrict__ lw,
                                            const float* __restrict__ lb,
                                            ushortT* __restrict__ nodecat) {
  int t = threadIdx.x;
  int node = blockIdx.x * 4 + (t >> 6), lane = t & 63;
  if (node >= NN) return;
  float v = h[(size_t)node * HH + lane];
  float mean = wave_sum64(v) * (1.0f / 64.0f);
  float d = v - mean;
  float var = wave_sum64(d * d) * (1.0f / 64.0f);
  nodecat[(size_t)node * KP + lane] = f2b(d * rsqrtf(var + 1e-5f) * lw[lane] + lb[lane]);
  if (lane < SDIM) {
    nodecat[(size_t)node * KP + HH + lane] = f2b(xs[(size_t)node * SDIM + lane]);
    nodecat[(size_t)node * KP + 80 + lane] = 0;
  }
}

// ---------------- MFMA bf16 GEMM: C[M,*] = act(A[M,K]@W[N,K]^T + bias) --------------
template <int ACT, int BF16OUT>
__global__ __launch_bounds__(256) void k_gemm_bf(
    const ushortT* __restrict__ A, int lda, const ushortT* __restrict__ W,
    const float* __restrict__ bias, void* __restrict__ Cout, int ldc, int M, int Kd) {
  int w = threadIdx.x >> 6, l = threadIdx.x & 63;
  int m0 = blockIdx.x * 64 + w * 16;
  int n0 = blockIdx.y * 64;
  int rowa = m0 + (l & 15);
  int kb = l >> 4;
  f32x4 acc0 = {0.f, 0.f, 0.f, 0.f}, acc1 = acc0, acc2 = acc0, acc3 = acc0;
  for (int k0 = 0; k0 < Kd; k0 += 32) {
    bf16x8 af = {0, 0, 0, 0, 0, 0, 0, 0};
    if (rowa < M) af = *(const bf16x8*)(A + (size_t)rowa * lda + k0 + kb * 8);
    const ushortT* wp = W + (size_t)(n0 + (l & 15)) * Kd + k0 + kb * 8;
    bf16x8 b0 = *(const bf16x8*)(wp);
    bf16x8 b1 = *(const bf16x8*)(wp + 16 * Kd);
    bf16x8 b2 = *(const bf16x8*)(wp + 32 * Kd);
    bf16x8 b3 = *(const bf16x8*)(wp + 48 * Kd);
    acc0 = __builtin_amdgcn_mfma_f32_16x16x32_bf16(af, b0, acc0, 0, 0, 0);
    acc1 = __builtin_amdgcn_mfma_f32_16x16x32_bf16(af, b1, acc1, 0, 0, 0);
    acc2 = __builtin_amdgcn_mfma_f32_16x16x32_bf16(af, b2, acc2, 0, 0, 0);
    acc3 = __builtin_amdgcn_mfma_f32_16x16x32_bf16(af, b3, acc3, 0, 0, 0);
  }
  int crow = m0 + (l >> 4) * 4;
  int ccol = n0 + (l & 15);
  f32x4 accs[4] = {acc0, acc1, acc2, acc3};
#pragma unroll
  for (int n = 0; n < 4; ++n) {
    int col = ccol + n * 16;
    float bv = bias ? bias[col] : 0.f;
#pragma unroll
    for (int r = 0; r < 4; ++r) {
      int row = crow + r;
      if (row < M) {
        float v = accs[n][r] + bv;
        if (ACT == 1) v = fmaxf(v, 0.f);
        else if (ACT == 2) v = 1.f / (1.f + expf(-v));
        else if (ACT == 3) v = tanhf(v);
        if (BF16OUT)
          ((ushortT*)Cout)[(size_t)row * ldc + col] = f2b(v);
        else
          ((float*)Cout)[(size_t)row * ldc + col] = v;
      }
    }
  }
}

// ------- edge combine: hidden = relu(cA[a]+cB[b]+W1e·ef[e]); p = hidden @ w2^T ------
template <int GATED>
__global__ __launch_bounds__(256) void k_edge_combine(
    const ushortT* __restrict__ cAB, const float* __restrict__ ef,
    const int* __restrict__ idxA, const int* __restrict__ idxB,
    const float* __restrict__ w1e, const float* __restrict__ w2,
    float* __restrict__ outp, int hop) {
  __shared__ float w1e_s[8][128];
  __shared__ float w2_s[4][128];
  int t = threadIdx.x;
  for (int i = t; i < 1024; i += 256) w1e_s[i >> 7][i & 127] = w1e[i];
  for (int i = t; i < 512; i += 256) w2_s[i >> 7][i & 127] = w2[i];
  __syncthreads();
  int es = t >> 2, q = t & 3;
  int e = blockIdx.x * 64 + es;
  int a = idxA[e], b = idxB[e];
  const ushortT* cA = cAB + (size_t)a * 256;
  const ushortT* cB = cAB + (size_t)b * 256 + 128;
  const float4* efp = (const float4*)(ef + (size_t)e * EFDIM);
  float4 e0 = efp[0], e1 = efp[1];
  float efv[8] = {e0.x, e0.y, e0.z, e0.w, e1.x, e1.y, e1.z, e1.w};
  float p[4] = {0.f, 0.f, 0.f, 0.f};
#pragma unroll
  for (int c = 0; c < 4; ++c) {
    int j = c * 32 + q * 8;
    uint4 ua4 = *(const uint4*)(cA + j);
    uint4 ub4 = *(const uint4*)(cB + j);
    const uintT* au = (const uintT*)&ua4;
    const uintT* bu = (const uintT*)&ub4;
    float h[8];
#pragma unroll
    for (int i2 = 0; i2 < 4; ++i2) {
      h[2 * i2] = b2f_lo(au[i2]) + b2f_lo(bu[i2]);
      h[2 * i2 + 1] = b2f_hi(au[i2]) + b2f_hi(bu[i2]);
    }
#pragma unroll
    for (int f = 0; f < 8; ++f) {
      float ev = efv[f];
      float4 w0 = *(const float4*)(&w1e_s[f][j]);
      float4 w1v = *(const float4*)(&w1e_s[f][j + 4]);
      h[0] += ev * w0.x; h[1] += ev * w0.y; h[2] += ev * w0.z; h[3] += ev * w0.w;
      h[4] += ev * w1v.x; h[5] += ev * w1v.y; h[6] += ev * w1v.z; h[7] += ev * w1v.w;
    }
#pragma unroll
    for (int i2 = 0; i2 < 8; ++i2) h[i2] = fmaxf(h[i2], 0.f);
#pragma unroll
    for (int o = 0; o < 4; ++o) {
      float4 u0 = *(const float4*)(&w2_s[o][j]);
      float4 u1 = *(const float4*)(&w2_s[o][j + 4]);
      p[o] += h[0] * u0.x + h[1] * u0.y + h[2] * u0.z + h[3] * u0.w +
              h[4] * u1.x + h[5] * u1.y + h[6] * u1.z + h[7] * u1.w;
    }
  }
#pragma unroll
  for (int o = 0; o < 4; ++o) {
    p[o] += __shfl_xor(p[o], 1, 64);
    p[o] += __shfl_xor(p[o], 2, 64);
  }
  float pv = (q == 0) ? p[0] : (q == 1) ? p[1] : (q == 2) ? p[2] : p[3];
  if (GATED) {
    outp[(size_t)e * (NHEAD * KHOP) + q * KHOP + hop] = 1.f / (1.f + expf(-pv));
  } else {
    outp[(size_t)e * 4 + q] = (pv > 0.f ? pv : 0.01f * pv) * 0.25f;
  }
}

// ---------------- segmented softmax over dest (wave per node) ----------------
__global__ __launch_bounds__(256) void k_segsoftmax(
    const float* __restrict__ s, const int* __restrict__ rp,
    const int* __restrict__ eids, float* __restrict__ wout, int hop) {
  int node = blockIdx.x * 4 + (threadIdx.x >> 6);
  if (node >= NN) return;
  int lane = threadIdx.x & 63;
  int beg = rp[node], end = rp[node + 1];
  if (beg == end) return;
  int li = lane >> 2, o = lane & 3;
  int deg = end - beg;
  if (deg <= 64) {
    int ee[4];
    float sv[4];
    int i0 = beg + li;
#pragma unroll
    for (int u = 0; u < 4; ++u) {
      int idx = i0 + u * 16;
      bool val = idx < end;
      int id2 = val ? idx : beg;
      int e = eids[id2];
      float v = s[(size_t)e * 4 + o];
      ee[u] = e;
      sv[u] = val ? v : -1e30f;
    }
    float mx = fmaxf(fmaxf(sv[0], sv[1]), fmaxf(sv[2], sv[3]));
#pragma unroll
    for (int m = 4; m <= 32; m <<= 1) mx = fmaxf(mx, __shfl_xor(mx, m, 64));
    float ex[4];
    float sum = 0.f;
#pragma unroll
    for (int u = 0; u < 4; ++u) {
      ex[u] = (sv[u] > -1e29f) ? expf(sv[u] - mx) : 0.f;
      sum += ex[u];
    }
#pragma unroll
    for (int m = 4; m <= 32; m <<= 1) sum += __shfl_xor(sum, m, 64);
    float inv = 1.f / (sum + 1e-9f);
#pragma unroll
    for (int u = 0; u < 4; ++u) {
      if (i0 + u * 16 < end)
        wout[(size_t)ee[u] * (NHEAD * KHOP) + o * KHOP + hop] = ex[u] * inv;
    }
  } else {
    float mx = -1e30f;
    for (int ii = beg + li; ii < end; ii += 16)
      mx = fmaxf(mx, s[(size_t)eids[ii] * 4 + o]);
#pragma unroll
    for (int m = 4; m <= 32; m <<= 1) mx = fmaxf(mx, __shfl_xor(mx, m, 64));
    float sum = 0.f;
    for (int ii = beg + li; ii < end; ii += 16)
      sum += expf(s[(size_t)eids[ii] * 4 + o] - mx);
#pragma unroll
    for (int m = 4; m <= 32; m <<= 1) sum += __shfl_xor(sum, m, 64);
    float inv = 1.f / (sum + 1e-9f);
    for (int ii = beg + li; ii < end; ii += 16) {
      int e = eids[ii];
      wout[(size_t)e * (NHEAD * KHOP) + o * KHOP + hop] =
          expf(s[(size_t)e * 4 + o] - mx) * inv;
    }
  }
}

// ------------- aggregate + proj + residual (wave per node, lane = h) -------------
__global__ __launch_bounds__(256) void k_aggregate(
    const ushortT* __restrict__ hn_bf, const float* __restrict__ ws, int hop,
    const int* __restrict__ rp, const int2* __restrict__ pair,
    const float* __restrict__ proj, float* __restrict__ h) {
  __shared__ float proj_s[64][68];
  __shared__ float agg_s[4][64];
  int t = threadIdx.x;
  for (int i = t; i < 4096; i += 256) proj_s[i >> 6][i & 63] = proj[i];
  int wv = t >> 6, lane = t & 63;
  int node = blockIdx.x * 4 + wv;
  float acc = 0.f;
  if (node < NN) {
    int beg = rp[node], end = rp[node + 1];
    int hd2 = (lane >> 4) * KHOP + hop;
    for (int ii = beg; ii < end; ii += 8) {
      int idxv[8];
      int2 pr[8];
      float wv8[8];
      float hv[8];
#pragma unroll
      for (int u = 0; u < 8; ++u) {
        int idx = ii + u;
        idxv[u] = (idx < end) ? idx : beg;
      }
#pragma unroll
      for (int u = 0; u < 8; ++u) pr[u] = pair[idxv[u]];
#pragma unroll
      for (int u = 0; u < 8; ++u)
        wv8[u] = ws[(size_t)pr[u].x * (NHEAD * KHOP) + hd2];
#pragma unroll
      for (int u = 0; u < 8; ++u)
        hv[u] = b2f(hn_bf[(size_t)pr[u].y * KP + lane]);
#pragma unroll
      for (int u = 0; u < 8; ++u) {
        float w = (ii + u < end) ? wv8[u] : 0.f;
        acc += w * hv[u];
      }
    }
  }
  agg_s[wv][lane] = acc;
  __syncthreads();
  if (node < NN) {
    float m = 0.f;
#pragma unroll
    for (int hh = 0; hh < 64; hh += 4) {
      float4 p = *(const float4*)(&proj_s[lane][hh]);
      m += p.x * agg_s[wv][hh] + p.y * agg_s[wv][hh + 1] +
           p.z * agg_s[wv][hh + 2] + p.w * agg_s[wv][hh + 3];
    }
    h[(size_t)node * HH + lane] += m;
  }
}

// ---------------- gating phase ----------------
__global__ void k_gatein(const float* __restrict__ x, const float* __restrict__ hf,
                         const float* __restrict__ hr, ushortT* __restrict__ gi) {
  int g = blockIdx.x * 256 + threadIdx.x;
  if (g >= NN * HH) return;
  int node = g >> 6, j = g & 63;
  float xv = x[g];
  gi[(size_t)node * GIN + j] = f2b(xv);
  gi[(size_t)node * GIN + 64 + j] = f2b(hf[g] - xv);
  gi[(size_t)node * GIN + 128 + j] = f2b(hr[g] - xv);
}

__global__ void k_candin(const float* __restrict__ x, const float* __restrict__ r,
                         ushortT* __restrict__ gi) {
  int g = blockIdx.x * 256 + threadIdx.x;
  if (g >= NN * HH) return;
  gi[(size_t)(g >> 6) * GIN + (g & 63)] = f2b(r[g] * x[g]);
}

__global__ void k_final(const float* __restrict__ x, const float* __restrict__ zv,
                        const float* __restrict__ cand, float* __restrict__ outF) {
  int g = blockIdx.x * 256 + threadIdx.x;
  if (g >= NN * HH) return;
  float z = zv[g];
  outF[g] = (1.f - z) * x[g] + z * cand[g];
}

extern "C" void kernel_launch(void* const* d_in, const int* in_sizes, int n_in,
                              void* d_out, int out_size, void* d_ws, size_t ws_size,
                              hipStream_t stream) {
  const float* x = (const float*)d_in[0];
  const float* xs = (const float*)d_in[1];
  const int* ei = (const int*)d_in[2];
  const float* ef = (const float*)d_in[3];
  const float* fw1 = (const float*)d_in[4];
  const float* fw2 = (const float*)d_in[5];
  const float* fpj = (const float*)d_in[6];
  const float* rw1 = (const float*)d_in[7];
  const float* rw2 = (const float*)d_in[8];
  const float* rpj = (const float*)d_in[9];
  const float* lnw = (const float*)d_in[10];
  const float* lnb = (const float*)d_in[11];
  const float* r_w1 = (const float*)d_in[12];
  const float* r_b1 = (const float*)d_in[13];
  const float* r_w2 = (const float*)d_in[14];
  const float* r_b2 = (const float*)d_in[15];
  const float* z_w1 = (const float*)d_in[16];
  const float* z_b1 = (const float*)d_in[17];
  const float* z_w2 = (const float*)d_in[18];
  const float* z_b2 = (const float*)d_in[19];
  const float* c_w1 = (const float*)d_in[20];
  const float* c_b1 = (const float*)d_in[21];
  const float* c_w2 = (const float*)d_in[22];
  const float* c_b2 = (const float*)d_in[23];
  const int* srcp = ei;
  const int* dstp = ei + EE;

  float* outF = (float*)d_out;
  float* outFW = outF + (size_t)NN * HH;
  float* outRW = outFW + (size_t)EE * NHEAD * KHOP;
  float* outZ = outRW + (size_t)EE * NHEAD * KHOP;
  float* outR = outZ + (size_t)NN * HH;

  char* Wb = (char*)d_ws;
  size_t off = 0;
  auto alloc = [&](size_t bytes) -> void* {
    void* p = Wb + off;
    off += (bytes + 255) & ~(size_t)255;
    return p;
  };
  float* h_fwd = (float*)alloc((size_t)NN * HH * 4);
  float* h_rev = (float*)alloc((size_t)NN * HH * 4);
  ushortT* nodecat_bf = (ushortT*)alloc((size_t)NN * KP * 2);
  float* raw = (float*)alloc((size_t)EE * NHEAD * 4);
  char* big = (char*)alloc((size_t)NN * 384 * 2);
  ushortT* cAB_bf = (ushortT*)big;
  ushortT* hid_bf = (ushortT*)big;
  ushortT* gi_bf = (ushortT*)alloc((size_t)NN * GIN * 2);
  float* cand = (float*)alloc((size_t)NN * HH * 4);
  ushortT* packAB_bf = (ushortT*)alloc((size_t)4 * 256 * KP * 2);
  float* packE = (float*)alloc((size_t)4 * 8 * 128 * 4);
  ushortT* rzw1_bf = (ushortT*)alloc((size_t)384 * GIN * 2);
  ushortT* rw2_bf = (ushortT*)alloc((size_t)HH * GIN * 2);
  ushortT* zw2_bf = (ushortT*)alloc((size_t)HH * GIN * 2);
  ushortT* cw1_bf = (ushortT*)alloc((size_t)GIN * GIN * 2);
  ushortT* cw2_bf = (ushortT*)alloc((size_t)HH * GIN * 2);
  float* rz_b1 = (float*)alloc(384 * 4);
  int* rp_d = (int*)alloc((NN + 8) * 4);
  int* rp_s = (int*)alloc((NN + 8) * 4);
  int* cur2 = (int*)alloc((size_t)2 * NN * 4);  // [cur_d | cur_s]
  int* cur_d = cur2;
  int* cur_s = cur2 + NN;
  int* eid_d = (int*)alloc((size_t)EE * 4);
  int* eid_s = (int*)alloc((size_t)EE * 4);
  int2* pair_d = (int2*)alloc((size_t)EE * 8);
  int2* pair_s = (int2*)alloc((size_t)EE * 8);

  hipMemcpyAsync(h_fwd, x, (size_t)NN * HH * 4, hipMemcpyDeviceToDevice, stream);
  hipMemcpyAsync(h_rev, x, (size_t)NN * HH * 4, hipMemcpyDeviceToDevice, stream);
  hipMemcpyAsync(rz_b1, r_b1, GIN * 4, hipMemcpyDeviceToDevice, stream);
  hipMemcpyAsync(rz_b1 + GIN, z_b1, GIN * 4, hipMemcpyDeviceToDevice, stream);

  const int EB = (EE + 255) / 256, NW = (NN + 3) / 4;
  const int PB = (256 * KP + 8 * 128 + 255) / 256;

  // weight repacks -> bf16 (one dispatch each)
  dim3 gPack(PB, 4);
  k_pack_bf<<<gPack, 256, 0, stream>>>(fw1, rw1, packAB_bf, packE);
  k_cvt6<<<(3 * CW1 + 3 * CW2 + 255) / 256, 256, 0, stream>>>(
      r_w1, z_w1, c_w1, r_w2, z_w2, c_w2, rzw1_bf, cw1_bf, rw2_bf, zw2_bf, cw2_bf);

  // CSR build (both directions)
  hipMemsetAsync(cur2, 0, (size_t)2 * NN * 4, stream);
  k_histo2<<<EB, 256, 0, stream>>>(srcp, dstp, cur_s, cur_d);
  k_scan2<<<2, 1024, 0, stream>>>(cur_d, cur_s, rp_d, rp_s);
  hipMemsetAsync(cur2, 0, (size_t)2 * NN * 4, stream);
  k_scatter2<<<EB, 256, 0, stream>>>(srcp, dstp, rp_s, rp_d, cur_s, cur_d, eid_s, eid_d);
  k_sortseg2<<<(2 * NN + 3) / 4, 256, 0, stream>>>(rp_d, rp_s, eid_d, eid_s);
  k_mkpair2<<<EB, 256, 0, stream>>>(eid_d, eid_s, srcp, dstp, pair_d, pair_s);

  const int MB64 = (NN + 63) / 64;  // 391
  dim3 gProj(MB64, 4);              // [NN,96]@[256,96]^T -> [NN,256]
  for (int k = 0; k < KHOP; ++k) {
    k_ln<<<NW, 256, 0, stream>>>(h_fwd, xs, lnw, lnb, nodecat_bf);
    k_gemm_bf<0, 1><<<gProj, 256, 0, stream>>>(nodecat_bf, KP,
                                               packAB_bf + (size_t)k * 256 * KP,
                                               nullptr, cAB_bf, 256, NN, KP);
    k_edge_combine<0><<<EE / 64, 256, 0, stream>>>(
        cAB_bf, ef, srcp, dstp, packE + (size_t)k * 8 * 128,
        fw2 + (size_t)k * NHEAD * WID, raw, 0);
    k_segsoftmax<<<NW, 256, 0, stream>>>(raw, rp_d, eid_d, outFW, k);
    k_aggregate<<<NW, 256, 0, stream>>>(nodecat_bf, outFW, k, rp_d, pair_d,
                                        fpj + (size_t)k * HH * HH, h_fwd);
  }
  for (int k = 0; k < KHOP; ++k) {
    k_ln<<<NW, 256, 0, stream>>>(h_rev, xs, lnw, lnb, nodecat_bf);
    k_gemm_bf<0, 1><<<gProj, 256, 0, stream>>>(nodecat_bf, KP,
                                               packAB_bf + (size_t)(2 + k) * 256 * KP,
                                               nullptr, cAB_bf, 256, NN, KP);
    k_edge_combine<1><<<EE / 64, 256, 0, stream>>>(
        cAB_bf, ef, dstp, srcp, packE + (size_t)(2 + k) * 8 * 128,
        rw2 + (size_t)k * NHEAD * WID, outRW, k);
    k_aggregate<<<NW, 256, 0, stream>>>(nodecat_bf, outRW, k, rp_s, pair_s,
                                        rpj + (size_t)k * HH * HH, h_rev);
  }

  // gating
  k_gatein<<<(NN * HH) / 256, 256, 0, stream>>>(x, h_fwd, h_rev, gi_bf);
  dim3 gRZ1(MB64, 6), gC1(MB64, 3), g2(MB64, 1);
  k_gemm_bf<1, 1><<<gRZ1, 256, 0, stream>>>(gi_bf, GIN, rzw1_bf, rz_b1, hid_bf, 384,
                                            NN, GIN);
  k_gemm_bf<2, 0><<<g2, 256, 0, stream>>>(hid_bf, 384, rw2_bf, r_b2, outR, HH, NN, GIN);
  k_gemm_bf<2, 0><<<g2, 256, 0, stream>>>(hid_bf + GIN, 384, zw2_bf, z_b2, outZ, HH,
                                          NN, GIN);
  k_candin<<<(NN * HH) / 256, 256, 0, stream>>>(x, outR, gi_bf);
  k_gemm_bf<1, 1><<<gC1, 256, 0, stream>>>(gi_bf, GIN, cw1_bf, c_b1, hid_bf, GIN, NN,
                                           GIN);
  k_gemm_bf<3, 0><<<g2, 256, 0, stream>>>(hid_bf, GIN, cw2_bf, c_b2, cand, HH, NN, GIN);
  k_final<<<(NN * HH) / 256, 256, 0, stream>>>(x, outZ, cand, outF);
}

// Round 7
// 611.499 us; speedup vs baseline: 8.0947x; 1.0649x over previous
//
#include <hip/hip_runtime.h>
#include <math.h>

#define NN 25000
#define EE 400000
#define HH 64
#define NHEAD 4
#define SDIM 16
#define EFDIM 8
#define KHOP 2
#define MIN 168   // 2H + 2S + EF
#define WID 128
#define GIN 192
#define KP 96     // padded K for node-proj GEMM (80 -> 96)

typedef __attribute__((ext_vector_type(8))) short bf16x8;
typedef __attribute__((ext_vector_type(4))) float f32x4;
typedef unsigned short ushortT;
typedef unsigned int uintT;

__device__ __forceinline__ float wave_sum64(float v) {
#pragma unroll
  for (int m = 1; m <= 32; m <<= 1) v += __shfl_xor(v, m, 64);
  return v;
}

__device__ __forceinline__ ushortT f2b(float f) {
  uintT u = __float_as_uint(f);
  return (ushortT)((u + 0x7FFFu + ((u >> 16) & 1u)) >> 16);
}
__device__ __forceinline__ float b2f(ushortT h) {
  return __uint_as_float(((uintT)h) << 16);
}
__device__ __forceinline__ float b2f_lo(uintT u) { return __uint_as_float(u << 16); }
__device__ __forceinline__ float b2f_hi(uintT u) { return __uint_as_float(u & 0xffff0000u); }

// ---------------- CSR build (both directions in one pass) ----------------
__global__ void k_histo2(const int* __restrict__ src, const int* __restrict__ dst,
                         int* __restrict__ cnt_s, int* __restrict__ cnt_d) {
  int e = blockIdx.x * 256 + threadIdx.x;
  if (e < EE) {
    atomicAdd(&cnt_d[dst[e]], 1);
    atomicAdd(&cnt_s[src[e]], 1);
  }
}

__global__ void k_scan2(const int* __restrict__ cnt_d, const int* __restrict__ cnt_s,
                        int* __restrict__ rp_d, int* __restrict__ rp_s) {
  const int* cnt = blockIdx.x ? cnt_s : cnt_d;
  int* rp = blockIdx.x ? rp_s : rp_d;
  __shared__ int part[1024];
  int t = threadIdx.x;
  const int CH = (NN + 1023) / 1024;
  int base = t * CH;
  int s = 0;
  for (int i = 0; i < CH; ++i) {
    int j = base + i;
    if (j < NN) s += cnt[j];
  }
  part[t] = s;
  __syncthreads();
  for (int off = 1; off < 1024; off <<= 1) {
    int v = (t >= off) ? part[t - off] : 0;
    __syncthreads();
    part[t] += v;
    __syncthreads();
  }
  int run = (t == 0) ? 0 : part[t - 1];
  for (int i = 0; i < CH; ++i) {
    int j = base + i;
    if (j < NN) { rp[j] = run; run += cnt[j]; }
  }
  if (t == 1023) rp[NN] = run;
}

__global__ void k_scatter2(const int* __restrict__ src, const int* __restrict__ dst,
                           const int* __restrict__ rp_s, const int* __restrict__ rp_d,
                           int* __restrict__ cur_s, int* __restrict__ cur_d,
                           int* __restrict__ eid_s, int* __restrict__ eid_d) {
  int e = blockIdx.x * 256 + threadIdx.x;
  if (e < EE) {
    int nd = dst[e];
    int pd = atomicAdd(&cur_d[nd], 1);
    eid_d[rp_d[nd] + pd] = e;
    int ns = src[e];
    int ps = atomicAdd(&cur_s[ns], 1);
    eid_s[rp_s[ns] + ps] = e;
  }
}

// wave-parallel bitonic sort of each segment (deterministic ascending order)
__global__ __launch_bounds__(256) void k_sortseg2(const int* __restrict__ rp_d,
                                                  const int* __restrict__ rp_s,
                                                  int* __restrict__ eid_d,
                                                  int* __restrict__ eid_s) {
  int gw = blockIdx.x * 4 + (threadIdx.x >> 6);
  int lane = threadIdx.x & 63;
  if (gw >= 2 * NN) return;
  const int* rp = (gw < NN) ? rp_d : rp_s;
  int* eids = (gw < NN) ? eid_d : eid_s;
  int node = (gw < NN) ? gw : gw - NN;
  int beg = rp[node], end = rp[node + 1];
  int deg = end - beg;
  if (deg <= 1) return;
  if (deg <= 64) {
    int v = (lane < deg) ? eids[beg + lane] : 0x7fffffff;
#pragma unroll
    for (int k = 2; k <= 64; k <<= 1) {
#pragma unroll
      for (int j = k >> 1; j > 0; j >>= 1) {
        int other = __shfl_xor(v, j, 64);
        bool takeMin = (((lane & k) == 0) == ((lane & j) == 0));
        v = takeMin ? min(v, other) : max(v, other);
      }
    }
    if (lane < deg) eids[beg + lane] = v;
  } else if (lane == 0) {
    for (int i = beg + 1; i < end; ++i) {
      int v = eids[i];
      int j = i - 1;
      while (j >= beg && eids[j] > v) { eids[j + 1] = eids[j]; --j; }
      eids[j + 1] = v;
    }
  }
}

// pair[ii] = {e, other_endpoint[e]} for both CSRs
__global__ void k_mkpair2(const int* __restrict__ eid_d, const int* __restrict__ eid_s,
                          const int* __restrict__ src, const int* __restrict__ dst,
                          int2* __restrict__ pair_d, int2* __restrict__ pair_s) {
  int i = blockIdx.x * 256 + threadIdx.x;
  if (i < EE) {
    int e1 = eid_d[i];
    pair_d[i] = make_int2(e1, src[e1]);
    int e2 = eid_s[i];
    pair_s[i] = make_int2(e2, dst[e2]);
  }
}

// ------------- weight repack: w1[128][168] -> pAB_bf[256][96], pE[8][128] -------------
__global__ void k_pack_bf(const float* __restrict__ fw1, const float* __restrict__ rw1,
                          ushortT* __restrict__ pAB_all, float* __restrict__ pE_all) {
  int y = blockIdx.y;
  const float* w1 = (y < 2) ? fw1 + (size_t)y * WID * MIN
                            : rw1 + (size_t)(y - 2) * WID * MIN;
  ushortT* pAB = pAB_all + (size_t)y * 256 * KP;
  float* pE = pE_all + (size_t)y * 8 * 128;
  int i = blockIdx.x * 256 + threadIdx.x;
  if (i < 256 * KP) {
    int j = i / KP, k = i % KP;
    float v = 0.f;
    if (k < 80) {
      int row = (j < 128) ? j : j - 128;
      int col = (j < 128) ? (k < 64 ? k : k + 64) : (k < 64 ? k + 64 : k + 80);
      v = w1[row * MIN + col];
    }
    pAB[i] = f2b(v);
  } else if (i < 256 * KP + 8 * 128) {
    int ii = i - 256 * KP;
    int f = ii >> 7, j = ii & 127;
    pE[ii] = w1[j * MIN + 160 + f];
  }
}

// fused conversion of all gating weights to bf16
#define CW1 (GIN * GIN)   // 36864
#define CW2 (HH * GIN)    // 12288
__global__ void k_cvt6(const float* __restrict__ r_w1, const float* __restrict__ z_w1,
                       const float* __restrict__ c_w1, const float* __restrict__ r_w2,
                       const float* __restrict__ z_w2, const float* __restrict__ c_w2,
                       ushortT* __restrict__ rzw1, ushortT* __restrict__ cw1,
                       ushortT* __restrict__ rw2, ushortT* __restrict__ zw2,
                       ushortT* __restrict__ cw2) {
  int i = blockIdx.x * 256 + threadIdx.x;
  if (i < CW1) rzw1[i] = f2b(r_w1[i]);
  else if (i < 2 * CW1) rzw1[i] = f2b(z_w1[i - CW1]);
  else if (i < 3 * CW1) cw1[i - 2 * CW1] = f2b(c_w1[i - 2 * CW1]);
  else if (i < 3 * CW1 + CW2) rw2[i - 3 * CW1] = f2b(r_w2[i - 3 * CW1]);
  else if (i < 3 * CW1 + 2 * CW2) zw2[i - 3 * CW1 - CW2] = f2b(z_w2[i - 3 * CW1 - CW2]);
  else if (i < 3 * CW1 + 3 * CW2) cw2[i - 3 * CW1 - 2 * CW2] = f2b(c_w2[i - 3 * CW1 - 2 * CW2]);
}

// ---------------- LayerNorm (both dirs): h -> nodecat_bf[N][96] ----------------
__global__ __launch_bounds__(256) void k_ln2(const float* __restrict__ hf,
                                             const float* __restrict__ hr,
                                             const float* __restrict__ xs,
                                             const float* __restrict__ lw,
                                             const float* __restrict__ lb,
                                             ushortT* __restrict__ ncf,
                                             ushortT* __restrict__ ncr) {
  const float* h = blockIdx.y ? hr : hf;
  ushortT* nodecat = blockIdx.y ? ncr : ncf;
  int t = threadIdx.x;
  int node = blockIdx.x * 4 + (t >> 6), lane = t & 63;
  if (node >= NN) return;
  float v = h[(size_t)node * HH + lane];
  float mean = wave_sum64(v) * (1.0f / 64.0f);
  float d = v - mean;
  float var = wave_sum64(d * d) * (1.0f / 64.0f);
  nodecat[(size_t)node * KP + lane] = f2b(d * rsqrtf(var + 1e-5f) * lw[lane] + lb[lane]);
  if (lane < SDIM) {
    nodecat[(size_t)node * KP + HH + lane] = f2b(xs[(size_t)node * SDIM + lane]);
    nodecat[(size_t)node * KP + 80 + lane] = 0;
  }
}

// ------- node projection GEMM, both dirs: C = A[NN,96] @ W[256,96]^T (bf16 out) -----
// A fragments loaded ONCE into registers; loop over all 4 n-chunks (A read 1x).
__global__ __launch_bounds__(256) void k_proj2(
    const ushortT* __restrict__ Af, const ushortT* __restrict__ Ar,
    const ushortT* __restrict__ Wf, const ushortT* __restrict__ Wr,
    ushortT* __restrict__ Cf, ushortT* __restrict__ Cr) {
  const ushortT* A = blockIdx.y ? Ar : Af;
  const ushortT* W = blockIdx.y ? Wr : Wf;
  ushortT* C = blockIdx.y ? Cr : Cf;
  int w = threadIdx.x >> 6, l = threadIdx.x & 63;
  int m0 = blockIdx.x * 64 + w * 16;
  int rowa = m0 + (l & 15);
  int kb = l >> 4;
  bf16x8 afr0 = {0,0,0,0,0,0,0,0}, afr1 = afr0, afr2 = afr0;
  if (rowa < NN) {
    const ushortT* ap = A + (size_t)rowa * KP + kb * 8;
    afr0 = *(const bf16x8*)(ap);
    afr1 = *(const bf16x8*)(ap + 32);
    afr2 = *(const bf16x8*)(ap + 64);
  }
  int crow = m0 + (l >> 4) * 4;
  int ccol0 = l & 15;
  for (int n0 = 0; n0 < 256; n0 += 64) {
    f32x4 acc[4];
#pragma unroll
    for (int n = 0; n < 4; ++n) acc[n] = (f32x4){0.f, 0.f, 0.f, 0.f};
    const ushortT* wbase = W + (size_t)(n0 + (l & 15)) * KP + kb * 8;
#pragma unroll
    for (int n = 0; n < 4; ++n) {
      const ushortT* wp = wbase + (size_t)(16 * n) * KP;
      acc[n] = __builtin_amdgcn_mfma_f32_16x16x32_bf16(afr0, *(const bf16x8*)(wp), acc[n], 0, 0, 0);
      acc[n] = __builtin_amdgcn_mfma_f32_16x16x32_bf16(afr1, *(const bf16x8*)(wp + 32), acc[n], 0, 0, 0);
      acc[n] = __builtin_amdgcn_mfma_f32_16x16x32_bf16(afr2, *(const bf16x8*)(wp + 64), acc[n], 0, 0, 0);
    }
#pragma unroll
    for (int n = 0; n < 4; ++n) {
      int col = n0 + ccol0 + n * 16;
#pragma unroll
      for (int r = 0; r < 4; ++r) {
        int row = crow + r;
        if (row < NN) C[(size_t)row * 256 + col] = f2b(acc[n][r]);
      }
    }
  }
}

// ------- generic MFMA GEMM (A-frags in regs, loop n-chunks): gating layers ---------
template <int ACT, int BF16OUT, int KD>
__global__ __launch_bounds__(256) void k_gemm2(
    const ushortT* __restrict__ A, int lda, const ushortT* __restrict__ W,
    const float* __restrict__ bias, void* __restrict__ Cout, int ldc, int M, int Nc) {
  constexpr int KS = KD / 32;
  int w = threadIdx.x >> 6, l = threadIdx.x & 63;
  int m0 = blockIdx.x * 64 + w * 16;
  int rowa = m0 + (l & 15);
  int kb = l >> 4;
  bf16x8 afr[KS];
#pragma unroll
  for (int ks = 0; ks < KS; ++ks) {
    afr[ks] = (bf16x8){0, 0, 0, 0, 0, 0, 0, 0};
    if (rowa < M) afr[ks] = *(const bf16x8*)(A + (size_t)rowa * lda + ks * 32 + kb * 8);
  }
  int crow = m0 + (l >> 4) * 4;
  int ccol0 = l & 15;
  for (int n0 = 0; n0 < Nc; n0 += 64) {
    f32x4 acc[4];
#pragma unroll
    for (int n = 0; n < 4; ++n) acc[n] = (f32x4){0.f, 0.f, 0.f, 0.f};
    const ushortT* wbase = W + (size_t)(n0 + (l & 15)) * KD + kb * 8;
#pragma unroll
    for (int n = 0; n < 4; ++n) {
      const ushortT* wp = wbase + (size_t)(16 * n) * KD;
#pragma unroll
      for (int ks = 0; ks < KS; ++ks)
        acc[n] = __builtin_amdgcn_mfma_f32_16x16x32_bf16(afr[ks], *(const bf16x8*)(wp + ks * 32),
                                                         acc[n], 0, 0, 0);
    }
#pragma unroll
    for (int n = 0; n < 4; ++n) {
      int col = n0 + ccol0 + n * 16;
      float bv = bias ? bias[col] : 0.f;
#pragma unroll
      for (int r = 0; r < 4; ++r) {
        int row = crow + r;
        if (row < M) {
          float v = acc[n][r] + bv;
          if (ACT == 1) v = fmaxf(v, 0.f);
          else if (ACT == 2) v = 1.f / (1.f + expf(-v));
          else if (ACT == 3) v = tanhf(v);
          if (BF16OUT)
            ((ushortT*)Cout)[(size_t)row * ldc + col] = f2b(v);
          else
            ((float*)Cout)[(size_t)row * ldc + col] = v;
        }
      }
    }
  }
}

// ------- edge combine, both dirs: hidden = relu(cA+cB+W1e·ef); p = hidden @ w2^T ----
// y=0 (fwd): write leaky(p)/4 to raw[e*4+q]; y=1 (rev): write sigmoid(p) to outRW.
__global__ __launch_bounds__(256) void k_edge2(
    const ushortT* __restrict__ cABf, const ushortT* __restrict__ cABr,
    const float* __restrict__ ef, const int* __restrict__ srcp,
    const int* __restrict__ dstp, const float* __restrict__ w1e_f,
    const float* __restrict__ w1e_r, const float* __restrict__ w2f,
    const float* __restrict__ w2r, float* __restrict__ rawout,
    float* __restrict__ outRW, int hop) {
  int y = blockIdx.y;
  const ushortT* cAB = y ? cABr : cABf;
  const int* idxA = y ? dstp : srcp;
  const int* idxB = y ? srcp : dstp;
  const float* w1e = y ? w1e_r : w1e_f;
  const float* w2 = y ? w2r : w2f;
  __shared__ float w1e_s[8][128];
  __shared__ float w2_s[4][128];
  int t = threadIdx.x;
  for (int i = t; i < 1024; i += 256) w1e_s[i >> 7][i & 127] = w1e[i];
  for (int i = t; i < 512; i += 256) w2_s[i >> 7][i & 127] = w2[i];
  __syncthreads();
  int es = t >> 2, q = t & 3;
  int e = blockIdx.x * 64 + es;
  int a = idxA[e], b = idxB[e];
  const ushortT* cA = cAB + (size_t)a * 256;
  const ushortT* cB = cAB + (size_t)b * 256 + 128;
  const float4* efp = (const float4*)(ef + (size_t)e * EFDIM);
  float4 e0 = efp[0], e1 = efp[1];
  float efv[8] = {e0.x, e0.y, e0.z, e0.w, e1.x, e1.y, e1.z, e1.w};
  float p[4] = {0.f, 0.f, 0.f, 0.f};
#pragma unroll
  for (int c = 0; c < 4; ++c) {
    int j = c * 32 + q * 8;
    uint4 ua4 = *(const uint4*)(cA + j);
    uint4 ub4 = *(const uint4*)(cB + j);
    const uintT* au = (const uintT*)&ua4;
    const uintT* bu = (const uintT*)&ub4;
    float h[8];
#pragma unroll
    for (int i2 = 0; i2 < 4; ++i2) {
      h[2 * i2] = b2f_lo(au[i2]) + b2f_lo(bu[i2]);
      h[2 * i2 + 1] = b2f_hi(au[i2]) + b2f_hi(bu[i2]);
    }
#pragma unroll
    for (int f = 0; f < 8; ++f) {
      float ev = efv[f];
      float4 w0 = *(const float4*)(&w1e_s[f][j]);
      float4 w1v = *(const float4*)(&w1e_s[f][j + 4]);
      h[0] += ev * w0.x; h[1] += ev * w0.y; h[2] += ev * w0.z; h[3] += ev * w0.w;
      h[4] += ev * w1v.x; h[5] += ev * w1v.y; h[6] += ev * w1v.z; h[7] += ev * w1v.w;
    }
#pragma unroll
    for (int i2 = 0; i2 < 8; ++i2) h[i2] = fmaxf(h[i2], 0.f);
#pragma unroll
    for (int o = 0; o < 4; ++o) {
      float4 u0 = *(const float4*)(&w2_s[o][j]);
      float4 u1 = *(const float4*)(&w2_s[o][j + 4]);
      p[o] += h[0] * u0.x + h[1] * u0.y + h[2] * u0.z + h[3] * u0.w +
              h[4] * u1.x + h[5] * u1.y + h[6] * u1.z + h[7] * u1.w;
    }
  }
#pragma unroll
  for (int o = 0; o < 4; ++o) {
    p[o] += __shfl_xor(p[o], 1, 64);
    p[o] += __shfl_xor(p[o], 2, 64);
  }
  float pv = (q == 0) ? p[0] : (q == 1) ? p[1] : (q == 2) ? p[2] : p[3];
  if (y) {
    outRW[(size_t)e * (NHEAD * KHOP) + q * KHOP + hop] = 1.f / (1.f + expf(-pv));
  } else {
    rawout[(size_t)e * 4 + q] = (pv > 0.f ? pv : 0.01f * pv) * 0.25f;
  }
}

// ---- fused softmax (SM=1) + aggregate + proj + residual (wave per node) ----
// SM=1: s = transformed scores; compute softmax, write wout, keep weights in LDS.
// SM=0: weights read from wsg (sigmoid gates, already final).
template <int SM>
__global__ __launch_bounds__(256) void k_softagg(
    const ushortT* __restrict__ hn_bf, const float* __restrict__ s,
    const float* __restrict__ wsg, int hop, const int* __restrict__ rp,
    const int2* __restrict__ pair, const float* __restrict__ proj,
    float* __restrict__ h, float* __restrict__ wout) {
  __shared__ float proj_s[64][68];
  __shared__ float agg_s[4][64];
  __shared__ float w_s[4][64][4];
  int t = threadIdx.x;
  for (int i = t; i < 4096; i += 256) proj_s[i >> 6][i & 63] = proj[i];
  int wvi = t >> 6, lane = t & 63;
  int node = blockIdx.x * 4 + wvi;
  __syncthreads();

  float acc = 0.f;
  if (node < NN) {
    int beg = rp[node], end = rp[node + 1];
    int deg = end - beg;
    float mxv = 0.f, invv = 0.f;  // only used in SM=1 deg>64 fallback
    if (SM && deg > 0) {
      int li = lane >> 2, o = lane & 3;
      if (deg <= 64) {
        int i0 = beg + li;
        int ee4[4];
        float sv[4];
#pragma unroll
        for (int u = 0; u < 4; ++u) {
          int idx = i0 + u * 16;
          bool val = idx < end;
          int2 pr = pair[val ? idx : beg];
          ee4[u] = pr.x;
          float v = s[(size_t)pr.x * 4 + o];
          sv[u] = val ? v : -1e30f;
        }
        float mx = fmaxf(fmaxf(sv[0], sv[1]), fmaxf(sv[2], sv[3]));
#pragma unroll
        for (int m = 4; m <= 32; m <<= 1) mx = fmaxf(mx, __shfl_xor(mx, m, 64));
        float ex[4];
        float sum = 0.f;
#pragma unroll
        for (int u = 0; u < 4; ++u) {
          ex[u] = (sv[u] > -1e29f) ? expf(sv[u] - mx) : 0.f;
          sum += ex[u];
        }
#pragma unroll
        for (int m = 4; m <= 32; m <<= 1) sum += __shfl_xor(sum, m, 64);
        float inv = 1.f / (sum + 1e-9f);
#pragma unroll
        for (int u = 0; u < 4; ++u) {
          if (i0 + u * 16 < end) {
            float wv = ex[u] * inv;
            wout[(size_t)ee4[u] * (NHEAD * KHOP) + o * KHOP + hop] = wv;
            w_s[wvi][li + u * 16][o] = wv;
          }
        }
      } else {
        float mx = -1e30f;
        for (int ii = beg + li; ii < end; ii += 16)
          mx = fmaxf(mx, s[(size_t)pair[ii].x * 4 + o]);
#pragma unroll
        for (int m = 4; m <= 32; m <<= 1) mx = fmaxf(mx, __shfl_xor(mx, m, 64));
        float sum = 0.f;
        for (int ii = beg + li; ii < end; ii += 16)
          sum += expf(s[(size_t)pair[ii].x * 4 + o] - mx);
#pragma unroll
        for (int m = 4; m <= 32; m <<= 1) sum += __shfl_xor(sum, m, 64);
        float inv = 1.f / (sum + 1e-9f);
        for (int ii = beg + li; ii < end; ii += 16) {
          int e = pair[ii].x;
          wout[(size_t)e * (NHEAD * KHOP) + o * KHOP + hop] =
              expf(s[(size_t)e * 4 + o] - mx) * inv;
        }
        mxv = mx;
        invv = inv;
      }
    }
    // aggregate phase
    int hd = lane >> 4;
    int hd2 = hd * KHOP + hop;
    float mx_hd = 0.f, inv_hd = 0.f;
    if (SM) {
      mx_hd = __shfl(mxv, hd, 64);
      inv_hd = __shfl(invv, hd, 64);
    }
    bool useLds = (deg <= 64);
    for (int ii = beg; ii < end; ii += 8) {
      int idxv[8];
      int2 pr[8];
      float wv8[8];
      float hv[8];
#pragma unroll
      for (int u = 0; u < 8; ++u) {
        int idx = ii + u;
        idxv[u] = (idx < end) ? idx : beg;
      }
#pragma unroll
      for (int u = 0; u < 8; ++u) pr[u] = pair[idxv[u]];
#pragma unroll
      for (int u = 0; u < 8; ++u) {
        if (SM) {
          if (useLds)
            wv8[u] = w_s[wvi][idxv[u] - beg][hd];
          else
            wv8[u] = expf(s[(size_t)pr[u].x * 4 + hd] - mx_hd) * inv_hd;
        } else {
          wv8[u] = wsg[(size_t)pr[u].x * (NHEAD * KHOP) + hd2];
        }
      }
#pragma unroll
      for (int u = 0; u < 8; ++u)
        hv[u] = b2f(hn_bf[(size_t)pr[u].y * KP + lane]);
#pragma unroll
      for (int u = 0; u < 8; ++u) {
        float w = (ii + u < end) ? wv8[u] : 0.f;
        acc += w * hv[u];
      }
    }
  }
  agg_s[wvi][lane] = acc;
  __syncthreads();
  if (node < NN) {
    float m = 0.f;
#pragma unroll
    for (int hh = 0; hh < 64; hh += 4) {
      float4 p = *(const float4*)(&proj_s[lane][hh]);
      m += p.x * agg_s[wvi][hh] + p.y * agg_s[wvi][hh + 1] +
           p.z * agg_s[wvi][hh + 2] + p.w * agg_s[wvi][hh + 3];
    }
    h[(size_t)node * HH + lane] += m;
  }
}

// ---------------- gating phase ----------------
__global__ void k_gatein(const float* __restrict__ x, const float* __restrict__ hf,
                         const float* __restrict__ hr, ushortT* __restrict__ gi) {
  int g = blockIdx.x * 256 + threadIdx.x;
  if (g >= NN * HH) return;
  int node = g >> 6, j = g & 63;
  float xv = x[g];
  gi[(size_t)node * GIN + j] = f2b(xv);
  gi[(size_t)node * GIN + 64 + j] = f2b(hf[g] - xv);
  gi[(size_t)node * GIN + 128 + j] = f2b(hr[g] - xv);
}

__global__ void k_candin(const float* __restrict__ x, const float* __restrict__ r,
                         ushortT* __restrict__ gi) {
  int g = blockIdx.x * 256 + threadIdx.x;
  if (g >= NN * HH) return;
  gi[(size_t)(g >> 6) * GIN + (g & 63)] = f2b(r[g] * x[g]);
}

__global__ void k_final(const float* __restrict__ x, const float* __restrict__ zv,
                        const float* __restrict__ cand, float* __restrict__ outF) {
  int g = blockIdx.x * 256 + threadIdx.x;
  if (g >= NN * HH) return;
  float z = zv[g];
  outF[g] = (1.f - z) * x[g] + z * cand[g];
}

extern "C" void kernel_launch(void* const* d_in, const int* in_sizes, int n_in,
                              void* d_out, int out_size, void* d_ws, size_t ws_size,
                              hipStream_t stream) {
  const float* x = (const float*)d_in[0];
  const float* xs = (const float*)d_in[1];
  const int* ei = (const int*)d_in[2];
  const float* ef = (const float*)d_in[3];
  const float* fw1 = (const float*)d_in[4];
  const float* fw2 = (const float*)d_in[5];
  const float* fpj = (const float*)d_in[6];
  const float* rw1 = (const float*)d_in[7];
  const float* rw2 = (const float*)d_in[8];
  const float* rpj = (const float*)d_in[9];
  const float* lnw = (const float*)d_in[10];
  const float* lnb = (const float*)d_in[11];
  const float* r_w1 = (const float*)d_in[12];
  const float* r_b1 = (const float*)d_in[13];
  const float* r_w2 = (const float*)d_in[14];
  const float* r_b2 = (const float*)d_in[15];
  const float* z_w1 = (const float*)d_in[16];
  const float* z_b1 = (const float*)d_in[17];
  const float* z_w2 = (const float*)d_in[18];
  const float* z_b2 = (const float*)d_in[19];
  const float* c_w1 = (const float*)d_in[20];
  const float* c_b1 = (const float*)d_in[21];
  const float* c_w2 = (const float*)d_in[22];
  const float* c_b2 = (const float*)d_in[23];
  const int* srcp = ei;
  const int* dstp = ei + EE;

  float* outF = (float*)d_out;
  float* outFW = outF + (size_t)NN * HH;
  float* outRW = outFW + (size_t)EE * NHEAD * KHOP;
  float* outZ = outRW + (size_t)EE * NHEAD * KHOP;
  float* outR = outZ + (size_t)NN * HH;

  char* Wb = (char*)d_ws;
  size_t off = 0;
  auto alloc = [&](size_t bytes) -> void* {
    void* p = Wb + off;
    off += (bytes + 255) & ~(size_t)255;
    return p;
  };
  float* h_fwd = (float*)alloc((size_t)NN * HH * 4);
  float* h_rev = (float*)alloc((size_t)NN * HH * 4);
  ushortT* ncat_f = (ushortT*)alloc((size_t)NN * KP * 2);
  ushortT* ncat_r = (ushortT*)alloc((size_t)NN * KP * 2);
  float* raw = (float*)alloc((size_t)EE * NHEAD * 4);
  // big region: hop phase -> cAB_f + cAB_r (2 x 12.8MB); gating -> hid_bf (19.2MB)
  char* big = (char*)alloc((size_t)2 * NN * 256 * 2);
  ushortT* cAB_f = (ushortT*)big;
  ushortT* cAB_r = (ushortT*)(big + (size_t)NN * 256 * 2);
  ushortT* hid_bf = (ushortT*)big;
  ushortT* gi_bf = (ushortT*)alloc((size_t)NN * GIN * 2);
  float* cand = (float*)alloc((size_t)NN * HH * 4);
  ushortT* packAB_bf = (ushortT*)alloc((size_t)4 * 256 * KP * 2);
  float* packE = (float*)alloc((size_t)4 * 8 * 128 * 4);
  ushortT* rzw1_bf = (ushortT*)alloc((size_t)384 * GIN * 2);
  ushortT* rw2_bf = (ushortT*)alloc((size_t)HH * GIN * 2);
  ushortT* zw2_bf = (ushortT*)alloc((size_t)HH * GIN * 2);
  ushortT* cw1_bf = (ushortT*)alloc((size_t)GIN * GIN * 2);
  ushortT* cw2_bf = (ushortT*)alloc((size_t)HH * GIN * 2);
  float* rz_b1 = (float*)alloc(384 * 4);
  int* rp_d = (int*)alloc((NN + 8) * 4);
  int* rp_s = (int*)alloc((NN + 8) * 4);
  int* cur2 = (int*)alloc((size_t)2 * NN * 4);
  int* cur_d = cur2;
  int* cur_s = cur2 + NN;
  int* eid_d = (int*)alloc((size_t)EE * 4);
  int* eid_s = (int*)alloc((size_t)EE * 4);
  int2* pair_d = (int2*)alloc((size_t)EE * 8);
  int2* pair_s = (int2*)alloc((size_t)EE * 8);

  hipMemcpyAsync(h_fwd, x, (size_t)NN * HH * 4, hipMemcpyDeviceToDevice, stream);
  hipMemcpyAsync(h_rev, x, (size_t)NN * HH * 4, hipMemcpyDeviceToDevice, stream);
  hipMemcpyAsync(rz_b1, r_b1, GIN * 4, hipMemcpyDeviceToDevice, stream);
  hipMemcpyAsync(rz_b1 + GIN, z_b1, GIN * 4, hipMemcpyDeviceToDevice, stream);

  const int EB = (EE + 255) / 256, NW = (NN + 3) / 4;
  const int PB = (256 * KP + 8 * 128 + 255) / 256;

  // weight repacks -> bf16
  dim3 gPack(PB, 4);
  k_pack_bf<<<gPack, 256, 0, stream>>>(fw1, rw1, packAB_bf, packE);
  k_cvt6<<<(3 * CW1 + 3 * CW2 + 255) / 256, 256, 0, stream>>>(
      r_w1, z_w1, c_w1, r_w2, z_w2, c_w2, rzw1_bf, cw1_bf, rw2_bf, zw2_bf, cw2_bf);

  // CSR build (both directions)
  hipMemsetAsync(cur2, 0, (size_t)2 * NN * 4, stream);
  k_histo2<<<EB, 256, 0, stream>>>(srcp, dstp, cur_s, cur_d);
  k_scan2<<<2, 1024, 0, stream>>>(cur_d, cur_s, rp_d, rp_s);
  hipMemsetAsync(cur2, 0, (size_t)2 * NN * 4, stream);
  k_scatter2<<<EB, 256, 0, stream>>>(srcp, dstp, rp_s, rp_d, cur_s, cur_d, eid_s, eid_d);
  k_sortseg2<<<(2 * NN + 3) / 4, 256, 0, stream>>>(rp_d, rp_s, eid_d, eid_s);
  k_mkpair2<<<EB, 256, 0, stream>>>(eid_d, eid_s, srcp, dstp, pair_d, pair_s);

  const int MB64 = (NN + 63) / 64;  // 391
  dim3 gLN(NW, 2), gProj(MB64, 2), gEdge(EE / 64, 2);
  for (int k = 0; k < KHOP; ++k) {
    k_ln2<<<gLN, 256, 0, stream>>>(h_fwd, h_rev, xs, lnw, lnb, ncat_f, ncat_r);
    k_proj2<<<gProj, 256, 0, stream>>>(ncat_f, ncat_r,
                                       packAB_bf + (size_t)k * 256 * KP,
                                       packAB_bf + (size_t)(2 + k) * 256 * KP,
                                       cAB_f, cAB_r);
    k_edge2<<<gEdge, 256, 0, stream>>>(cAB_f, cAB_r, ef, srcp, dstp,
                                       packE + (size_t)k * 8 * 128,
                                       packE + (size_t)(2 + k) * 8 * 128,
                                       fw2 + (size_t)k * NHEAD * WID,
                                       rw2 + (size_t)k * NHEAD * WID, raw, outRW, k);
    k_softagg<1><<<NW, 256, 0, stream>>>(ncat_f, raw, nullptr, k, rp_d, pair_d,
                                         fpj + (size_t)k * HH * HH, h_fwd, outFW);
    k_softagg<0><<<NW, 256, 0, stream>>>(ncat_r, nullptr, outRW, k, rp_s, pair_s,
                                         rpj + (size_t)k * HH * HH, h_rev, nullptr);
  }

  // gating
  k_gatein<<<(NN * HH) / 256, 256, 0, stream>>>(x, h_fwd, h_rev, gi_bf);
  k_gemm2<1, 1, GIN><<<MB64, 256, 0, stream>>>(gi_bf, GIN, rzw1_bf, rz_b1, hid_bf,
                                               384, NN, 384);
  k_gemm2<2, 0, GIN><<<MB64, 256, 0, stream>>>(hid_bf, 384, rw2_bf, r_b2, outR, HH,
                                               NN, HH);
  k_gemm2<2, 0, GIN><<<MB64, 256, 0, stream>>>(hid_bf + GIN, 384, zw2_bf, z_b2, outZ,
                                               HH, NN, HH);
  k_candin<<<(NN * HH) / 256, 256, 0, stream>>>(x, outR, gi_bf);
  k_gemm2<1, 1, GIN><<<MB64, 256, 0, stream>>>(gi_bf, GIN, cw1_bf, c_b1, hid_bf, GIN,
                                               NN, GIN);
  k_gemm2<3, 0, GIN><<<MB64, 256, 0, stream>>>(hid_bf, GIN, cw2_bf, c_b2, cand, HH,
                                               NN, HH);
  k_final<<<(NN * HH) / 256, 256, 0, stream>>>(x, outZ, cand, outF);
}

// Round 9
// 609.463 us; speedup vs baseline: 8.1218x; 1.0033x over previous
//
#include <hip/hip_runtime.h>
#include <math.h>

#define NN 25000
#define EE 400000
#define HH 64
#define NHEAD 4
#define SDIM 16
#define EFDIM 8
#define KHOP 2
#define MIN 168   // 2H + 2S + EF
#define WID 128
#define GIN 192
#define KP 96     // padded K for node-proj GEMM (80 -> 96)

typedef __attribute__((ext_vector_type(8))) short bf16x8;
typedef __attribute__((ext_vector_type(4))) float f32x4;
typedef unsigned short ushortT;
typedef unsigned int uintT;

__device__ __forceinline__ float wave_sum64(float v) {
#pragma unroll
  for (int m = 1; m <= 32; m <<= 1) v += __shfl_xor(v, m, 64);
  return v;
}

__device__ __forceinline__ ushortT f2b(float f) {
  uintT u = __float_as_uint(f);
  return (ushortT)((u + 0x7FFFu + ((u >> 16) & 1u)) >> 16);
}
__device__ __forceinline__ float b2f(ushortT h) {
  return __uint_as_float(((uintT)h) << 16);
}
__device__ __forceinline__ float b2f_lo(uintT u) { return __uint_as_float(u << 16); }
__device__ __forceinline__ float b2f_hi(uintT u) { return __uint_as_float(u & 0xffff0000u); }

// ---------------- CSR build (both directions in one pass) ----------------
__global__ void k_histo2(const int* __restrict__ src, const int* __restrict__ dst,
                         int* __restrict__ cnt_s, int* __restrict__ cnt_d) {
  int e = blockIdx.x * 256 + threadIdx.x;
  if (e < EE) {
    atomicAdd(&cnt_d[dst[e]], 1);
    atomicAdd(&cnt_s[src[e]], 1);
  }
}

__global__ void k_scan2(const int* __restrict__ cnt_d, const int* __restrict__ cnt_s,
                        int* __restrict__ rp_d, int* __restrict__ rp_s) {
  const int* cnt = blockIdx.x ? cnt_s : cnt_d;
  int* rp = blockIdx.x ? rp_s : rp_d;
  __shared__ int part[1024];
  int t = threadIdx.x;
  const int CH = (NN + 1023) / 1024;
  int base = t * CH;
  int s = 0;
  for (int i = 0; i < CH; ++i) {
    int j = base + i;
    if (j < NN) s += cnt[j];
  }
  part[t] = s;
  __syncthreads();
  for (int off = 1; off < 1024; off <<= 1) {
    int v = (t >= off) ? part[t - off] : 0;
    __syncthreads();
    part[t] += v;
    __syncthreads();
  }
  int run = (t == 0) ? 0 : part[t - 1];
  for (int i = 0; i < CH; ++i) {
    int j = base + i;
    if (j < NN) { rp[j] = run; run += cnt[j]; }
  }
  if (t == 1023) rp[NN] = run;
}

__global__ void k_scatter2(const int* __restrict__ src, const int* __restrict__ dst,
                           const int* __restrict__ rp_s, const int* __restrict__ rp_d,
                           int* __restrict__ cur_s, int* __restrict__ cur_d,
                           int* __restrict__ eid_s, int* __restrict__ eid_d) {
  int e = blockIdx.x * 256 + threadIdx.x;
  if (e < EE) {
    int nd = dst[e];
    int pd = atomicAdd(&cur_d[nd], 1);
    eid_d[rp_d[nd] + pd] = e;
    int ns = src[e];
    int ps = atomicAdd(&cur_s[ns], 1);
    eid_s[rp_s[ns] + ps] = e;
  }
}

// wave-parallel bitonic sort of each segment (deterministic ascending order)
__global__ __launch_bounds__(256) void k_sortseg2(const int* __restrict__ rp_d,
                                                  const int* __restrict__ rp_s,
                                                  int* __restrict__ eid_d,
                                                  int* __restrict__ eid_s) {
  int gw = blockIdx.x * 4 + (threadIdx.x >> 6);
  int lane = threadIdx.x & 63;
  if (gw >= 2 * NN) return;
  const int* rp = (gw < NN) ? rp_d : rp_s;
  int* eids = (gw < NN) ? eid_d : eid_s;
  int node = (gw < NN) ? gw : gw - NN;
  int beg = rp[node], end = rp[node + 1];
  int deg = end - beg;
  if (deg <= 1) return;
  if (deg <= 64) {
    int v = (lane < deg) ? eids[beg + lane] : 0x7fffffff;
#pragma unroll
    for (int k = 2; k <= 64; k <<= 1) {
#pragma unroll
      for (int j = k >> 1; j > 0; j >>= 1) {
        int other = __shfl_xor(v, j, 64);
        bool takeMin = (((lane & k) == 0) == ((lane & j) == 0));
        v = takeMin ? min(v, other) : max(v, other);
      }
    }
    if (lane < deg) eids[beg + lane] = v;
  } else if (lane == 0) {
    for (int i = beg + 1; i < end; ++i) {
      int v = eids[i];
      int j = i - 1;
      while (j >= beg && eids[j] > v) { eids[j + 1] = eids[j]; --j; }
      eids[j + 1] = v;
    }
  }
}

// pos[ii] = {e, other_node, owner_node, 0} + position-ordered ef (float, coalesced)
__global__ void k_mkpos2(const int* __restrict__ eid_d, const int* __restrict__ eid_s,
                         const int* __restrict__ src, const int* __restrict__ dst,
                         const float* __restrict__ ef, int4* __restrict__ pos_f,
                         int4* __restrict__ pos_r, float4* __restrict__ efs_f,
                         float4* __restrict__ efs_r) {
  int i = blockIdx.x * 256 + threadIdx.x;
  if (i >= EE) return;
  int e1 = eid_d[i];
  pos_f[i] = make_int4(e1, src[e1], dst[e1], 0);
  int e2 = eid_s[i];
  pos_r[i] = make_int4(e2, dst[e2], src[e2], 0);
  efs_f[2 * i] = *(const float4*)(ef + (size_t)e1 * EFDIM);
  efs_f[2 * i + 1] = *(const float4*)(ef + (size_t)e1 * EFDIM + 4);
  efs_r[2 * i] = *(const float4*)(ef + (size_t)e2 * EFDIM);
  efs_r[2 * i + 1] = *(const float4*)(ef + (size_t)e2 * EFDIM + 4);
}

// ------- weight repack: w1[128][168] -> pAB_bf[256][96], pE[8][128] float ----------
#define PACKN (256 * KP + 8 * 128)
__global__ void k_pack_bf(const float* __restrict__ fw1, const float* __restrict__ rw1,
                          ushortT* __restrict__ pAB_all, float* __restrict__ pE_all) {
  int y = blockIdx.y;
  const float* w1 = (y < 2) ? fw1 + (size_t)y * WID * MIN
                            : rw1 + (size_t)(y - 2) * WID * MIN;
  ushortT* pAB = pAB_all + (size_t)y * 256 * KP;
  float* pE = pE_all + (size_t)y * 8 * 128;
  int i = blockIdx.x * 256 + threadIdx.x;
  if (i < 256 * KP) {
    int j = i / KP, k = i % KP;
    float v = 0.f;
    if (k < 80) {
      int row = (j < 128) ? j : j - 128;
      int col = (j < 128) ? (k < 64 ? k : k + 64) : (k < 64 ? k + 64 : k + 80);
      v = w1[row * MIN + col];
    }
    pAB[i] = f2b(v);
  } else if (i < PACKN) {
    int ii = i - 256 * KP;
    int f = ii >> 7, j = ii & 127;
    pE[ii] = w1[j * MIN + 160 + f];
  }
}

// fused conversion of all gating weights to bf16
#define CW1 (GIN * GIN)   // 36864
#define CW2 (HH * GIN)    // 12288
__global__ void k_cvt6(const float* __restrict__ r_w1, const float* __restrict__ z_w1,
                       const float* __restrict__ c_w1, const float* __restrict__ r_w2,
                       const float* __restrict__ z_w2, const float* __restrict__ c_w2,
                       ushortT* __restrict__ rzw1, ushortT* __restrict__ cw1,
                       ushortT* __restrict__ rw2, ushortT* __restrict__ zw2,
                       ushortT* __restrict__ cw2) {
  int i = blockIdx.x * 256 + threadIdx.x;
  if (i < CW1) rzw1[i] = f2b(r_w1[i]);
  else if (i < 2 * CW1) rzw1[i] = f2b(z_w1[i - CW1]);
  else if (i < 3 * CW1) cw1[i - 2 * CW1] = f2b(c_w1[i - 2 * CW1]);
  else if (i < 3 * CW1 + CW2) rw2[i - 3 * CW1] = f2b(r_w2[i - 3 * CW1]);
  else if (i < 3 * CW1 + 2 * CW2) zw2[i - 3 * CW1 - CW2] = f2b(z_w2[i - 3 * CW1 - CW2]);
  else if (i < 3 * CW1 + 3 * CW2) cw2[i - 3 * CW1 - 2 * CW2] = f2b(c_w2[i - 3 * CW1 - 2 * CW2]);
}

// ---------------- LayerNorm (both dirs): h -> nodecat_bf[N][96] ----------------
__global__ __launch_bounds__(256) void k_ln2(const float* __restrict__ hf,
                                             const float* __restrict__ hr,
                                             const float* __restrict__ xs,
                                             const float* __restrict__ lw,
                                             const float* __restrict__ lb,
                                             ushortT* __restrict__ ncf,
                                             ushortT* __restrict__ ncr) {
  const float* h = blockIdx.y ? hr : hf;
  ushortT* nodecat = blockIdx.y ? ncr : ncf;
  int t = threadIdx.x;
  int node = blockIdx.x * 4 + (t >> 6), lane = t & 63;
  if (node >= NN) return;
  float v = h[(size_t)node * HH + lane];
  float mean = wave_sum64(v) * (1.0f / 64.0f);
  float d = v - mean;
  float var = wave_sum64(d * d) * (1.0f / 64.0f);
  nodecat[(size_t)node * KP + lane] = f2b(d * rsqrtf(var + 1e-5f) * lw[lane] + lb[lane]);
  if (lane < SDIM) {
    nodecat[(size_t)node * KP + HH + lane] = f2b(xs[(size_t)node * SDIM + lane]);
    nodecat[(size_t)node * KP + 80 + lane] = 0;
  }
}

// ------- node projection GEMM, both dirs: C = A[NN,96] @ W[256,96]^T (bf16 out) -----
__global__ __launch_bounds__(256) void k_proj2(
    const ushortT* __restrict__ Af, const ushortT* __restrict__ Ar,
    const ushortT* __restrict__ Wf, const ushortT* __restrict__ Wr,
    ushortT* __restrict__ Cf, ushortT* __restrict__ Cr) {
  const ushortT* A = blockIdx.y ? Ar : Af;
  const ushortT* W = blockIdx.y ? Wr : Wf;
  ushortT* C = blockIdx.y ? Cr : Cf;
  int w = threadIdx.x >> 6, l = threadIdx.x & 63;
  int m0 = blockIdx.x * 64 + w * 16;
  int rowa = m0 + (l & 15);
  int kb = l >> 4;
  bf16x8 afr0 = {0,0,0,0,0,0,0,0}, afr1 = afr0, afr2 = afr0;
  if (rowa < NN) {
    const ushortT* ap = A + (size_t)rowa * KP + kb * 8;
    afr0 = *(const bf16x8*)(ap);
    afr1 = *(const bf16x8*)(ap + 32);
    afr2 = *(const bf16x8*)(ap + 64);
  }
  int crow = m0 + (l >> 4) * 4;
  int ccol0 = l & 15;
  for (int n0 = 0; n0 < 256; n0 += 64) {
    f32x4 acc[4];
#pragma unroll
    for (int n = 0; n < 4; ++n) acc[n] = (f32x4){0.f, 0.f, 0.f, 0.f};
    const ushortT* wbase = W + (size_t)(n0 + (l & 15)) * KP + kb * 8;
#pragma unroll
    for (int n = 0; n < 4; ++n) {
      const ushortT* wp = wbase + (size_t)(16 * n) * KP;
      acc[n] = __builtin_amdgcn_mfma_f32_16x16x32_bf16(afr0, *(const bf16x8*)(wp), acc[n], 0, 0, 0);
      acc[n] = __builtin_amdgcn_mfma_f32_16x16x32_bf16(afr1, *(const bf16x8*)(wp + 32), acc[n], 0, 0, 0);
      acc[n] = __builtin_amdgcn_mfma_f32_16x16x32_bf16(afr2, *(const bf16x8*)(wp + 64), acc[n], 0, 0, 0);
    }
#pragma unroll
    for (int n = 0; n < 4; ++n) {
      int col = n0 + ccol0 + n * 16;
#pragma unroll
      for (int r = 0; r < 4; ++r) {
        int row = crow + r;
        if (row < NN) C[(size_t)row * 256 + col] = f2b(acc[n][r]);
      }
    }
  }
}

// ------- generic MFMA GEMM; ACT 5 = fused GRU final: out=(1-z)x+z*tanh(v) ---------
template <int ACT, int BF16OUT, int KD>
__global__ __launch_bounds__(256) void k_gemm2(
    const ushortT* __restrict__ A, int lda, const ushortT* __restrict__ W,
    const float* __restrict__ bias, void* __restrict__ Cout, int ldc, int M, int Nc,
    const float* __restrict__ zv, const float* __restrict__ xp) {
  constexpr int KS = KD / 32;
  int w = threadIdx.x >> 6, l = threadIdx.x & 63;
  int m0 = blockIdx.x * 64 + w * 16;
  int rowa = m0 + (l & 15);
  int kb = l >> 4;
  bf16x8 afr[KS];
#pragma unroll
  for (int ks = 0; ks < KS; ++ks) {
    afr[ks] = (bf16x8){0, 0, 0, 0, 0, 0, 0, 0};
    if (rowa < M) afr[ks] = *(const bf16x8*)(A + (size_t)rowa * lda + ks * 32 + kb * 8);
  }
  int crow = m0 + (l >> 4) * 4;
  int ccol0 = l & 15;
  for (int n0 = 0; n0 < Nc; n0 += 64) {
    f32x4 acc[4];
#pragma unroll
    for (int n = 0; n < 4; ++n) acc[n] = (f32x4){0.f, 0.f, 0.f, 0.f};
    const ushortT* wbase = W + (size_t)(n0 + (l & 15)) * KD + kb * 8;
#pragma unroll
    for (int n = 0; n < 4; ++n) {
      const ushortT* wp = wbase + (size_t)(16 * n) * KD;
#pragma unroll
      for (int ks = 0; ks < KS; ++ks)
        acc[n] = __builtin_amdgcn_mfma_f32_16x16x32_bf16(afr[ks], *(const bf16x8*)(wp + ks * 32),
                                                         acc[n], 0, 0, 0);
    }
#pragma unroll
    for (int n = 0; n < 4; ++n) {
      int col = n0 + ccol0 + n * 16;
      float bv = bias ? bias[col] : 0.f;
#pragma unroll
      for (int r = 0; r < 4; ++r) {
        int row = crow + r;
        if (row < M) {
          float v = acc[n][r] + bv;
          if (ACT == 1) v = fmaxf(v, 0.f);
          else if (ACT == 2) v = 1.f / (1.f + expf(-v));
          else if (ACT == 3) v = tanhf(v);
          else if (ACT == 5) {
            float z = zv[(size_t)row * HH + col];
            float xv = xp[(size_t)row * HH + col];
            v = (1.f - z) * xv + z * tanhf(v);
          }
          if (BF16OUT)
            ((ushortT*)Cout)[(size_t)row * ldc + col] = f2b(v);
          else
            ((float*)Cout)[(size_t)row * ldc + col] = v;
        }
      }
    }
  }
}

// dual r2/z2 second-layer gemm (sigmoid): y=0 -> outR, y=1 -> outZ
__global__ __launch_bounds__(256) void k_gemm_rz(
    const ushortT* __restrict__ hid, const ushortT* __restrict__ rw2,
    const ushortT* __restrict__ zw2, const float* __restrict__ rb2,
    const float* __restrict__ zb2, float* __restrict__ outR, float* __restrict__ outZ) {
  int y = blockIdx.y;
  const ushortT* A = hid + (y ? GIN : 0);
  const ushortT* W = y ? zw2 : rw2;
  const float* bias = y ? zb2 : rb2;
  float* C = y ? outZ : outR;
  constexpr int KS = GIN / 32;
  int w = threadIdx.x >> 6, l = threadIdx.x & 63;
  int m0 = blockIdx.x * 64 + w * 16;
  int rowa = m0 + (l & 15);
  int kb = l >> 4;
  bf16x8 afr[KS];
#pragma unroll
  for (int ks = 0; ks < KS; ++ks) {
    afr[ks] = (bf16x8){0, 0, 0, 0, 0, 0, 0, 0};
    if (rowa < NN) afr[ks] = *(const bf16x8*)(A + (size_t)rowa * 384 + ks * 32 + kb * 8);
  }
  int crow = m0 + (l >> 4) * 4;
  int ccol0 = l & 15;
  f32x4 acc[4];
#pragma unroll
  for (int n = 0; n < 4; ++n) acc[n] = (f32x4){0.f, 0.f, 0.f, 0.f};
  const ushortT* wbase = W + (size_t)(l & 15) * GIN + kb * 8;
#pragma unroll
  for (int n = 0; n < 4; ++n) {
    const ushortT* wp = wbase + (size_t)(16 * n) * GIN;
#pragma unroll
    for (int ks = 0; ks < KS; ++ks)
      acc[n] = __builtin_amdgcn_mfma_f32_16x16x32_bf16(afr[ks], *(const bf16x8*)(wp + ks * 32),
                                                       acc[n], 0, 0, 0);
  }
#pragma unroll
  for (int n = 0; n < 4; ++n) {
    int col = ccol0 + n * 16;
    float bv = bias[col];
#pragma unroll
    for (int r = 0; r < 4; ++r) {
      int row = crow + r;
      if (row < NN) {
        float v = acc[n][r] + bv;
        C[(size_t)row * HH + col] = 1.f / (1.f + expf(-v));
      }
    }
  }
}

// ------- edge combine, CSR-position-ordered, both dirs -----------------------------
// hidden = relu(cA[other] + cB[owner] + W1e.ef);  p = hidden @ w2^T
// y=0 (fwd): s_seq[ii*4+q] = leaky(p)/4 (sequential).
// y=1 (rev): sig -> outRW[e] (scatter, output) + ws_seq[ii*4+q] (sequential).
__global__ __launch_bounds__(256) void k_edge3(
    const ushortT* __restrict__ cABf, const ushortT* __restrict__ cABr,
    const int4* __restrict__ pos_f, const int4* __restrict__ pos_r,
    const float4* __restrict__ efs_f, const float4* __restrict__ efs_r,
    const float* __restrict__ w1e_f, const float* __restrict__ w1e_r,
    const float* __restrict__ w2f, const float* __restrict__ w2r,
    float* __restrict__ s_seq, float* __restrict__ outRW,
    float* __restrict__ ws_seq, int hop) {
  int y = blockIdx.y;
  const ushortT* cAB = y ? cABr : cABf;
  const int4* pos = y ? pos_r : pos_f;
  const float4* efs = y ? efs_r : efs_f;
  const float* w1e = y ? w1e_r : w1e_f;
  const float* w2 = y ? w2r : w2f;
  __shared__ float w1e_s[8][128];
  __shared__ float w2_s[4][128];
  int t = threadIdx.x;
  for (int i = t; i < 1024; i += 256) w1e_s[i >> 7][i & 127] = w1e[i];
  for (int i = t; i < 512; i += 256) w2_s[i >> 7][i & 127] = w2[i];
  __syncthreads();
  int es = t >> 2, q = t & 3;
  size_t ii = (size_t)blockIdx.x * 64 + es;
  int4 pr = pos[ii];
  const ushortT* cA = cAB + (size_t)pr.y * 256;
  const ushortT* cBp = cAB + (size_t)pr.z * 256 + 128;
  float4 e0 = efs[2 * ii], e1 = efs[2 * ii + 1];
  float efv[8] = {e0.x, e0.y, e0.z, e0.w, e1.x, e1.y, e1.z, e1.w};
  float p[4] = {0.f, 0.f, 0.f, 0.f};
#pragma unroll
  for (int c = 0; c < 4; ++c) {
    int j = c * 32 + q * 8;
    uint4 ua4 = *(const uint4*)(cA + j);
    uint4 ub4 = *(const uint4*)(cBp + j);
    const uintT* au = (const uintT*)&ua4;
    const uintT* bu = (const uintT*)&ub4;
    float h[8];
#pragma unroll
    for (int i2 = 0; i2 < 4; ++i2) {
      h[2 * i2] = b2f_lo(au[i2]) + b2f_lo(bu[i2]);
      h[2 * i2 + 1] = b2f_hi(au[i2]) + b2f_hi(bu[i2]);
    }
#pragma unroll
    for (int f = 0; f < 8; ++f) {
      float ev = efv[f];
      float4 w0 = *(const float4*)(&w1e_s[f][j]);
      float4 w1v = *(const float4*)(&w1e_s[f][j + 4]);
      h[0] += ev * w0.x; h[1] += ev * w0.y; h[2] += ev * w0.z; h[3] += ev * w0.w;
      h[4] += ev * w1v.x; h[5] += ev * w1v.y; h[6] += ev * w1v.z; h[7] += ev * w1v.w;
    }
#pragma unroll
    for (int i2 = 0; i2 < 8; ++i2) h[i2] = fmaxf(h[i2], 0.f);
#pragma unroll
    for (int o = 0; o < 4; ++o) {
      float4 u0 = *(const float4*)(&w2_s[o][j]);
      float4 u1 = *(const float4*)(&w2_s[o][j + 4]);
      p[o] += h[0] * u0.x + h[1] * u0.y + h[2] * u0.z + h[3] * u0.w +
              h[4] * u1.x + h[5] * u1.y + h[6] * u1.z + h[7] * u1.w;
    }
  }
#pragma unroll
  for (int o = 0; o < 4; ++o) {
    p[o] += __shfl_xor(p[o], 1, 64);
    p[o] += __shfl_xor(p[o], 2, 64);
  }
  float pv = (q == 0) ? p[0] : (q == 1) ? p[1] : (q == 2) ? p[2] : p[3];
  if (y) {
    float sig = 1.f / (1.f + expf(-pv));
    outRW[(size_t)pr.x * (NHEAD * KHOP) + q * KHOP + hop] = sig;
    ws_seq[ii * 4 + q] = sig;
  } else {
    s_seq[ii * 4 + q] = (pv > 0.f ? pv : 0.01f * pv) * 0.25f;
  }
}

// ---- fused softmax (SM=1) + aggregate + proj + residual (wave per node) ----
template <int SM>
__global__ __launch_bounds__(256) void k_softagg(
    const ushortT* __restrict__ hn_bf, const float* __restrict__ s_seq,
    const float* __restrict__ ws_seq, int hop, const int* __restrict__ rp,
    const int4* __restrict__ pos, const float* __restrict__ proj,
    float* __restrict__ h, float* __restrict__ wout) {
  __shared__ float proj_s[64][68];
  __shared__ float agg_s[4][64];
  __shared__ float w_s[4][64][4];
  int t = threadIdx.x;
  for (int i = t; i < 4096; i += 256) proj_s[i >> 6][i & 63] = proj[i];
  int wvi = t >> 6, lane = t & 63;
  int node = blockIdx.x * 4 + wvi;
  __syncthreads();

  float acc = 0.f;
  if (node < NN) {
    int beg = rp[node], end = rp[node + 1];
    int deg = end - beg;
    float mxv = 0.f, invv = 0.f;
    if (SM && deg > 0) {
      int li = lane >> 2, o = lane & 3;
      if (deg <= 64) {
        int i0 = beg + li;
        int ee4[4];
        float sv[4];
#pragma unroll
        for (int u = 0; u < 4; ++u) {
          int idx = i0 + u * 16;
          bool val = idx < end;
          int id2 = val ? idx : beg;
          ee4[u] = pos[id2].x;
          float v = s_seq[(size_t)id2 * 4 + o];
          sv[u] = val ? v : -1e30f;
        }
        float mx = fmaxf(fmaxf(sv[0], sv[1]), fmaxf(sv[2], sv[3]));
#pragma unroll
        for (int m = 4; m <= 32; m <<= 1) mx = fmaxf(mx, __shfl_xor(mx, m, 64));
        float ex[4];
        float sum = 0.f;
#pragma unroll
        for (int u = 0; u < 4; ++u) {
          ex[u] = (sv[u] > -1e29f) ? expf(sv[u] - mx) : 0.f;
          sum += ex[u];
        }
#pragma unroll
        for (int m = 4; m <= 32; m <<= 1) sum += __shfl_xor(sum, m, 64);
        float inv = 1.f / (sum + 1e-9f);
#pragma unroll
        for (int u = 0; u < 4; ++u) {
          if (i0 + u * 16 < end) {
            float wv = ex[u] * inv;
            wout[(size_t)ee4[u] * (NHEAD * KHOP) + o * KHOP + hop] = wv;
            w_s[wvi][li + u * 16][o] = wv;
          }
        }
      } else {
        float mx = -1e30f;
        for (int ii = beg + li; ii < end; ii += 16)
          mx = fmaxf(mx, s_seq[(size_t)ii * 4 + o]);
#pragma unroll
        for (int m = 4; m <= 32; m <<= 1) mx = fmaxf(mx, __shfl_xor(mx, m, 64));
        float sum = 0.f;
        for (int ii = beg + li; ii < end; ii += 16)
          sum += expf(s_seq[(size_t)ii * 4 + o] - mx);
#pragma unroll
        for (int m = 4; m <= 32; m <<= 1) sum += __shfl_xor(sum, m, 64);
        float inv = 1.f / (sum + 1e-9f);
        for (int ii = beg + li; ii < end; ii += 16) {
          wout[(size_t)pos[ii].x * (NHEAD * KHOP) + o * KHOP + hop] =
              expf(s_seq[(size_t)ii * 4 + o] - mx) * inv;
        }
        mxv = mx;
        invv = inv;
      }
    }
    // aggregate phase
    int hd = lane >> 4;
    float mx_hd = 0.f, inv_hd = 0.f;
    if (SM) {
      mx_hd = __shfl(mxv, hd, 64);
      inv_hd = __shfl(invv, hd, 64);
    }
    bool useLds = (deg <= 64);
    for (int ii = beg; ii < end; ii += 8) {
      int idxv[8];
      int other[8];
      float wv8[8];
      float hv[8];
#pragma unroll
      for (int u = 0; u < 8; ++u) {
        int idx = ii + u;
        idxv[u] = (idx < end) ? idx : beg;
      }
#pragma unroll
      for (int u = 0; u < 8; ++u) other[u] = pos[idxv[u]].y;
#pragma unroll
      for (int u = 0; u < 8; ++u) {
        if (SM) {
          if (useLds)
            wv8[u] = w_s[wvi][idxv[u] - beg][hd];
          else
            wv8[u] = expf(s_seq[(size_t)idxv[u] * 4 + hd] - mx_hd) * inv_hd;
        } else {
          wv8[u] = ws_seq[(size_t)idxv[u] * 4 + hd];
        }
      }
#pragma unroll
      for (int u = 0; u < 8; ++u)
        hv[u] = b2f(hn_bf[(size_t)other[u] * KP + lane]);
#pragma unroll
      for (int u = 0; u < 8; ++u) {
        float w = (ii + u < end) ? wv8[u] : 0.f;
        acc += w * hv[u];
      }
    }
  }
  agg_s[wvi][lane] = acc;
  __syncthreads();
  if (node < NN) {
    float m = 0.f;
#pragma unroll
    for (int hh = 0; hh < 64; hh += 4) {
      float4 p = *(const float4*)(&proj_s[lane][hh]);
      m += p.x * agg_s[wvi][hh] + p.y * agg_s[wvi][hh + 1] +
           p.z * agg_s[wvi][hh + 2] + p.w * agg_s[wvi][hh + 3];
    }
    h[(size_t)node * HH + lane] += m;
  }
}

// ---------------- gating phase ----------------
__global__ void k_gatein(const float* __restrict__ x, const float* __restrict__ hf,
                         const float* __restrict__ hr, ushortT* __restrict__ gi) {
  int g = blockIdx.x * 256 + threadIdx.x;
  if (g >= NN * HH) return;
  int node = g >> 6, j = g & 63;
  float xv = x[g];
  gi[(size_t)node * GIN + j] = f2b(xv);
  gi[(size_t)node * GIN + 64 + j] = f2b(hf[g] - xv);
  gi[(size_t)node * GIN + 128 + j] = f2b(hr[g] - xv);
}

__global__ void k_candin(const float* __restrict__ x, const float* __restrict__ r,
                         ushortT* __restrict__ gi) {
  int g = blockIdx.x * 256 + threadIdx.x;
  if (g >= NN * HH) return;
  gi[(size_t)(g >> 6) * GIN + (g & 63)] = f2b(r[g] * x[g]);
}

extern "C" void kernel_launch(void* const* d_in, const int* in_sizes, int n_in,
                              void* d_out, int out_size, void* d_ws, size_t ws_size,
                              hipStream_t stream) {
  const float* x = (const float*)d_in[0];
  const float* xs = (const float*)d_in[1];
  const int* ei = (const int*)d_in[2];
  const float* ef = (const float*)d_in[3];
  const float* fw1 = (const float*)d_in[4];
  const float* fw2 = (const float*)d_in[5];
  const float* fpj = (const float*)d_in[6];
  const float* rw1 = (const float*)d_in[7];
  const float* rw2 = (const float*)d_in[8];
  const float* rpj = (const float*)d_in[9];
  const float* lnw = (const float*)d_in[10];
  const float* lnb = (const float*)d_in[11];
  const float* r_w1 = (const float*)d_in[12];
  const float* r_b1 = (const float*)d_in[13];
  const float* r_w2 = (const float*)d_in[14];
  const float* r_b2 = (const float*)d_in[15];
  const float* z_w1 = (const float*)d_in[16];
  const float* z_b1 = (const float*)d_in[17];
  const float* z_w2 = (const float*)d_in[18];
  const float* z_b2 = (const float*)d_in[19];
  const float* c_w1 = (const float*)d_in[20];
  const float* c_b1 = (const float*)d_in[21];
  const float* c_w2 = (const float*)d_in[22];
  const float* c_b2 = (const float*)d_in[23];
  const int* srcp = ei;
  const int* dstp = ei + EE;

  float* outF = (float*)d_out;
  float* outFW = outF + (size_t)NN * HH;
  float* outRW = outFW + (size_t)EE * NHEAD * KHOP;
  float* outZ = outRW + (size_t)EE * NHEAD * KHOP;
  float* outR = outZ + (size_t)NN * HH;

  char* Wb = (char*)d_ws;
  size_t off = 0;
  auto alloc = [&](size_t bytes) -> void* {
    void* p = Wb + off;
    off += (bytes + 255) & ~(size_t)255;
    return p;
  };
  float* h_fwd = (float*)alloc((size_t)NN * HH * 4);
  float* h_rev = (float*)alloc((size_t)NN * HH * 4);
  ushortT* ncat_f = (ushortT*)alloc((size_t)NN * KP * 2);
  ushortT* ncat_r = (ushortT*)alloc((size_t)NN * KP * 2);
  float* s_seq = (float*)alloc((size_t)EE * NHEAD * 4);
  float* ws_seq = (float*)alloc((size_t)EE * NHEAD * 4);
  char* big = (char*)alloc((size_t)2 * NN * 256 * 2);
  ushortT* cAB_f = (ushortT*)big;
  ushortT* cAB_r = (ushortT*)(big + (size_t)NN * 256 * 2);
  ushortT* hid_bf = (ushortT*)big;
  ushortT* gi_bf = (ushortT*)alloc((size_t)NN * GIN * 2);
  ushortT* packAB_bf = (ushortT*)alloc((size_t)4 * 256 * KP * 2);
  float* packE = (float*)alloc((size_t)4 * 8 * 128 * 4);
  ushortT* rzw1_bf = (ushortT*)alloc((size_t)384 * GIN * 2);
  ushortT* rw2_bf = (ushortT*)alloc((size_t)HH * GIN * 2);
  ushortT* zw2_bf = (ushortT*)alloc((size_t)HH * GIN * 2);
  ushortT* cw1_bf = (ushortT*)alloc((size_t)GIN * GIN * 2);
  ushortT* cw2_bf = (ushortT*)alloc((size_t)HH * GIN * 2);
  float* rz_b1 = (float*)alloc(384 * 4);
  int* rp_d = (int*)alloc((NN + 8) * 4);
  int* rp_s = (int*)alloc((NN + 8) * 4);
  int* cur2 = (int*)alloc((size_t)2 * NN * 4);
  int* cur_d = cur2;
  int* cur_s = cur2 + NN;
  int* eid_d = (int*)alloc((size_t)EE * 4);
  int* eid_s = (int*)alloc((size_t)EE * 4);
  int4* pos_f = (int4*)alloc((size_t)EE * 16);
  int4* pos_r = (int4*)alloc((size_t)EE * 16);
  float4* efs_f = (float4*)alloc((size_t)EE * 32);
  float4* efs_r = (float4*)alloc((size_t)EE * 32);

  (void)hipMemcpyAsync(h_fwd, x, (size_t)NN * HH * 4, hipMemcpyDeviceToDevice, stream);
  (void)hipMemcpyAsync(h_rev, x, (size_t)NN * HH * 4, hipMemcpyDeviceToDevice, stream);
  (void)hipMemcpyAsync(rz_b1, r_b1, GIN * 4, hipMemcpyDeviceToDevice, stream);
  (void)hipMemcpyAsync(rz_b1 + GIN, z_b1, GIN * 4, hipMemcpyDeviceToDevice, stream);

  const int EB = (EE + 255) / 256, NW = (NN + 3) / 4;
  const int PB = (PACKN + 255) / 256;

  // weight repacks
  dim3 gPack(PB, 4);
  k_pack_bf<<<gPack, 256, 0, stream>>>(fw1, rw1, packAB_bf, packE);
  k_cvt6<<<(3 * CW1 + 3 * CW2 + 255) / 256, 256, 0, stream>>>(
      r_w1, z_w1, c_w1, r_w2, z_w2, c_w2, rzw1_bf, cw1_bf, rw2_bf, zw2_bf, cw2_bf);

  // CSR build (both directions)
  (void)hipMemsetAsync(cur2, 0, (size_t)2 * NN * 4, stream);
  k_histo2<<<EB, 256, 0, stream>>>(srcp, dstp, cur_s, cur_d);
  k_scan2<<<2, 1024, 0, stream>>>(cur_d, cur_s, rp_d, rp_s);
  (void)hipMemsetAsync(cur2, 0, (size_t)2 * NN * 4, stream);
  k_scatter2<<<EB, 256, 0, stream>>>(srcp, dstp, rp_s, rp_d, cur_s, cur_d, eid_s, eid_d);
  k_sortseg2<<<(2 * NN + 3) / 4, 256, 0, stream>>>(rp_d, rp_s, eid_d, eid_s);
  k_mkpos2<<<EB, 256, 0, stream>>>(eid_d, eid_s, srcp, dstp, ef, pos_f, pos_r, efs_f, efs_r);

  const int MB64 = (NN + 63) / 64;  // 391
  dim3 gLN(NW, 2), gProj(MB64, 2), gEdge(EE / 64, 2);
  for (int k = 0; k < KHOP; ++k) {
    k_ln2<<<gLN, 256, 0, stream>>>(h_fwd, h_rev, xs, lnw, lnb, ncat_f, ncat_r);
    k_proj2<<<gProj, 256, 0, stream>>>(ncat_f, ncat_r,
                                       packAB_bf + (size_t)k * 256 * KP,
                                       packAB_bf + (size_t)(2 + k) * 256 * KP,
                                       cAB_f, cAB_r);
    k_edge3<<<gEdge, 256, 0, stream>>>(cAB_f, cAB_r, pos_f, pos_r, efs_f, efs_r,
                                       packE + (size_t)k * 8 * 128,
                                       packE + (size_t)(2 + k) * 8 * 128,
                                       fw2 + (size_t)k * NHEAD * WID,
                                       rw2 + (size_t)k * NHEAD * WID,
                                       s_seq, outRW, ws_seq, k);
    k_softagg<1><<<NW, 256, 0, stream>>>(ncat_f, s_seq, nullptr, k, rp_d, pos_f,
                                         fpj + (size_t)k * HH * HH, h_fwd, outFW);
    k_softagg<0><<<NW, 256, 0, stream>>>(ncat_r, nullptr, ws_seq, k, rp_s, pos_r,
                                         rpj + (size_t)k * HH * HH, h_rev, nullptr);
  }

  // gating
  k_gatein<<<(NN * HH) / 256, 256, 0, stream>>>(x, h_fwd, h_rev, gi_bf);
  k_gemm2<1, 1, GIN><<<MB64, 256, 0, stream>>>(gi_bf, GIN, rzw1_bf, rz_b1, hid_bf,
                                               384, NN, 384, nullptr, nullptr);
  dim3 gRZ(MB64, 2);
  k_gemm_rz<<<gRZ, 256, 0, stream>>>(hid_bf, rw2_bf, zw2_bf, r_b2, z_b2, outR, outZ);
  k_candin<<<(NN * HH) / 256, 256, 0, stream>>>(x, outR, gi_bf);
  k_gemm2<1, 1, GIN><<<MB64, 256, 0, stream>>>(gi_bf, GIN, cw1_bf, c_b1, hid_bf, GIN,
                                               NN, GIN, nullptr, nullptr);
  k_gemm2<5, 0, GIN><<<MB64, 256, 0, stream>>>(hid_bf, GIN, cw2_bf, c_b2, outF, HH,
                                               NN, HH, outZ, x);
}

// Round 11
// 547.044 us; speedup vs baseline: 9.0485x; 1.1141x over previous
//
#include <hip/hip_runtime.h>
#include <hip/hip_fp16.h>
#include <math.h>

#define NN 25000
#define EE 400000
#define HH 64
#define NHEAD 4
#define SDIM 16
#define EFDIM 8
#define KHOP 2
#define MIN 168   // 2H + 2S + EF
#define WID 128
#define GIN 192
#define KP 96     // padded K for node-proj GEMM (80 -> 96)

typedef __attribute__((ext_vector_type(8))) short bf16x8;
typedef __attribute__((ext_vector_type(4))) float f32x4;
typedef unsigned short ushortT;
typedef unsigned int uintT;

__device__ __forceinline__ float wave_sum64(float v) {
#pragma unroll
  for (int m = 1; m <= 32; m <<= 1) v += __shfl_xor(v, m, 64);
  return v;
}

__device__ __forceinline__ ushortT f2b(float f) {
  uintT u = __float_as_uint(f);
  return (ushortT)((u + 0x7FFFu + ((u >> 16) & 1u)) >> 16);
}
__device__ __forceinline__ float b2f(ushortT h) {
  return __uint_as_float(((uintT)h) << 16);
}

union U4H8 {
  uint4 u;
  __half2 h[4];
};

// packed-f16 ReLU via sign-bit mask (no __hmax2 on ROCm 7.2)
__device__ __forceinline__ __half2 relu2(__half2 v) {
  union { __half2 h; uintT u; } x;
  x.h = v;
  uintT mask = ((x.u & 0x80008000u) >> 15) * 0xFFFFu;
  x.u &= ~mask;
  return x.h;
}

// ---------------- CSR build (both directions in one pass) ----------------
__global__ void k_histo2(const int* __restrict__ src, const int* __restrict__ dst,
                         int* __restrict__ cnt_s, int* __restrict__ cnt_d) {
  int e = blockIdx.x * 256 + threadIdx.x;
  if (e < EE) {
    atomicAdd(&cnt_d[dst[e]], 1);
    atomicAdd(&cnt_s[src[e]], 1);
  }
}

__global__ void k_scan2(const int* __restrict__ cnt_d, const int* __restrict__ cnt_s,
                        int* __restrict__ rp_d, int* __restrict__ rp_s) {
  const int* cnt = blockIdx.x ? cnt_s : cnt_d;
  int* rp = blockIdx.x ? rp_s : rp_d;
  __shared__ int part[1024];
  int t = threadIdx.x;
  const int CH = (NN + 1023) / 1024;
  int base = t * CH;
  int s = 0;
  for (int i = 0; i < CH; ++i) {
    int j = base + i;
    if (j < NN) s += cnt[j];
  }
  part[t] = s;
  __syncthreads();
  for (int off = 1; off < 1024; off <<= 1) {
    int v = (t >= off) ? part[t - off] : 0;
    __syncthreads();
    part[t] += v;
    __syncthreads();
  }
  int run = (t == 0) ? 0 : part[t - 1];
  for (int i = 0; i < CH; ++i) {
    int j = base + i;
    if (j < NN) { rp[j] = run; run += cnt[j]; }
  }
  if (t == 1023) rp[NN] = run;
}

__global__ void k_scatter2(const int* __restrict__ src, const int* __restrict__ dst,
                           const int* __restrict__ rp_s, const int* __restrict__ rp_d,
                           int* __restrict__ cur_s, int* __restrict__ cur_d,
                           int* __restrict__ eid_s, int* __restrict__ eid_d) {
  int e = blockIdx.x * 256 + threadIdx.x;
  if (e < EE) {
    int nd = dst[e];
    int pd = atomicAdd(&cur_d[nd], 1);
    eid_d[rp_d[nd] + pd] = e;
    int ns = src[e];
    int ps = atomicAdd(&cur_s[ns], 1);
    eid_s[rp_s[ns] + ps] = e;
  }
}

// wave-parallel bitonic sort of each segment (deterministic ascending order)
__global__ __launch_bounds__(256) void k_sortseg2(const int* __restrict__ rp_d,
                                                  const int* __restrict__ rp_s,
                                                  int* __restrict__ eid_d,
                                                  int* __restrict__ eid_s) {
  int gw = blockIdx.x * 4 + (threadIdx.x >> 6);
  int lane = threadIdx.x & 63;
  if (gw >= 2 * NN) return;
  const int* rp = (gw < NN) ? rp_d : rp_s;
  int* eids = (gw < NN) ? eid_d : eid_s;
  int node = (gw < NN) ? gw : gw - NN;
  int beg = rp[node], end = rp[node + 1];
  int deg = end - beg;
  if (deg <= 1) return;
  if (deg <= 64) {
    int v = (lane < deg) ? eids[beg + lane] : 0x7fffffff;
#pragma unroll
    for (int k = 2; k <= 64; k <<= 1) {
#pragma unroll
      for (int j = k >> 1; j > 0; j >>= 1) {
        int other = __shfl_xor(v, j, 64);
        bool takeMin = (((lane & k) == 0) == ((lane & j) == 0));
        v = takeMin ? min(v, other) : max(v, other);
      }
    }
    if (lane < deg) eids[beg + lane] = v;
  } else if (lane == 0) {
    for (int i = beg + 1; i < end; ++i) {
      int v = eids[i];
      int j = i - 1;
      while (j >= beg && eids[j] > v) { eids[j + 1] = eids[j]; --j; }
      eids[j + 1] = v;
    }
  }
}

// pos[ii] = {e, other_node, owner_node, 0}; position-ordered ef packed f16 (uint4)
__global__ void k_mkpos2(const int* __restrict__ eid_d, const int* __restrict__ eid_s,
                         const int* __restrict__ src, const int* __restrict__ dst,
                         const float* __restrict__ ef, int4* __restrict__ pos_f,
                         int4* __restrict__ pos_r, uint4* __restrict__ efh_f,
                         uint4* __restrict__ efh_r) {
  int i = blockIdx.x * 256 + threadIdx.x;
  if (i >= EE) return;
  int e1 = eid_d[i];
  pos_f[i] = make_int4(e1, src[e1], dst[e1], 0);
  int e2 = eid_s[i];
  pos_r[i] = make_int4(e2, dst[e2], src[e2], 0);
  {
    float4 a0 = *(const float4*)(ef + (size_t)e1 * EFDIM);
    float4 a1 = *(const float4*)(ef + (size_t)e1 * EFDIM + 4);
    U4H8 u;
    u.h[0] = __floats2half2_rn(a0.x, a0.y);
    u.h[1] = __floats2half2_rn(a0.z, a0.w);
    u.h[2] = __floats2half2_rn(a1.x, a1.y);
    u.h[3] = __floats2half2_rn(a1.z, a1.w);
    efh_f[i] = u.u;
  }
  {
    float4 b0 = *(const float4*)(ef + (size_t)e2 * EFDIM);
    float4 b1 = *(const float4*)(ef + (size_t)e2 * EFDIM + 4);
    U4H8 u;
    u.h[0] = __floats2half2_rn(b0.x, b0.y);
    u.h[1] = __floats2half2_rn(b0.z, b0.w);
    u.h[2] = __floats2half2_rn(b1.x, b1.y);
    u.h[3] = __floats2half2_rn(b1.z, b1.w);
    efh_r[i] = u.u;
  }
}

// ---- weight repack: pAB bf16[256][96] + w1e2 half2[8][64] + w22 half2[4][64] ----
#define PACKN (256 * KP + 512 + 256)
__global__ void k_pack_bf(const float* __restrict__ fw1, const float* __restrict__ rw1,
                          const float* __restrict__ fw2, const float* __restrict__ rw2,
                          ushortT* __restrict__ pAB_all, __half2* __restrict__ w1e2_all,
                          __half2* __restrict__ w22_all) {
  int y = blockIdx.y;
  const float* w1 = (y < 2) ? fw1 + (size_t)y * WID * MIN
                            : rw1 + (size_t)(y - 2) * WID * MIN;
  const float* w2 = (y < 2) ? fw2 + (size_t)y * NHEAD * WID
                            : rw2 + (size_t)(y - 2) * NHEAD * WID;
  int i = blockIdx.x * 256 + threadIdx.x;
  if (i < 256 * KP) {
    int j = i / KP, k = i % KP;
    float v = 0.f;
    if (k < 80) {
      int row = (j < 128) ? j : j - 128;
      int col = (j < 128) ? (k < 64 ? k : k + 64) : (k < 64 ? k + 64 : k + 80);
      v = w1[row * MIN + col];
    }
    pAB_all[(size_t)y * 256 * KP + i] = f2b(v);
  } else if (i < 256 * KP + 512) {
    int jj = i - 256 * KP;
    int f = jj >> 6, jp = jj & 63;
    // w1e[f][j] = w1[j*MIN + 160 + f]
    w1e2_all[y * 512 + jj] =
        __floats2half2_rn(w1[(2 * jp) * MIN + 160 + f], w1[(2 * jp + 1) * MIN + 160 + f]);
  } else if (i < PACKN) {
    int jj = i - 256 * KP - 512;
    int o = jj >> 6, jp = jj & 63;
    w22_all[y * 256 + jj] = __floats2half2_rn(w2[o * WID + 2 * jp], w2[o * WID + 2 * jp + 1]);
  }
}

// fused conversion of all gating weights to bf16
#define CW1 (GIN * GIN)   // 36864
#define CW2 (HH * GIN)    // 12288
__global__ void k_cvt6(const float* __restrict__ r_w1, const float* __restrict__ z_w1,
                       const float* __restrict__ c_w1, const float* __restrict__ r_w2,
                       const float* __restrict__ z_w2, const float* __restrict__ c_w2,
                       ushortT* __restrict__ rzw1, ushortT* __restrict__ cw1,
                       ushortT* __restrict__ rw2, ushortT* __restrict__ zw2,
                       ushortT* __restrict__ cw2) {
  int i = blockIdx.x * 256 + threadIdx.x;
  if (i < CW1) rzw1[i] = f2b(r_w1[i]);
  else if (i < 2 * CW1) rzw1[i] = f2b(z_w1[i - CW1]);
  else if (i < 3 * CW1) cw1[i - 2 * CW1] = f2b(c_w1[i - 2 * CW1]);
  else if (i < 3 * CW1 + CW2) rw2[i - 3 * CW1] = f2b(r_w2[i - 3 * CW1]);
  else if (i < 3 * CW1 + 2 * CW2) zw2[i - 3 * CW1 - CW2] = f2b(z_w2[i - 3 * CW1 - CW2]);
  else if (i < 3 * CW1 + 3 * CW2) cw2[i - 3 * CW1 - 2 * CW2] = f2b(c_w2[i - 3 * CW1 - 2 * CW2]);
}

// ---- initial LayerNorm (h = x for both dirs): writes ncat0_{f,r}; xs/pad into all 4 ----
__global__ __launch_bounds__(256) void k_ln_init(
    const float* __restrict__ x, const float* __restrict__ xs,
    const float* __restrict__ lw, const float* __restrict__ lb,
    ushortT* __restrict__ ncf0, ushortT* __restrict__ ncr0,
    ushortT* __restrict__ ncf1, ushortT* __restrict__ ncr1) {
  int t = threadIdx.x;
  int node = blockIdx.x * 4 + (t >> 6), lane = t & 63;
  if (node >= NN) return;
  float v = x[(size_t)node * HH + lane];
  float mean = wave_sum64(v) * (1.0f / 64.0f);
  float d = v - mean;
  float var = wave_sum64(d * d) * (1.0f / 64.0f);
  ushortT val = f2b(d * rsqrtf(var + 1e-5f) * lw[lane] + lb[lane]);
  ncf0[(size_t)node * KP + lane] = val;
  ncr0[(size_t)node * KP + lane] = val;
  if (lane < SDIM) {
    ushortT xv = f2b(xs[(size_t)node * SDIM + lane]);
    ncf0[(size_t)node * KP + HH + lane] = xv;
    ncr0[(size_t)node * KP + HH + lane] = xv;
    ncf1[(size_t)node * KP + HH + lane] = xv;
    ncr1[(size_t)node * KP + HH + lane] = xv;
    ncf0[(size_t)node * KP + 80 + lane] = 0;
    ncr0[(size_t)node * KP + 80 + lane] = 0;
    ncf1[(size_t)node * KP + 80 + lane] = 0;
    ncr1[(size_t)node * KP + 80 + lane] = 0;
  }
}

// ------- node projection GEMM, both dirs: C = A[NN,96] @ W[256,96]^T (f16 out) -----
__global__ __launch_bounds__(256) void k_proj2(
    const ushortT* __restrict__ Af, const ushortT* __restrict__ Ar,
    const ushortT* __restrict__ Wf, const ushortT* __restrict__ Wr,
    ushortT* __restrict__ Cf, ushortT* __restrict__ Cr) {
  const ushortT* A = blockIdx.y ? Ar : Af;
  const ushortT* W = blockIdx.y ? Wr : Wf;
  ushortT* C = blockIdx.y ? Cr : Cf;
  int w = threadIdx.x >> 6, l = threadIdx.x & 63;
  int m0 = blockIdx.x * 64 + w * 16;
  int rowa = m0 + (l & 15);
  int kb = l >> 4;
  bf16x8 afr0 = {0,0,0,0,0,0,0,0}, afr1 = afr0, afr2 = afr0;
  if (rowa < NN) {
    const ushortT* ap = A + (size_t)rowa * KP + kb * 8;
    afr0 = *(const bf16x8*)(ap);
    afr1 = *(const bf16x8*)(ap + 32);
    afr2 = *(const bf16x8*)(ap + 64);
  }
  int crow = m0 + (l >> 4) * 4;
  int ccol0 = l & 15;
  for (int n0 = 0; n0 < 256; n0 += 64) {
    f32x4 acc[4];
#pragma unroll
    for (int n = 0; n < 4; ++n) acc[n] = (f32x4){0.f, 0.f, 0.f, 0.f};
    const ushortT* wbase = W + (size_t)(n0 + (l & 15)) * KP + kb * 8;
#pragma unroll
    for (int n = 0; n < 4; ++n) {
      const ushortT* wp = wbase + (size_t)(16 * n) * KP;
      acc[n] = __builtin_amdgcn_mfma_f32_16x16x32_bf16(afr0, *(const bf16x8*)(wp), acc[n], 0, 0, 0);
      acc[n] = __builtin_amdgcn_mfma_f32_16x16x32_bf16(afr1, *(const bf16x8*)(wp + 32), acc[n], 0, 0, 0);
      acc[n] = __builtin_amdgcn_mfma_f32_16x16x32_bf16(afr2, *(const bf16x8*)(wp + 64), acc[n], 0, 0, 0);
    }
#pragma unroll
    for (int n = 0; n < 4; ++n) {
      int col = n0 + ccol0 + n * 16;
#pragma unroll
      for (int r = 0; r < 4; ++r) {
        int row = crow + r;
        if (row < NN)
          C[(size_t)row * 256 + col] = __half_as_ushort(__float2half(acc[n][r]));
      }
    }
  }
}

// ------- generic MFMA GEMM; ACT 5 = fused GRU final: out=(1-z)x+z*tanh(v) ---------
template <int ACT, int BF16OUT, int KD>
__global__ __launch_bounds__(256) void k_gemm2(
    const ushortT* __restrict__ A, int lda, const ushortT* __restrict__ W,
    const float* __restrict__ bias, void* __restrict__ Cout, int ldc, int M, int Nc,
    const float* __restrict__ zv, const float* __restrict__ xp) {
  constexpr int KS = KD / 32;
  int w = threadIdx.x >> 6, l = threadIdx.x & 63;
  int m0 = blockIdx.x * 64 + w * 16;
  int rowa = m0 + (l & 15);
  int kb = l >> 4;
  bf16x8 afr[KS];
#pragma unroll
  for (int ks = 0; ks < KS; ++ks) {
    afr[ks] = (bf16x8){0, 0, 0, 0, 0, 0, 0, 0};
    if (rowa < M) afr[ks] = *(const bf16x8*)(A + (size_t)rowa * lda + ks * 32 + kb * 8);
  }
  int crow = m0 + (l >> 4) * 4;
  int ccol0 = l & 15;
  for (int n0 = 0; n0 < Nc; n0 += 64) {
    f32x4 acc[4];
#pragma unroll
    for (int n = 0; n < 4; ++n) acc[n] = (f32x4){0.f, 0.f, 0.f, 0.f};
    const ushortT* wbase = W + (size_t)(n0 + (l & 15)) * KD + kb * 8;
#pragma unroll
    for (int n = 0; n < 4; ++n) {
      const ushortT* wp = wbase + (size_t)(16 * n) * KD;
#pragma unroll
      for (int ks = 0; ks < KS; ++ks)
        acc[n] = __builtin_amdgcn_mfma_f32_16x16x32_bf16(afr[ks], *(const bf16x8*)(wp + ks * 32),
                                                         acc[n], 0, 0, 0);
    }
#pragma unroll
    for (int n = 0; n < 4; ++n) {
      int col = n0 + ccol0 + n * 16;
      float bv = bias ? bias[col] : 0.f;
#pragma unroll
      for (int r = 0; r < 4; ++r) {
        int row = crow + r;
        if (row < M) {
          float v = acc[n][r] + bv;
          if (ACT == 1) v = fmaxf(v, 0.f);
          else if (ACT == 2) v = 1.f / (1.f + expf(-v));
          else if (ACT == 3) v = tanhf(v);
          else if (ACT == 5) {
            float z = zv[(size_t)row * HH + col];
            float xv = xp[(size_t)row * HH + col];
            v = (1.f - z) * xv + z * tanhf(v);
          }
          if (BF16OUT)
            ((ushortT*)Cout)[(size_t)row * ldc + col] = f2b(v);
          else
            ((float*)Cout)[(size_t)row * ldc + col] = v;
        }
      }
    }
  }
}

// dual r2/z2 second-layer gemm (sigmoid): y=0 -> outR + gi[0:64]=r*x ; y=1 -> outZ
__global__ __launch_bounds__(256) void k_gemm_rz(
    const ushortT* __restrict__ hid, const ushortT* __restrict__ rw2,
    const ushortT* __restrict__ zw2, const float* __restrict__ rb2,
    const float* __restrict__ zb2, float* __restrict__ outR, float* __restrict__ outZ,
    const float* __restrict__ x, ushortT* __restrict__ gi) {
  int y = blockIdx.y;
  const ushortT* A = hid + (y ? GIN : 0);
  const ushortT* W = y ? zw2 : rw2;
  const float* bias = y ? zb2 : rb2;
  float* C = y ? outZ : outR;
  constexpr int KS = GIN / 32;
  int w = threadIdx.x >> 6, l = threadIdx.x & 63;
  int m0 = blockIdx.x * 64 + w * 16;
  int rowa = m0 + (l & 15);
  int kb = l >> 4;
  bf16x8 afr[KS];
#pragma unroll
  for (int ks = 0; ks < KS; ++ks) {
    afr[ks] = (bf16x8){0, 0, 0, 0, 0, 0, 0, 0};
    if (rowa < NN) afr[ks] = *(const bf16x8*)(A + (size_t)rowa * 384 + ks * 32 + kb * 8);
  }
  int crow = m0 + (l >> 4) * 4;
  int ccol0 = l & 15;
  f32x4 acc[4];
#pragma unroll
  for (int n = 0; n < 4; ++n) acc[n] = (f32x4){0.f, 0.f, 0.f, 0.f};
  const ushortT* wbase = W + (size_t)(l & 15) * GIN + kb * 8;
#pragma unroll
  for (int n = 0; n < 4; ++n) {
    const ushortT* wp = wbase + (size_t)(16 * n) * GIN;
#pragma unroll
    for (int ks = 0; ks < KS; ++ks)
      acc[n] = __builtin_amdgcn_mfma_f32_16x16x32_bf16(afr[ks], *(const bf16x8*)(wp + ks * 32),
                                                       acc[n], 0, 0, 0);
  }
#pragma unroll
  for (int n = 0; n < 4; ++n) {
    int col = ccol0 + n * 16;
    float bv = bias[col];
#pragma unroll
    for (int r = 0; r < 4; ++r) {
      int row = crow + r;
      if (row < NN) {
        float v = acc[n][r] + bv;
        float sig = 1.f / (1.f + expf(-v));
        C[(size_t)row * HH + col] = sig;
        if (y == 0)  // fused candin: gi[0:64] = r * x
          gi[(size_t)row * GIN + col] = f2b(sig * x[(size_t)row * HH + col]);
      }
    }
  }
}

// ------- edge combine, CSR-position-ordered, both dirs, packed f16 math -----------
// hidden = relu(cA[other] + cB[owner] + W1e.ef);  p = hidden @ w2^T
// y=0 (fwd): s_seq[ii*4+q] = leaky(p)/4 (sequential).
// y=1 (rev): sig -> outRW[e] (scatter, output) + ws_seq[ii*4+q] (sequential).
__global__ __launch_bounds__(256) void k_edge3(
    const ushortT* __restrict__ cABf, const ushortT* __restrict__ cABr,
    const int4* __restrict__ pos_f, const int4* __restrict__ pos_r,
    const uint4* __restrict__ efh_f, const uint4* __restrict__ efh_r,
    const __half2* __restrict__ w1e2_f, const __half2* __restrict__ w1e2_r,
    const __half2* __restrict__ w22_f, const __half2* __restrict__ w22_r,
    float* __restrict__ s_seq, float* __restrict__ outRW,
    float* __restrict__ ws_seq, int hop) {
  int y = blockIdx.y;
  const __half2* cAB2 = (const __half2*)(y ? cABr : cABf);
  const int4* pos = y ? pos_r : pos_f;
  const uint4* efh = y ? efh_r : efh_f;
  const __half2* w1e2 = y ? w1e2_r : w1e2_f;
  const __half2* w22 = y ? w22_r : w22_f;
  __shared__ __half2 w1e2_s[8][64];
  __shared__ __half2 w22_s[4][64];
  int t = threadIdx.x;
  for (int i = t; i < 512; i += 256) w1e2_s[i >> 6][i & 63] = w1e2[i];
  if (t < 256) w22_s[t >> 6][t & 63] = w22[t];
  __syncthreads();
  int es = t >> 2, q = t & 3;
  size_t ii = (size_t)blockIdx.x * 64 + es;
  int4 pr = pos[ii];
  const __half2* cA2 = cAB2 + (size_t)pr.y * 128;
  const __half2* cB2 = cAB2 + (size_t)pr.z * 128 + 64;
  U4H8 efu;
  efu.u = efh[ii];
  __half2 efb[8];
#pragma unroll
  for (int f2v = 0; f2v < 4; ++f2v) {
    efb[2 * f2v] = __half2half2(__low2half(efu.h[f2v]));
    efb[2 * f2v + 1] = __half2half2(__high2half(efu.h[f2v]));
  }
  float pf[4] = {0.f, 0.f, 0.f, 0.f};
#pragma unroll
  for (int c = 0; c < 4; ++c) {
    int jp0 = c * 16 + q * 4;
    U4H8 ua, ub;
    ua.u = *(const uint4*)(cA2 + jp0);
    ub.u = *(const uint4*)(cB2 + jp0);
    __half2 h2v[4];
#pragma unroll
    for (int i2 = 0; i2 < 4; ++i2) h2v[i2] = __hadd2(ua.h[i2], ub.h[i2]);
#pragma unroll
    for (int f = 0; f < 8; ++f) {
      U4H8 wv;
      wv.u = *(const uint4*)(&w1e2_s[f][jp0]);
#pragma unroll
      for (int i2 = 0; i2 < 4; ++i2) h2v[i2] = __hfma2(efb[f], wv.h[i2], h2v[i2]);
    }
#pragma unroll
    for (int i2 = 0; i2 < 4; ++i2) h2v[i2] = relu2(h2v[i2]);
#pragma unroll
    for (int o = 0; o < 4; ++o) {
      U4H8 wv;
      wv.u = *(const uint4*)(&w22_s[o][jp0]);
      __half2 p2 = __hmul2(h2v[0], wv.h[0]);
      p2 = __hfma2(h2v[1], wv.h[1], p2);
      p2 = __hfma2(h2v[2], wv.h[2], p2);
      p2 = __hfma2(h2v[3], wv.h[3], p2);
      pf[o] += __low2float(p2) + __high2float(p2);
    }
  }
#pragma unroll
  for (int m = 1; m <= 2; m <<= 1) {
    pf[0] += __shfl_xor(pf[0], m, 64);
    pf[1] += __shfl_xor(pf[1], m, 64);
    pf[2] += __shfl_xor(pf[2], m, 64);
    pf[3] += __shfl_xor(pf[3], m, 64);
  }
  float pv = (q == 0) ? pf[0] : (q == 1) ? pf[1] : (q == 2) ? pf[2] : pf[3];
  if (y) {
    float sig = 1.f / (1.f + expf(-pv));
    outRW[(size_t)pr.x * (NHEAD * KHOP) + q * KHOP + hop] = sig;
    ws_seq[ii * 4 + q] = sig;
  } else {
    s_seq[ii * 4 + q] = (pv > 0.f ? pv : 0.01f * pv) * 0.25f;
  }
}

// ---- merged softmax/sigmoid + aggregate + proj + residual (+LN / +gatein) ----
// blockIdx.y = 0: fwd chain (softmax from s_seq, writes wout); 1: rev chain (ws_seq).
// DO_LN: epilogue computes LayerNorm of h_new -> ncat_next. DO_GATE: writes gi.
template <int DO_LN, int DO_GATE>
__global__ __launch_bounds__(256) void k_softagg3(
    const ushortT* __restrict__ ncf, const ushortT* __restrict__ ncr,
    ushortT* __restrict__ ncf_n, ushortT* __restrict__ ncr_n,
    const float* __restrict__ s_seq, const float* __restrict__ ws_seq, int hop,
    const int* __restrict__ rp_d, const int* __restrict__ rp_s,
    const int4* __restrict__ pos_f, const int4* __restrict__ pos_r,
    const float* __restrict__ proj_f, const float* __restrict__ proj_r,
    float* __restrict__ h_f, float* __restrict__ h_r, float* __restrict__ wout,
    const float* __restrict__ lnw, const float* __restrict__ lnb,
    const float* __restrict__ x, ushortT* __restrict__ gi) {
  int y = blockIdx.y;
  const ushortT* hn_bf = y ? ncr : ncf;
  const int* rp = y ? rp_s : rp_d;
  const int4* pos = y ? pos_r : pos_f;
  const float* proj = y ? proj_r : proj_f;
  float* h = y ? h_r : h_f;
  __shared__ float proj_s[64][68];
  __shared__ float agg_s[4][64];
  __shared__ float w_s[4][64][4];
  int t = threadIdx.x;
  for (int i = t; i < 4096; i += 256) proj_s[i >> 6][i & 63] = proj[i];
  int wvi = t >> 6, lane = t & 63;
  int node = blockIdx.x * 4 + wvi;
  __syncthreads();

  float acc = 0.f;
  int beg = 0, end = 0;
  if (node < NN) {
    beg = rp[node];
    end = rp[node + 1];
    int deg = end - beg;
    float mxv = 0.f, invv = 0.f;
    if (y == 0 && deg > 0) {
      int li = lane >> 2, o = lane & 3;
      if (deg <= 64) {
        int i0 = beg + li;
        int ee4[4];
        float sv[4];
#pragma unroll
        for (int u = 0; u < 4; ++u) {
          int idx = i0 + u * 16;
          bool val = idx < end;
          int id2 = val ? idx : beg;
          ee4[u] = pos[id2].x;
          float v = s_seq[(size_t)id2 * 4 + o];
          sv[u] = val ? v : -1e30f;
        }
        float mx = fmaxf(fmaxf(sv[0], sv[1]), fmaxf(sv[2], sv[3]));
#pragma unroll
        for (int m = 4; m <= 32; m <<= 1) mx = fmaxf(mx, __shfl_xor(mx, m, 64));
        float ex[4];
        float sum = 0.f;
#pragma unroll
        for (int u = 0; u < 4; ++u) {
          ex[u] = (sv[u] > -1e29f) ? expf(sv[u] - mx) : 0.f;
          sum += ex[u];
        }
#pragma unroll
        for (int m = 4; m <= 32; m <<= 1) sum += __shfl_xor(sum, m, 64);
        float inv = 1.f / (sum + 1e-9f);
#pragma unroll
        for (int u = 0; u < 4; ++u) {
          if (i0 + u * 16 < end) {
            float wv = ex[u] * inv;
            wout[(size_t)ee4[u] * (NHEAD * KHOP) + o * KHOP + hop] = wv;
            w_s[wvi][li + u * 16][o] = wv;
          }
        }
      } else {
        float mx = -1e30f;
        for (int ii = beg + li; ii < end; ii += 16)
          mx = fmaxf(mx, s_seq[(size_t)ii * 4 + o]);
#pragma unroll
        for (int m = 4; m <= 32; m <<= 1) mx = fmaxf(mx, __shfl_xor(mx, m, 64));
        float sum = 0.f;
        for (int ii = beg + li; ii < end; ii += 16)
          sum += expf(s_seq[(size_t)ii * 4 + o] - mx);
#pragma unroll
        for (int m = 4; m <= 32; m <<= 1) sum += __shfl_xor(sum, m, 64);
        float inv = 1.f / (sum + 1e-9f);
        for (int ii = beg + li; ii < end; ii += 16) {
          wout[(size_t)pos[ii].x * (NHEAD * KHOP) + o * KHOP + hop] =
              expf(s_seq[(size_t)ii * 4 + o] - mx) * inv;
        }
        mxv = mx;
        invv = inv;
      }
    }
    // aggregate phase
    int hd = lane >> 4;
    float mx_hd = 0.f, inv_hd = 0.f;
    if (y == 0) {
      mx_hd = __shfl(mxv, hd, 64);
      inv_hd = __shfl(invv, hd, 64);
    }
    bool useLds = ((end - beg) <= 64);
    for (int ii = beg; ii < end; ii += 8) {
      int idxv[8];
      int other[8];
      float wv8[8];
      float hv[8];
#pragma unroll
      for (int u = 0; u < 8; ++u) {
        int idx = ii + u;
        idxv[u] = (idx < end) ? idx : beg;
      }
#pragma unroll
      for (int u = 0; u < 8; ++u) other[u] = pos[idxv[u]].y;
#pragma unroll
      for (int u = 0; u < 8; ++u) {
        if (y == 0) {
          if (useLds)
            wv8[u] = w_s[wvi][idxv[u] - beg][hd];
          else
            wv8[u] = expf(s_seq[(size_t)idxv[u] * 4 + hd] - mx_hd) * inv_hd;
        } else {
          wv8[u] = ws_seq[(size_t)idxv[u] * 4 + hd];
        }
      }
#pragma unroll
      for (int u = 0; u < 8; ++u)
        hv[u] = b2f(hn_bf[(size_t)other[u] * KP + lane]);
#pragma unroll
      for (int u = 0; u < 8; ++u) {
        float w = (ii + u < end) ? wv8[u] : 0.f;
        acc += w * hv[u];
      }
    }
  }
  agg_s[wvi][lane] = acc;
  __syncthreads();
  if (node < NN) {
    float m = 0.f;
#pragma unroll
    for (int hh = 0; hh < 64; hh += 4) {
      float4 p = *(const float4*)(&proj_s[lane][hh]);
      m += p.x * agg_s[wvi][hh] + p.y * agg_s[wvi][hh + 1] +
           p.z * agg_s[wvi][hh + 2] + p.w * agg_s[wvi][hh + 3];
    }
    size_t g = (size_t)node * HH + lane;
    float hnew = h[g] + m;
    h[g] = hnew;
    if (DO_LN) {
      float mean = wave_sum64(hnew) * (1.0f / 64.0f);
      float d = hnew - mean;
      float var = wave_sum64(d * d) * (1.0f / 64.0f);
      ushortT val = f2b(d * rsqrtf(var + 1e-5f) * lnw[lane] + lnb[lane]);
      (y ? ncr_n : ncf_n)[(size_t)node * KP + lane] = val;
    }
    if (DO_GATE) {
      float xv = x[g];
      if (y == 0) {
        gi[(size_t)node * GIN + lane] = f2b(xv);
        gi[(size_t)node * GIN + 64 + lane] = f2b(hnew - xv);
      } else {
        gi[(size_t)node * GIN + 128 + lane] = f2b(hnew - xv);
      }
    }
  }
}

extern "C" void kernel_launch(void* const* d_in, const int* in_sizes, int n_in,
                              void* d_out, int out_size, void* d_ws, size_t ws_size,
                              hipStream_t stream) {
  const float* x = (const float*)d_in[0];
  const float* xs = (const float*)d_in[1];
  const int* ei = (const int*)d_in[2];
  const float* ef = (const float*)d_in[3];
  const float* fw1 = (const float*)d_in[4];
  const float* fw2 = (const float*)d_in[5];
  const float* fpj = (const float*)d_in[6];
  const float* rw1 = (const float*)d_in[7];
  const float* rw2 = (const float*)d_in[8];
  const float* rpj = (const float*)d_in[9];
  const float* lnw = (const float*)d_in[10];
  const float* lnb = (const float*)d_in[11];
  const float* r_w1 = (const float*)d_in[12];
  const float* r_b1 = (const float*)d_in[13];
  const float* r_w2 = (const float*)d_in[14];
  const float* r_b2 = (const float*)d_in[15];
  const float* z_w1 = (const float*)d_in[16];
  const float* z_b1 = (const float*)d_in[17];
  const float* z_w2 = (const float*)d_in[18];
  const float* z_b2 = (const float*)d_in[19];
  const float* c_w1 = (const float*)d_in[20];
  const float* c_b1 = (const float*)d_in[21];
  const float* c_w2 = (const float*)d_in[22];
  const float* c_b2 = (const float*)d_in[23];
  const int* srcp = ei;
  const int* dstp = ei + EE;

  float* outF = (float*)d_out;
  float* outFW = outF + (size_t)NN * HH;
  float* outRW = outFW + (size_t)EE * NHEAD * KHOP;
  float* outZ = outRW + (size_t)EE * NHEAD * KHOP;
  float* outR = outZ + (size_t)NN * HH;

  char* Wb = (char*)d_ws;
  size_t off = 0;
  auto alloc = [&](size_t bytes) -> void* {
    void* p = Wb + off;
    off += (bytes + 255) & ~(size_t)255;
    return p;
  };
  float* h_fwd = (float*)alloc((size_t)NN * HH * 4);
  float* h_rev = (float*)alloc((size_t)NN * HH * 4);
  ushortT* ncat_f0 = (ushortT*)alloc((size_t)NN * KP * 2);
  ushortT* ncat_r0 = (ushortT*)alloc((size_t)NN * KP * 2);
  ushortT* ncat_f1 = (ushortT*)alloc((size_t)NN * KP * 2);
  ushortT* ncat_r1 = (ushortT*)alloc((size_t)NN * KP * 2);
  float* s_seq = (float*)alloc((size_t)EE * NHEAD * 4);
  float* ws_seq = (float*)alloc((size_t)EE * NHEAD * 4);
  char* big = (char*)alloc((size_t)2 * NN * 256 * 2);
  ushortT* cAB_f = (ushortT*)big;          // f16 during hops
  ushortT* cAB_r = (ushortT*)(big + (size_t)NN * 256 * 2);
  ushortT* hid_bf = (ushortT*)big;         // bf16 during gating
  ushortT* gi_bf = (ushortT*)alloc((size_t)NN * GIN * 2);
  ushortT* packAB_bf = (ushortT*)alloc((size_t)4 * 256 * KP * 2);
  __half2* w1e2h = (__half2*)alloc((size_t)4 * 512 * 4);
  __half2* w22h = (__half2*)alloc((size_t)4 * 256 * 4);
  ushortT* rzw1_bf = (ushortT*)alloc((size_t)384 * GIN * 2);
  ushortT* rw2_bf = (ushortT*)alloc((size_t)HH * GIN * 2);
  ushortT* zw2_bf = (ushortT*)alloc((size_t)HH * GIN * 2);
  ushortT* cw1_bf = (ushortT*)alloc((size_t)GIN * GIN * 2);
  ushortT* cw2_bf = (ushortT*)alloc((size_t)HH * GIN * 2);
  float* rz_b1 = (float*)alloc(384 * 4);
  int* rp_d = (int*)alloc((NN + 8) * 4);
  int* rp_s = (int*)alloc((NN + 8) * 4);
  int* cur2 = (int*)alloc((size_t)2 * NN * 4);
  int* cur_d = cur2;
  int* cur_s = cur2 + NN;
  int* eid_d = (int*)alloc((size_t)EE * 4);
  int* eid_s = (int*)alloc((size_t)EE * 4);
  int4* pos_f = (int4*)alloc((size_t)EE * 16);
  int4* pos_r = (int4*)alloc((size_t)EE * 16);
  uint4* efh_f = (uint4*)alloc((size_t)EE * 16);
  uint4* efh_r = (uint4*)alloc((size_t)EE * 16);

  (void)hipMemcpyAsync(h_fwd, x, (size_t)NN * HH * 4, hipMemcpyDeviceToDevice, stream);
  (void)hipMemcpyAsync(h_rev, x, (size_t)NN * HH * 4, hipMemcpyDeviceToDevice, stream);
  (void)hipMemcpyAsync(rz_b1, r_b1, GIN * 4, hipMemcpyDeviceToDevice, stream);
  (void)hipMemcpyAsync(rz_b1 + GIN, z_b1, GIN * 4, hipMemcpyDeviceToDevice, stream);

  const int EB = (EE + 255) / 256, NW = (NN + 3) / 4;
  const int PB = (PACKN + 255) / 256;

  // weight repacks
  dim3 gPack(PB, 4);
  k_pack_bf<<<gPack, 256, 0, stream>>>(fw1, rw1, fw2, rw2, packAB_bf, w1e2h, w22h);
  k_cvt6<<<(3 * CW1 + 3 * CW2 + 255) / 256, 256, 0, stream>>>(
      r_w1, z_w1, c_w1, r_w2, z_w2, c_w2, rzw1_bf, cw1_bf, rw2_bf, zw2_bf, cw2_bf);

  // CSR build (both directions)
  (void)hipMemsetAsync(cur2, 0, (size_t)2 * NN * 4, stream);
  k_histo2<<<EB, 256, 0, stream>>>(srcp, dstp, cur_s, cur_d);
  k_scan2<<<2, 1024, 0, stream>>>(cur_d, cur_s, rp_d, rp_s);
  (void)hipMemsetAsync(cur2, 0, (size_t)2 * NN * 4, stream);
  k_scatter2<<<EB, 256, 0, stream>>>(srcp, dstp, rp_s, rp_d, cur_s, cur_d, eid_s, eid_d);
  k_sortseg2<<<(2 * NN + 3) / 4, 256, 0, stream>>>(rp_d, rp_s, eid_d, eid_s);
  k_mkpos2<<<EB, 256, 0, stream>>>(eid_d, eid_s, srcp, dstp, ef, pos_f, pos_r, efh_f, efh_r);

  // initial LN (h = x for both chains)
  k_ln_init<<<NW, 256, 0, stream>>>(x, xs, lnw, lnb, ncat_f0, ncat_r0, ncat_f1, ncat_r1);

  const int MB64 = (NN + 63) / 64;  // 391
  dim3 gProj(MB64, 2), gEdge(EE / 64, 2), gAgg(NW, 2);
  for (int k = 0; k < KHOP; ++k) {
    const ushortT* nf = k ? ncat_f1 : ncat_f0;
    const ushortT* nr = k ? ncat_r1 : ncat_r0;
    k_proj2<<<gProj, 256, 0, stream>>>(nf, nr,
                                       packAB_bf + (size_t)k * 256 * KP,
                                       packAB_bf + (size_t)(2 + k) * 256 * KP,
                                       cAB_f, cAB_r);
    k_edge3<<<gEdge, 256, 0, stream>>>(cAB_f, cAB_r, pos_f, pos_r, efh_f, efh_r,
                                       w1e2h + (size_t)k * 512,
                                       w1e2h + (size_t)(2 + k) * 512,
                                       w22h + (size_t)k * 256,
                                       w22h + (size_t)(2 + k) * 256,
                                       s_seq, outRW, ws_seq, k);
    if (k == 0)
      k_softagg3<1, 0><<<gAgg, 256, 0, stream>>>(
          nf, nr, ncat_f1, ncat_r1, s_seq, ws_seq, k, rp_d, rp_s, pos_f, pos_r,
          fpj + (size_t)k * HH * HH, rpj + (size_t)k * HH * HH, h_fwd, h_rev, outFW,
          lnw, lnb, x, gi_bf);
    else
      k_softagg3<0, 1><<<gAgg, 256, 0, stream>>>(
          nf, nr, ncat_f1, ncat_r1, s_seq, ws_seq, k, rp_d, rp_s, pos_f, pos_r,
          fpj + (size_t)k * HH * HH, rpj + (size_t)k * HH * HH, h_fwd, h_rev, outFW,
          lnw, lnb, x, gi_bf);
  }

  // gating
  k_gemm2<1, 1, GIN><<<MB64, 256, 0, stream>>>(gi_bf, GIN, rzw1_bf, rz_b1, hid_bf,
                                               384, NN, 384, nullptr, nullptr);
  dim3 gRZ(MB64, 2);
  k_gemm_rz<<<gRZ, 256, 0, stream>>>(hid_bf, rw2_bf, zw2_bf, r_b2, z_b2, outR, outZ,
                                     x, gi_bf);
  k_gemm2<1, 1, GIN><<<MB64, 256, 0, stream>>>(gi_bf, GIN, cw1_bf, c_b1, hid_bf, GIN,
                                               NN, GIN, nullptr, nullptr);
  k_gemm2<5, 0, GIN><<<MB64, 256, 0, stream>>>(hid_bf, GIN, cw2_bf, c_b2, outF, HH,
                                               NN, HH, outZ, x);
}

// Round 12
// 533.926 us; speedup vs baseline: 9.2708x; 1.0246x over previous
//
#include <hip/hip_runtime.h>
#include <hip/hip_fp16.h>
#include <math.h>

#define NN 25000
#define EE 400000
#define HH 64
#define NHEAD 4
#define SDIM 16
#define EFDIM 8
#define KHOP 2
#define MIN 168   // 2H + 2S + EF
#define WID 128
#define GIN 192
#define KP 96     // padded K for node-proj GEMM (80 -> 96)

typedef __attribute__((ext_vector_type(8))) short bf16x8;
typedef __attribute__((ext_vector_type(4))) float f32x4;
typedef unsigned short ushortT;
typedef unsigned int uintT;

__device__ __forceinline__ float wave_sum64(float v) {
#pragma unroll
  for (int m = 1; m <= 32; m <<= 1) v += __shfl_xor(v, m, 64);
  return v;
}

__device__ __forceinline__ ushortT f2b(float f) {
  uintT u = __float_as_uint(f);
  return (ushortT)((u + 0x7FFFu + ((u >> 16) & 1u)) >> 16);
}
__device__ __forceinline__ float b2f(ushortT h) {
  return __uint_as_float(((uintT)h) << 16);
}

union U4H8 {
  uint4 u;
  __half2 h[4];
};

// packed-f16 ReLU via sign-bit mask (no __hmax2 on ROCm 7.2)
__device__ __forceinline__ __half2 relu2(__half2 v) {
  union { __half2 h; uintT u; } x;
  x.h = v;
  uintT mask = ((x.u & 0x80008000u) >> 15) * 0xFFFFu;
  x.u &= ~mask;
  return x.h;
}

// ---------------- CSR build (both directions in one pass) ----------------
__global__ void k_histo2(const int* __restrict__ src, const int* __restrict__ dst,
                         int* __restrict__ cnt_s, int* __restrict__ cnt_d) {
  int e = blockIdx.x * 256 + threadIdx.x;
  if (e < EE) {
    atomicAdd(&cnt_d[dst[e]], 1);
    atomicAdd(&cnt_s[src[e]], 1);
  }
}

__global__ void k_scan2(const int* __restrict__ cnt_d, const int* __restrict__ cnt_s,
                        int* __restrict__ rp_d, int* __restrict__ rp_s) {
  const int* cnt = blockIdx.x ? cnt_s : cnt_d;
  int* rp = blockIdx.x ? rp_s : rp_d;
  __shared__ int part[1024];
  int t = threadIdx.x;
  const int CH = (NN + 1023) / 1024;
  int base = t * CH;
  int s = 0;
  for (int i = 0; i < CH; ++i) {
    int j = base + i;
    if (j < NN) s += cnt[j];
  }
  part[t] = s;
  __syncthreads();
  for (int off = 1; off < 1024; off <<= 1) {
    int v = (t >= off) ? part[t - off] : 0;
    __syncthreads();
    part[t] += v;
    __syncthreads();
  }
  int run = (t == 0) ? 0 : part[t - 1];
  for (int i = 0; i < CH; ++i) {
    int j = base + i;
    if (j < NN) { rp[j] = run; run += cnt[j]; }
  }
  if (t == 1023) rp[NN] = run;
}

__global__ void k_scatter2(const int* __restrict__ src, const int* __restrict__ dst,
                           const int* __restrict__ rp_s, const int* __restrict__ rp_d,
                           int* __restrict__ cur_s, int* __restrict__ cur_d,
                           int* __restrict__ eid_s, int* __restrict__ eid_d) {
  int e = blockIdx.x * 256 + threadIdx.x;
  if (e < EE) {
    int nd = dst[e];
    int pd = atomicAdd(&cur_d[nd], 1);
    eid_d[rp_d[nd] + pd] = e;
    int ns = src[e];
    int ps = atomicAdd(&cur_s[ns], 1);
    eid_s[rp_s[ns] + ps] = e;
  }
}

// wave-parallel bitonic sort of each segment (deterministic ascending order)
__global__ __launch_bounds__(256) void k_sortseg2(const int* __restrict__ rp_d,
                                                  const int* __restrict__ rp_s,
                                                  int* __restrict__ eid_d,
                                                  int* __restrict__ eid_s) {
  int gw = blockIdx.x * 4 + (threadIdx.x >> 6);
  int lane = threadIdx.x & 63;
  if (gw >= 2 * NN) return;
  const int* rp = (gw < NN) ? rp_d : rp_s;
  int* eids = (gw < NN) ? eid_d : eid_s;
  int node = (gw < NN) ? gw : gw - NN;
  int beg = rp[node], end = rp[node + 1];
  int deg = end - beg;
  if (deg <= 1) return;
  if (deg <= 64) {
    int v = (lane < deg) ? eids[beg + lane] : 0x7fffffff;
#pragma unroll
    for (int k = 2; k <= 64; k <<= 1) {
#pragma unroll
      for (int j = k >> 1; j > 0; j >>= 1) {
        int other = __shfl_xor(v, j, 64);
        bool takeMin = (((lane & k) == 0) == ((lane & j) == 0));
        v = takeMin ? min(v, other) : max(v, other);
      }
    }
    if (lane < deg) eids[beg + lane] = v;
  } else if (lane == 0) {
    for (int i = beg + 1; i < end; ++i) {
      int v = eids[i];
      int j = i - 1;
      while (j >= beg && eids[j] > v) { eids[j + 1] = eids[j]; --j; }
      eids[j + 1] = v;
    }
  }
}

// pos[ii] = {e, other_node, owner_node, 0}; position-ordered ef packed f16 (uint4)
__global__ void k_mkpos2(const int* __restrict__ eid_d, const int* __restrict__ eid_s,
                         const int* __restrict__ src, const int* __restrict__ dst,
                         const float* __restrict__ ef, int4* __restrict__ pos_f,
                         int4* __restrict__ pos_r, uint4* __restrict__ efh_f,
                         uint4* __restrict__ efh_r) {
  int i = blockIdx.x * 256 + threadIdx.x;
  if (i >= EE) return;
  int e1 = eid_d[i];
  pos_f[i] = make_int4(e1, src[e1], dst[e1], 0);
  int e2 = eid_s[i];
  pos_r[i] = make_int4(e2, dst[e2], src[e2], 0);
  {
    float4 a0 = *(const float4*)(ef + (size_t)e1 * EFDIM);
    float4 a1 = *(const float4*)(ef + (size_t)e1 * EFDIM + 4);
    U4H8 u;
    u.h[0] = __floats2half2_rn(a0.x, a0.y);
    u.h[1] = __floats2half2_rn(a0.z, a0.w);
    u.h[2] = __floats2half2_rn(a1.x, a1.y);
    u.h[3] = __floats2half2_rn(a1.z, a1.w);
    efh_f[i] = u.u;
  }
  {
    float4 b0 = *(const float4*)(ef + (size_t)e2 * EFDIM);
    float4 b1 = *(const float4*)(ef + (size_t)e2 * EFDIM + 4);
    U4H8 u;
    u.h[0] = __floats2half2_rn(b0.x, b0.y);
    u.h[1] = __floats2half2_rn(b0.z, b0.w);
    u.h[2] = __floats2half2_rn(b1.x, b1.y);
    u.h[3] = __floats2half2_rn(b1.z, b1.w);
    efh_r[i] = u.u;
  }
}

// ---- weight repack: pAB bf16[256][96] + w1e2 half2[8][64] + w22 half2[4][64] ----
#define PACKN (256 * KP + 512 + 256)
__global__ void k_pack_bf(const float* __restrict__ fw1, const float* __restrict__ rw1,
                          const float* __restrict__ fw2, const float* __restrict__ rw2,
                          ushortT* __restrict__ pAB_all, __half2* __restrict__ w1e2_all,
                          __half2* __restrict__ w22_all) {
  int y = blockIdx.y;
  const float* w1 = (y < 2) ? fw1 + (size_t)y * WID * MIN
                            : rw1 + (size_t)(y - 2) * WID * MIN;
  const float* w2 = (y < 2) ? fw2 + (size_t)y * NHEAD * WID
                            : rw2 + (size_t)(y - 2) * NHEAD * WID;
  int i = blockIdx.x * 256 + threadIdx.x;
  if (i < 256 * KP) {
    int j = i / KP, k = i % KP;
    float v = 0.f;
    if (k < 80) {
      int row = (j < 128) ? j : j - 128;
      int col = (j < 128) ? (k < 64 ? k : k + 64) : (k < 64 ? k + 64 : k + 80);
      v = w1[row * MIN + col];
    }
    pAB_all[(size_t)y * 256 * KP + i] = f2b(v);
  } else if (i < 256 * KP + 512) {
    int jj = i - 256 * KP;
    int f = jj >> 6, jp = jj & 63;
    w1e2_all[y * 512 + jj] =
        __floats2half2_rn(w1[(2 * jp) * MIN + 160 + f], w1[(2 * jp + 1) * MIN + 160 + f]);
  } else if (i < PACKN) {
    int jj = i - 256 * KP - 512;
    int o = jj >> 6, jp = jj & 63;
    w22_all[y * 256 + jj] = __floats2half2_rn(w2[o * WID + 2 * jp], w2[o * WID + 2 * jp + 1]);
  }
}

// fused conversion of all gating weights to bf16
#define CW1 (GIN * GIN)   // 36864
#define CW2 (HH * GIN)    // 12288
__global__ void k_cvt6(const float* __restrict__ r_w1, const float* __restrict__ z_w1,
                       const float* __restrict__ c_w1, const float* __restrict__ r_w2,
                       const float* __restrict__ z_w2, const float* __restrict__ c_w2,
                       ushortT* __restrict__ rzw1, ushortT* __restrict__ cw1,
                       ushortT* __restrict__ rw2, ushortT* __restrict__ zw2,
                       ushortT* __restrict__ cw2) {
  int i = blockIdx.x * 256 + threadIdx.x;
  if (i < CW1) rzw1[i] = f2b(r_w1[i]);
  else if (i < 2 * CW1) rzw1[i] = f2b(z_w1[i - CW1]);
  else if (i < 3 * CW1) cw1[i - 2 * CW1] = f2b(c_w1[i - 2 * CW1]);
  else if (i < 3 * CW1 + CW2) rw2[i - 3 * CW1] = f2b(r_w2[i - 3 * CW1]);
  else if (i < 3 * CW1 + 2 * CW2) zw2[i - 3 * CW1 - CW2] = f2b(z_w2[i - 3 * CW1 - CW2]);
  else if (i < 3 * CW1 + 3 * CW2) cw2[i - 3 * CW1 - 2 * CW2] = f2b(c_w2[i - 3 * CW1 - 2 * CW2]);
}

// ---- initial LayerNorm (h = x for both dirs): writes ncat0_{f,r}; xs/pad into all 4 ----
__global__ __launch_bounds__(256) void k_ln_init(
    const float* __restrict__ x, const float* __restrict__ xs,
    const float* __restrict__ lw, const float* __restrict__ lb,
    ushortT* __restrict__ ncf0, ushortT* __restrict__ ncr0,
    ushortT* __restrict__ ncf1, ushortT* __restrict__ ncr1) {
  int t = threadIdx.x;
  int node = blockIdx.x * 4 + (t >> 6), lane = t & 63;
  if (node >= NN) return;
  float v = x[(size_t)node * HH + lane];
  float mean = wave_sum64(v) * (1.0f / 64.0f);
  float d = v - mean;
  float var = wave_sum64(d * d) * (1.0f / 64.0f);
  ushortT val = f2b(d * rsqrtf(var + 1e-5f) * lw[lane] + lb[lane]);
  ncf0[(size_t)node * KP + lane] = val;
  ncr0[(size_t)node * KP + lane] = val;
  if (lane < SDIM) {
    ushortT xv = f2b(xs[(size_t)node * SDIM + lane]);
    ncf0[(size_t)node * KP + HH + lane] = xv;
    ncr0[(size_t)node * KP + HH + lane] = xv;
    ncf1[(size_t)node * KP + HH + lane] = xv;
    ncr1[(size_t)node * KP + HH + lane] = xv;
    ncf0[(size_t)node * KP + 80 + lane] = 0;
    ncr0[(size_t)node * KP + 80 + lane] = 0;
    ncf1[(size_t)node * KP + 80 + lane] = 0;
    ncr1[(size_t)node * KP + 80 + lane] = 0;
  }
}

// ------- node projection GEMM, both dirs: C = A[NN,96] @ W[256,96]^T (f16 out) -----
__global__ __launch_bounds__(256) void k_proj2(
    const ushortT* __restrict__ Af, const ushortT* __restrict__ Ar,
    const ushortT* __restrict__ Wf, const ushortT* __restrict__ Wr,
    ushortT* __restrict__ Cf, ushortT* __restrict__ Cr) {
  const ushortT* A = blockIdx.y ? Ar : Af;
  const ushortT* W = blockIdx.y ? Wr : Wf;
  ushortT* C = blockIdx.y ? Cr : Cf;
  int w = threadIdx.x >> 6, l = threadIdx.x & 63;
  int m0 = blockIdx.x * 64 + w * 16;
  int rowa = m0 + (l & 15);
  int kb = l >> 4;
  bf16x8 afr0 = {0,0,0,0,0,0,0,0}, afr1 = afr0, afr2 = afr0;
  if (rowa < NN) {
    const ushortT* ap = A + (size_t)rowa * KP + kb * 8;
    afr0 = *(const bf16x8*)(ap);
    afr1 = *(const bf16x8*)(ap + 32);
    afr2 = *(const bf16x8*)(ap + 64);
  }
  int crow = m0 + (l >> 4) * 4;
  int ccol0 = l & 15;
  for (int n0 = 0; n0 < 256; n0 += 64) {
    f32x4 acc[4];
#pragma unroll
    for (int n = 0; n < 4; ++n) acc[n] = (f32x4){0.f, 0.f, 0.f, 0.f};
    const ushortT* wbase = W + (size_t)(n0 + (l & 15)) * KP + kb * 8;
#pragma unroll
    for (int n = 0; n < 4; ++n) {
      const ushortT* wp = wbase + (size_t)(16 * n) * KP;
      acc[n] = __builtin_amdgcn_mfma_f32_16x16x32_bf16(afr0, *(const bf16x8*)(wp), acc[n], 0, 0, 0);
      acc[n] = __builtin_amdgcn_mfma_f32_16x16x32_bf16(afr1, *(const bf16x8*)(wp + 32), acc[n], 0, 0, 0);
      acc[n] = __builtin_amdgcn_mfma_f32_16x16x32_bf16(afr2, *(const bf16x8*)(wp + 64), acc[n], 0, 0, 0);
    }
#pragma unroll
    for (int n = 0; n < 4; ++n) {
      int col = n0 + ccol0 + n * 16;
#pragma unroll
      for (int r = 0; r < 4; ++r) {
        int row = crow + r;
        if (row < NN)
          C[(size_t)row * 256 + col] = __half_as_ushort(__float2half(acc[n][r]));
      }
    }
  }
}

// ------- generic MFMA GEMM; ACT 5 = fused GRU final: out=(1-z)x+z*tanh(v) ---------
template <int ACT, int BF16OUT, int KD>
__global__ __launch_bounds__(256) void k_gemm2(
    const ushortT* __restrict__ A, int lda, const ushortT* __restrict__ W,
    const float* __restrict__ bias, void* __restrict__ Cout, int ldc, int M, int Nc,
    const float* __restrict__ zv, const float* __restrict__ xp) {
  constexpr int KS = KD / 32;
  int w = threadIdx.x >> 6, l = threadIdx.x & 63;
  int m0 = blockIdx.x * 64 + w * 16;
  int rowa = m0 + (l & 15);
  int kb = l >> 4;
  bf16x8 afr[KS];
#pragma unroll
  for (int ks = 0; ks < KS; ++ks) {
    afr[ks] = (bf16x8){0, 0, 0, 0, 0, 0, 0, 0};
    if (rowa < M) afr[ks] = *(const bf16x8*)(A + (size_t)rowa * lda + ks * 32 + kb * 8);
  }
  int crow = m0 + (l >> 4) * 4;
  int ccol0 = l & 15;
  for (int n0 = 0; n0 < Nc; n0 += 64) {
    f32x4 acc[4];
#pragma unroll
    for (int n = 0; n < 4; ++n) acc[n] = (f32x4){0.f, 0.f, 0.f, 0.f};
    const ushortT* wbase = W + (size_t)(n0 + (l & 15)) * KD + kb * 8;
#pragma unroll
    for (int n = 0; n < 4; ++n) {
      const ushortT* wp = wbase + (size_t)(16 * n) * KD;
#pragma unroll
      for (int ks = 0; ks < KS; ++ks)
        acc[n] = __builtin_amdgcn_mfma_f32_16x16x32_bf16(afr[ks], *(const bf16x8*)(wp + ks * 32),
                                                         acc[n], 0, 0, 0);
    }
#pragma unroll
    for (int n = 0; n < 4; ++n) {
      int col = n0 + ccol0 + n * 16;
      float bv = bias ? bias[col] : 0.f;
#pragma unroll
      for (int r = 0; r < 4; ++r) {
        int row = crow + r;
        if (row < M) {
          float v = acc[n][r] + bv;
          if (ACT == 1) v = fmaxf(v, 0.f);
          else if (ACT == 2) v = 1.f / (1.f + expf(-v));
          else if (ACT == 3) v = tanhf(v);
          else if (ACT == 5) {
            float z = zv[(size_t)row * HH + col];
            float xv = xp[(size_t)row * HH + col];
            v = (1.f - z) * xv + z * tanhf(v);
          }
          if (BF16OUT)
            ((ushortT*)Cout)[(size_t)row * ldc + col] = f2b(v);
          else
            ((float*)Cout)[(size_t)row * ldc + col] = v;
        }
      }
    }
  }
}

// dual r2/z2 second-layer gemm (sigmoid): y=0 -> outR + gi[0:64]=r*x ; y=1 -> outZ
__global__ __launch_bounds__(256) void k_gemm_rz(
    const ushortT* __restrict__ hid, const ushortT* __restrict__ rw2,
    const ushortT* __restrict__ zw2, const float* __restrict__ rb2,
    const float* __restrict__ zb2, float* __restrict__ outR, float* __restrict__ outZ,
    const float* __restrict__ x, ushortT* __restrict__ gi) {
  int y = blockIdx.y;
  const ushortT* A = hid + (y ? GIN : 0);
  const ushortT* W = y ? zw2 : rw2;
  const float* bias = y ? zb2 : rb2;
  float* C = y ? outZ : outR;
  constexpr int KS = GIN / 32;
  int w = threadIdx.x >> 6, l = threadIdx.x & 63;
  int m0 = blockIdx.x * 64 + w * 16;
  int rowa = m0 + (l & 15);
  int kb = l >> 4;
  bf16x8 afr[KS];
#pragma unroll
  for (int ks = 0; ks < KS; ++ks) {
    afr[ks] = (bf16x8){0, 0, 0, 0, 0, 0, 0, 0};
    if (rowa < NN) afr[ks] = *(const bf16x8*)(A + (size_t)rowa * 384 + ks * 32 + kb * 8);
  }
  int crow = m0 + (l >> 4) * 4;
  int ccol0 = l & 15;
  f32x4 acc[4];
#pragma unroll
  for (int n = 0; n < 4; ++n) acc[n] = (f32x4){0.f, 0.f, 0.f, 0.f};
  const ushortT* wbase = W + (size_t)(l & 15) * GIN + kb * 8;
#pragma unroll
  for (int n = 0; n < 4; ++n) {
    const ushortT* wp = wbase + (size_t)(16 * n) * GIN;
#pragma unroll
    for (int ks = 0; ks < KS; ++ks)
      acc[n] = __builtin_amdgcn_mfma_f32_16x16x32_bf16(afr[ks], *(const bf16x8*)(wp + ks * 32),
                                                       acc[n], 0, 0, 0);
  }
#pragma unroll
  for (int n = 0; n < 4; ++n) {
    int col = ccol0 + n * 16;
    float bv = bias[col];
#pragma unroll
    for (int r = 0; r < 4; ++r) {
      int row = crow + r;
      if (row < NN) {
        float v = acc[n][r] + bv;
        float sig = 1.f / (1.f + expf(-v));
        C[(size_t)row * HH + col] = sig;
        if (y == 0)  // fused candin: gi[0:64] = r * x
          gi[(size_t)row * GIN + col] = f2b(sig * x[(size_t)row * HH + col]);
      }
    }
  }
}

// ------- edge combine, CSR-position-ordered, both dirs, packed f16 math -----------
__global__ __launch_bounds__(256) void k_edge3(
    const ushortT* __restrict__ cABf, const ushortT* __restrict__ cABr,
    const int4* __restrict__ pos_f, const int4* __restrict__ pos_r,
    const uint4* __restrict__ efh_f, const uint4* __restrict__ efh_r,
    const __half2* __restrict__ w1e2_f, const __half2* __restrict__ w1e2_r,
    const __half2* __restrict__ w22_f, const __half2* __restrict__ w22_r,
    float* __restrict__ s_seq, float* __restrict__ outRW,
    float* __restrict__ ws_seq, int hop) {
  int y = blockIdx.y;
  const __half2* cAB2 = (const __half2*)(y ? cABr : cABf);
  const int4* pos = y ? pos_r : pos_f;
  const uint4* efh = y ? efh_r : efh_f;
  const __half2* w1e2 = y ? w1e2_r : w1e2_f;
  const __half2* w22 = y ? w22_r : w22_f;
  __shared__ __half2 w1e2_s[8][64];
  __shared__ __half2 w22_s[4][64];
  int t = threadIdx.x;
  for (int i = t; i < 512; i += 256) w1e2_s[i >> 6][i & 63] = w1e2[i];
  if (t < 256) w22_s[t >> 6][t & 63] = w22[t];
  __syncthreads();
  int es = t >> 2, q = t & 3;
  size_t ii = (size_t)blockIdx.x * 64 + es;
  int4 pr = pos[ii];
  const __half2* cA2 = cAB2 + (size_t)pr.y * 128;
  const __half2* cB2 = cAB2 + (size_t)pr.z * 128 + 64;
  U4H8 efu;
  efu.u = efh[ii];
  __half2 efb[8];
#pragma unroll
  for (int f2v = 0; f2v < 4; ++f2v) {
    efb[2 * f2v] = __half2half2(__low2half(efu.h[f2v]));
    efb[2 * f2v + 1] = __half2half2(__high2half(efu.h[f2v]));
  }
  float pf[4] = {0.f, 0.f, 0.f, 0.f};
#pragma unroll
  for (int c = 0; c < 4; ++c) {
    int jp0 = c * 16 + q * 4;
    U4H8 ua, ub;
    ua.u = *(const uint4*)(cA2 + jp0);
    ub.u = *(const uint4*)(cB2 + jp0);
    __half2 h2v[4];
#pragma unroll
    for (int i2 = 0; i2 < 4; ++i2) h2v[i2] = __hadd2(ua.h[i2], ub.h[i2]);
#pragma unroll
    for (int f = 0; f < 8; ++f) {
      U4H8 wv;
      wv.u = *(const uint4*)(&w1e2_s[f][jp0]);
#pragma unroll
      for (int i2 = 0; i2 < 4; ++i2) h2v[i2] = __hfma2(efb[f], wv.h[i2], h2v[i2]);
    }
#pragma unroll
    for (int i2 = 0; i2 < 4; ++i2) h2v[i2] = relu2(h2v[i2]);
#pragma unroll
    for (int o = 0; o < 4; ++o) {
      U4H8 wv;
      wv.u = *(const uint4*)(&w22_s[o][jp0]);
      __half2 p2 = __hmul2(h2v[0], wv.h[0]);
      p2 = __hfma2(h2v[1], wv.h[1], p2);
      p2 = __hfma2(h2v[2], wv.h[2], p2);
      p2 = __hfma2(h2v[3], wv.h[3], p2);
      pf[o] += __low2float(p2) + __high2float(p2);
    }
  }
#pragma unroll
  for (int m = 1; m <= 2; m <<= 1) {
    pf[0] += __shfl_xor(pf[0], m, 64);
    pf[1] += __shfl_xor(pf[1], m, 64);
    pf[2] += __shfl_xor(pf[2], m, 64);
    pf[3] += __shfl_xor(pf[3], m, 64);
  }
  float pv = (q == 0) ? pf[0] : (q == 1) ? pf[1] : (q == 2) ? pf[2] : pf[3];
  if (y) {
    float sig = 1.f / (1.f + expf(-pv));
    outRW[(size_t)pr.x * (NHEAD * KHOP) + q * KHOP + hop] = sig;
    ws_seq[ii * 4 + q] = sig;
  } else {
    s_seq[ii * 4 + q] = (pv > 0.f ? pv : 0.01f * pv) * 0.25f;
  }
}

// ---- merged softmax/sigmoid + aggregate + proj + residual (+LN / +gatein) ----
// 16 nodes/block: each wave serially processes 4 nodes; proj staged once;
// per-node prefetch fills w_s (weights) and ot_s (other*KP) in LDS (deg<=64 path).
template <int DO_LN, int DO_GATE>
__global__ __launch_bounds__(256) void k_softagg4(
    const ushortT* __restrict__ ncf, const ushortT* __restrict__ ncr,
    ushortT* __restrict__ ncf_n, ushortT* __restrict__ ncr_n,
    const float* __restrict__ s_seq, const float* __restrict__ ws_seq, int hop,
    const int* __restrict__ rp_d, const int* __restrict__ rp_s,
    const int4* __restrict__ pos_f, const int4* __restrict__ pos_r,
    const float* __restrict__ proj_f, const float* __restrict__ proj_r,
    float* __restrict__ h_f, float* __restrict__ h_r, float* __restrict__ wout,
    const float* __restrict__ lnw, const float* __restrict__ lnb,
    const float* __restrict__ x, ushortT* __restrict__ gi) {
  int y = blockIdx.y;
  const ushortT* hn_bf = y ? ncr : ncf;
  const int* rp = y ? rp_s : rp_d;
  const int4* pos = y ? pos_r : pos_f;
  const float* proj = y ? proj_r : proj_f;
  float* h = y ? h_r : h_f;
  __shared__ float proj_s[64][68];
  __shared__ float agg_s[4][64];
  __shared__ float w_s[4][64][4];
  __shared__ int ot_s[4][64];
  int t = threadIdx.x;
  for (int i = t; i < 4096; i += 256) proj_s[i >> 6][i & 63] = proj[i];
  int wvi = t >> 6, lane = t & 63;
  __syncthreads();

  for (int it = 0; it < 4; ++it) {
    int node = blockIdx.x * 16 + wvi * 4 + it;
    if (node >= NN) continue;
    int beg = rp[node], end = rp[node + 1];
    int deg = end - beg;
    bool small = (deg <= 64);
    float mxv = 0.f, invv = 0.f;  // deg>64 fwd fallback state
    int li = lane >> 2, o = lane & 3;
    if (deg > 0 && small) {
      // prefetch phase: fill ot_s (+ w_s for both dirs)
      int i0 = beg + li;
      if (y == 0) {
        int ee4[4];
        float sv[4];
#pragma unroll
        for (int u = 0; u < 4; ++u) {
          int idx = i0 + u * 16;
          bool val = idx < end;
          int4 pr = pos[val ? idx : beg];
          ee4[u] = pr.x;
          if (o == 0 && val) ot_s[wvi][li + u * 16] = pr.y * KP;
          float v = s_seq[(size_t)(val ? idx : beg) * 4 + o];
          sv[u] = val ? v : -1e30f;
        }
        float mx = fmaxf(fmaxf(sv[0], sv[1]), fmaxf(sv[2], sv[3]));
#pragma unroll
        for (int m = 4; m <= 32; m <<= 1) mx = fmaxf(mx, __shfl_xor(mx, m, 64));
        float ex[4];
        float sum = 0.f;
#pragma unroll
        for (int u = 0; u < 4; ++u) {
          ex[u] = (sv[u] > -1e29f) ? expf(sv[u] - mx) : 0.f;
          sum += ex[u];
        }
#pragma unroll
        for (int m = 4; m <= 32; m <<= 1) sum += __shfl_xor(sum, m, 64);
        float inv = 1.f / (sum + 1e-9f);
#pragma unroll
        for (int u = 0; u < 4; ++u) {
          if (i0 + u * 16 < end) {
            float wv = ex[u] * inv;
            wout[(size_t)ee4[u] * (NHEAD * KHOP) + o * KHOP + hop] = wv;
            w_s[wvi][li + u * 16][o] = wv;
          }
        }
      } else {
#pragma unroll
        for (int u = 0; u < 4; ++u) {
          int idx = i0 + u * 16;
          bool val = idx < end;
          if (val) {
            if (o == 0) {
              int4 pr = pos[idx];
              ot_s[wvi][li + u * 16] = pr.y * KP;
            }
            w_s[wvi][li + u * 16][o] = ws_seq[(size_t)idx * 4 + o];
          }
        }
      }
    } else if (deg > 0) {
      // deg > 64 fwd: compute softmax stats + write wout (global recompute path)
      if (y == 0) {
        float mx = -1e30f;
        for (int ii = beg + li; ii < end; ii += 16)
          mx = fmaxf(mx, s_seq[(size_t)ii * 4 + o]);
#pragma unroll
        for (int m = 4; m <= 32; m <<= 1) mx = fmaxf(mx, __shfl_xor(mx, m, 64));
        float sum = 0.f;
        for (int ii = beg + li; ii < end; ii += 16)
          sum += expf(s_seq[(size_t)ii * 4 + o] - mx);
#pragma unroll
        for (int m = 4; m <= 32; m <<= 1) sum += __shfl_xor(sum, m, 64);
        float inv = 1.f / (sum + 1e-9f);
        for (int ii = beg + li; ii < end; ii += 16) {
          wout[(size_t)pos[ii].x * (NHEAD * KHOP) + o * KHOP + hop] =
              expf(s_seq[(size_t)ii * 4 + o] - mx) * inv;
        }
        mxv = mx;
        invv = inv;
      }
    }
    // aggregate phase
    int hd = lane >> 4;
    float acc = 0.f;
    if (small) {
      for (int ii = 0; ii < deg; ii += 8) {
#pragma unroll
        for (int u = 0; u < 8; ++u) {
          int ed = ii + u;
          int edc = (ed < deg) ? ed : 0;
          int ot = ot_s[wvi][edc];
          float w = w_s[wvi][edc][hd];
          float hv = b2f(hn_bf[(size_t)ot + lane]);
          acc += ((ed < deg) ? w : 0.f) * hv;
        }
      }
    } else {
      float mx_hd = 0.f, inv_hd = 0.f;
      if (y == 0) {
        mx_hd = __shfl(mxv, hd, 64);
        inv_hd = __shfl(invv, hd, 64);
      }
      for (int ii = beg; ii < end; ++ii) {
        int4 pr = pos[ii];
        float w;
        if (y == 0)
          w = expf(s_seq[(size_t)ii * 4 + hd] - mx_hd) * inv_hd;
        else
          w = ws_seq[(size_t)ii * 4 + hd];
        acc += w * b2f(hn_bf[(size_t)pr.y * KP + lane]);
      }
    }
    agg_s[wvi][lane] = acc;  // same-wave LDS RAW: no barrier needed
    float m = 0.f;
#pragma unroll
    for (int hh = 0; hh < 64; hh += 4) {
      float4 p = *(const float4*)(&proj_s[lane][hh]);
      m += p.x * agg_s[wvi][hh] + p.y * agg_s[wvi][hh + 1] +
           p.z * agg_s[wvi][hh + 2] + p.w * agg_s[wvi][hh + 3];
    }
    size_t g = (size_t)node * HH + lane;
    float hnew = h[g] + m;
    h[g] = hnew;
    if (DO_LN) {
      float mean = wave_sum64(hnew) * (1.0f / 64.0f);
      float d = hnew - mean;
      float var = wave_sum64(d * d) * (1.0f / 64.0f);
      ushortT val = f2b(d * rsqrtf(var + 1e-5f) * lnw[lane] + lnb[lane]);
      (y ? ncr_n : ncf_n)[(size_t)node * KP + lane] = val;
    }
    if (DO_GATE) {
      float xv = x[g];
      if (y == 0) {
        gi[(size_t)node * GIN + lane] = f2b(xv);
        gi[(size_t)node * GIN + 64 + lane] = f2b(hnew - xv);
      } else {
        gi[(size_t)node * GIN + 128 + lane] = f2b(hnew - xv);
      }
    }
  }
}

extern "C" void kernel_launch(void* const* d_in, const int* in_sizes, int n_in,
                              void* d_out, int out_size, void* d_ws, size_t ws_size,
                              hipStream_t stream) {
  const float* x = (const float*)d_in[0];
  const float* xs = (const float*)d_in[1];
  const int* ei = (const int*)d_in[2];
  const float* ef = (const float*)d_in[3];
  const float* fw1 = (const float*)d_in[4];
  const float* fw2 = (const float*)d_in[5];
  const float* fpj = (const float*)d_in[6];
  const float* rw1 = (const float*)d_in[7];
  const float* rw2 = (const float*)d_in[8];
  const float* rpj = (const float*)d_in[9];
  const float* lnw = (const float*)d_in[10];
  const float* lnb = (const float*)d_in[11];
  const float* r_w1 = (const float*)d_in[12];
  const float* r_b1 = (const float*)d_in[13];
  const float* r_w2 = (const float*)d_in[14];
  const float* r_b2 = (const float*)d_in[15];
  const float* z_w1 = (const float*)d_in[16];
  const float* z_b1 = (const float*)d_in[17];
  const float* z_w2 = (const float*)d_in[18];
  const float* z_b2 = (const float*)d_in[19];
  const float* c_w1 = (const float*)d_in[20];
  const float* c_b1 = (const float*)d_in[21];
  const float* c_w2 = (const float*)d_in[22];
  const float* c_b2 = (const float*)d_in[23];
  const int* srcp = ei;
  const int* dstp = ei + EE;

  float* outF = (float*)d_out;
  float* outFW = outF + (size_t)NN * HH;
  float* outRW = outFW + (size_t)EE * NHEAD * KHOP;
  float* outZ = outRW + (size_t)EE * NHEAD * KHOP;
  float* outR = outZ + (size_t)NN * HH;

  char* Wb = (char*)d_ws;
  size_t off = 0;
  auto alloc = [&](size_t bytes) -> void* {
    void* p = Wb + off;
    off += (bytes + 255) & ~(size_t)255;
    return p;
  };
  float* h_fwd = (float*)alloc((size_t)NN * HH * 4);
  float* h_rev = (float*)alloc((size_t)NN * HH * 4);
  ushortT* ncat_f0 = (ushortT*)alloc((size_t)NN * KP * 2);
  ushortT* ncat_r0 = (ushortT*)alloc((size_t)NN * KP * 2);
  ushortT* ncat_f1 = (ushortT*)alloc((size_t)NN * KP * 2);
  ushortT* ncat_r1 = (ushortT*)alloc((size_t)NN * KP * 2);
  float* s_seq = (float*)alloc((size_t)EE * NHEAD * 4);
  float* ws_seq = (float*)alloc((size_t)EE * NHEAD * 4);
  char* big = (char*)alloc((size_t)2 * NN * 256 * 2);
  ushortT* cAB_f = (ushortT*)big;          // f16 during hops
  ushortT* cAB_r = (ushortT*)(big + (size_t)NN * 256 * 2);
  ushortT* hid_bf = (ushortT*)big;         // bf16 during gating
  ushortT* gi_bf = (ushortT*)alloc((size_t)NN * GIN * 2);
  ushortT* packAB_bf = (ushortT*)alloc((size_t)4 * 256 * KP * 2);
  __half2* w1e2h = (__half2*)alloc((size_t)4 * 512 * 4);
  __half2* w22h = (__half2*)alloc((size_t)4 * 256 * 4);
  ushortT* rzw1_bf = (ushortT*)alloc((size_t)384 * GIN * 2);
  ushortT* rw2_bf = (ushortT*)alloc((size_t)HH * GIN * 2);
  ushortT* zw2_bf = (ushortT*)alloc((size_t)HH * GIN * 2);
  ushortT* cw1_bf = (ushortT*)alloc((size_t)GIN * GIN * 2);
  ushortT* cw2_bf = (ushortT*)alloc((size_t)HH * GIN * 2);
  float* rz_b1 = (float*)alloc(384 * 4);
  int* rp_d = (int*)alloc((NN + 8) * 4);
  int* rp_s = (int*)alloc((NN + 8) * 4);
  int* cur2 = (int*)alloc((size_t)2 * NN * 4);
  int* cur_d = cur2;
  int* cur_s = cur2 + NN;
  int* eid_d = (int*)alloc((size_t)EE * 4);
  int* eid_s = (int*)alloc((size_t)EE * 4);
  int4* pos_f = (int4*)alloc((size_t)EE * 16);
  int4* pos_r = (int4*)alloc((size_t)EE * 16);
  uint4* efh_f = (uint4*)alloc((size_t)EE * 16);
  uint4* efh_r = (uint4*)alloc((size_t)EE * 16);

  (void)hipMemcpyAsync(h_fwd, x, (size_t)NN * HH * 4, hipMemcpyDeviceToDevice, stream);
  (void)hipMemcpyAsync(h_rev, x, (size_t)NN * HH * 4, hipMemcpyDeviceToDevice, stream);
  (void)hipMemcpyAsync(rz_b1, r_b1, GIN * 4, hipMemcpyDeviceToDevice, stream);
  (void)hipMemcpyAsync(rz_b1 + GIN, z_b1, GIN * 4, hipMemcpyDeviceToDevice, stream);

  const int EB = (EE + 255) / 256, NW = (NN + 3) / 4;
  const int PB = (PACKN + 255) / 256;

  // weight repacks
  dim3 gPack(PB, 4);
  k_pack_bf<<<gPack, 256, 0, stream>>>(fw1, rw1, fw2, rw2, packAB_bf, w1e2h, w22h);
  k_cvt6<<<(3 * CW1 + 3 * CW2 + 255) / 256, 256, 0, stream>>>(
      r_w1, z_w1, c_w1, r_w2, z_w2, c_w2, rzw1_bf, cw1_bf, rw2_bf, zw2_bf, cw2_bf);

  // CSR build (both directions)
  (void)hipMemsetAsync(cur2, 0, (size_t)2 * NN * 4, stream);
  k_histo2<<<EB, 256, 0, stream>>>(srcp, dstp, cur_s, cur_d);
  k_scan2<<<2, 1024, 0, stream>>>(cur_d, cur_s, rp_d, rp_s);
  (void)hipMemsetAsync(cur2, 0, (size_t)2 * NN * 4, stream);
  k_scatter2<<<EB, 256, 0, stream>>>(srcp, dstp, rp_s, rp_d, cur_s, cur_d, eid_s, eid_d);
  k_sortseg2<<<(2 * NN + 3) / 4, 256, 0, stream>>>(rp_d, rp_s, eid_d, eid_s);
  k_mkpos2<<<EB, 256, 0, stream>>>(eid_d, eid_s, srcp, dstp, ef, pos_f, pos_r, efh_f, efh_r);

  // initial LN (h = x for both chains)
  k_ln_init<<<NW, 256, 0, stream>>>(x, xs, lnw, lnb, ncat_f0, ncat_r0, ncat_f1, ncat_r1);

  const int MB64 = (NN + 63) / 64;   // 391
  const int NB16 = (NN + 15) / 16;   // 1563
  dim3 gProj(MB64, 2), gEdge(EE / 64, 2), gAgg(NB16, 2);
  for (int k = 0; k < KHOP; ++k) {
    const ushortT* nf = k ? ncat_f1 : ncat_f0;
    const ushortT* nr = k ? ncat_r1 : ncat_r0;
    k_proj2<<<gProj, 256, 0, stream>>>(nf, nr,
                                       packAB_bf + (size_t)k * 256 * KP,
                                       packAB_bf + (size_t)(2 + k) * 256 * KP,
                                       cAB_f, cAB_r);
    k_edge3<<<gEdge, 256, 0, stream>>>(cAB_f, cAB_r, pos_f, pos_r, efh_f, efh_r,
                                       w1e2h + (size_t)k * 512,
                                       w1e2h + (size_t)(2 + k) * 512,
                                       w22h + (size_t)k * 256,
                                       w22h + (size_t)(2 + k) * 256,
                                       s_seq, outRW, ws_seq, k);
    if (k == 0)
      k_softagg4<1, 0><<<gAgg, 256, 0, stream>>>(
          nf, nr, ncat_f1, ncat_r1, s_seq, ws_seq, k, rp_d, rp_s, pos_f, pos_r,
          fpj + (size_t)k * HH * HH, rpj + (size_t)k * HH * HH, h_fwd, h_rev, outFW,
          lnw, lnb, x, gi_bf);
    else
      k_softagg4<0, 1><<<gAgg, 256, 0, stream>>>(
          nf, nr, ncat_f1, ncat_r1, s_seq, ws_seq, k, rp_d, rp_s, pos_f, pos_r,
          fpj + (size_t)k * HH * HH, rpj + (size_t)k * HH * HH, h_fwd, h_rev, outFW,
          lnw, lnb, x, gi_bf);
  }

  // gating
  k_gemm2<1, 1, GIN><<<MB64, 256, 0, stream>>>(gi_bf, GIN, rzw1_bf, rz_b1, hid_bf,
                                               384, NN, 384, nullptr, nullptr);
  dim3 gRZ(MB64, 2);
  k_gemm_rz<<<gRZ, 256, 0, stream>>>(hid_bf, rw2_bf, zw2_bf, r_b2, z_b2, outR, outZ,
                                     x, gi_bf);
  k_gemm2<1, 1, GIN><<<MB64, 256, 0, stream>>>(gi_bf, GIN, cw1_bf, c_b1, hid_bf, GIN,
                                               NN, GIN, nullptr, nullptr);
  k_gemm2<5, 0, GIN><<<MB64, 256, 0, stream>>>(hid_bf, GIN, cw2_bf, c_b2, outF, HH,
                                               NN, HH, outZ, x);
}